// Round 11
// baseline (5341.269 us; speedup 1.0000x reference)
//
#include <hip/hip_runtime.h>
#include <hip/hip_fp16.h>
#include <math.h>

#define NN 32768
#define HH 128
#define DD 16
#define BB 256
#define E2N (NN*DD)
#define NF (NN*HH)

typedef __attribute__((ext_vector_type(8))) short bf16x8;
typedef __attribute__((ext_vector_type(4))) short bf16x4;
typedef __attribute__((ext_vector_type(4))) float f32x4;
typedef __attribute__((ext_vector_type(4))) unsigned short u16x4;
typedef __attribute__((ext_vector_type(8))) unsigned short u16x8;
typedef _Float16 f16x8 __attribute__((ext_vector_type(8)));

__device__ __forceinline__ float fsig(float x) { return 1.0f/(1.0f + __expf(-x)); }
__device__ __forceinline__ float ftanh(float x) {
  float cx = fminf(fmaxf(x, -15.0f), 15.0f);
  float e = __expf(2.0f*cx);
  return 1.0f - 2.0f/(e + 1.0f);
}

// round-to-nearest-even fp32 -> bf16 (top 16 bits)
__device__ __forceinline__ unsigned bf16_rne(float x) {
  unsigned u = __float_as_uint(x);
  return (u + 0x7FFFu + ((u >> 16) & 1u)) >> 16;
}
__device__ __forceinline__ void bsplit(float x, short& hi, short& lo) {
  unsigned hb = bf16_rne(x);
  float hf = __uint_as_float(hb << 16);
  hi = (short)hb;
  lo = (short)bf16_rne(x - hf);
}

// ---------------- transpose prep (weights -> [K][Nout] layout) ----------------
struct TDesc { const float* src; float* dst; int R; int C; };
struct TDescArr { TDesc d[26]; };

__global__ void transpose_many(TDescArr da) {
  TDesc t = da.d[blockIdx.y];
  int idx = blockIdx.x*256 + threadIdx.x;
  if (idx < t.R*t.C) {
    int r = idx / t.C, c = idx - r*t.C;
    t.dst[(size_t)c*t.R + r] = t.src[idx];
  }
}

__global__ void bias_sum_kernel(const float* __restrict__ bih, const float* __restrict__ bhh,
                                float* __restrict__ bsum) {
  int i = blockIdx.x*256 + threadIdx.x;
  if (i < 2048) bsum[i] = bih[i] + bhh[i];
}

// split 4 matrices [512][128] fp32 -> fp16 hi/lo (exact 2-term split)
__global__ void wsplit16_kernel(const float* __restrict__ W,
                                unsigned short* __restrict__ hi,
                                unsigned short* __restrict__ lo) {
  int i = blockIdx.x*256 + threadIdx.x;   // 4*512*128 elems
  float x = W[i];
  __half h = __float2half_rn(x);
  __half l = __float2half_rn(x - __half2float(h));
  hi[i] = __half_as_ushort(h);
  lo[i] = __half_as_ushort(l);
}

// ---------------- embeddings ----------------
__global__ void embed3_kernel(const int* __restrict__ a_ids, const int* __restrict__ d_ids,
                              const int* __restrict__ a2_ids,
                              const float* __restrict__ ea, const float* __restrict__ ed,
                              const float* __restrict__ ea2,
                              float* __restrict__ ha, float* __restrict__ hd,
                              float* __restrict__ hg2) {
  int idx = blockIdx.x*256 + threadIdx.x;
  int n = idx >> 7, j = idx & 127;
  int w = blockIdx.y;
  if (w == 0)      ha[idx]  = ea[(size_t)a_ids[n]*128 + j];
  else if (w == 1) hd[idx]  = ed[(size_t)d_ids[n]*128 + j];
  else             hg2[idx] = ea2[(size_t)a2_ids[n]*128 + j];
}

// ---------------- generic GEMM: C = act(A @ W^T + bias + beta*C) ----------------
template<int BN, int ACT>
__global__ __launch_bounds__(256) void gemm_nt(
    const float* __restrict__ A0, const float* __restrict__ A1,
    const float* __restrict__ A2, const float* __restrict__ A3,
    int lda, const float* __restrict__ WT, const float* __restrict__ bias,
    float* __restrict__ C, int K, int beta)
{
  extern __shared__ float sm[];
  const int KP = K + 4;
  float* At = sm;             // [32][KP]
  float* Bc = sm + 32*KP;     // [16][BN]
  const int tid = threadIdx.x;
  const int m0 = blockIdx.x*32;
  const int ng = tid >> 5, cg = tid & 31;
  const int n0 = ng*4, c4 = cg*4;
  constexpr int G = BN/128;
  float acc[G][4][4];
#pragma unroll
  for (int g=0; g<G; ++g)
#pragma unroll
    for (int i=0;i<4;++i)
#pragma unroll
      for (int e=0;e<4;++e) acc[g][i][e] = 0.0f;

  const int nf4 = K >> 2;
  for (int idx = tid; idx < 32*nf4; idx += 256) {
    int row = idx / nf4;
    int kk = (idx - row*nf4) << 2;
    const float* Ap = (kk < 128) ? A0 : (kk < 256) ? A1 : (kk < 384) ? A2 : A3;
    float4 v = *(const float4*)(Ap + (size_t)(m0+row)*lda + (kk & 127));
    *(float4*)(At + row*KP + kk) = v;
  }
  const int nchunk = K >> 4;
  for (int kc = 0; kc < nchunk; ++kc) {
    __syncthreads();
    for (int idx = tid; idx < 16*(BN/4); idx += 256) {
      int kk = idx / (BN/4);
      int jq = idx - kk*(BN/4);
      *(float4*)(Bc + kk*BN + jq*4) = *(const float4*)(WT + (size_t)(kc*16+kk)*BN + jq*4);
    }
    __syncthreads();
    for (int k=0;k<16;++k) {
      const int kk = kc*16 + k;
      float av[4];
#pragma unroll
      for (int i=0;i<4;++i) av[i] = At[(n0+i)*KP + kk];
#pragma unroll
      for (int g=0; g<G; ++g) {
        float4 bv = *(const float4*)(Bc + k*BN + g*128 + c4);
        float bb[4] = {bv.x, bv.y, bv.z, bv.w};
#pragma unroll
        for (int i=0;i<4;++i)
#pragma unroll
          for (int e=0;e<4;++e)
            acc[g][i][e] += av[i]*bb[e];
      }
    }
  }
#pragma unroll
  for (int g=0; g<G; ++g) {
#pragma unroll
    for (int i=0;i<4;++i) {
      float* dst = C + (size_t)(m0+n0+i)*BN + g*128 + c4;
      float o[4];
#pragma unroll
      for (int e=0;e<4;++e) o[e] = acc[g][i][e];
      if (bias) {
#pragma unroll
        for (int e=0;e<4;++e) o[e] += bias[g*128 + c4 + e];
      }
      if (beta) {
        float4 p = *(const float4*)dst;
        o[0]+=p.x; o[1]+=p.y; o[2]+=p.z; o[3]+=p.w;
      }
      if (ACT==1) {
#pragma unroll
        for (int e=0;e<4;++e) o[e] = fmaxf(o[e], 0.0f);
      }
      *(float4*)dst = make_float4(o[0],o[1],o[2],o[3]);
    }
  }
}

// ---------------- Gx precompute (fp16 MFMA): Gx[row][512] = Wih . fs[row] + bsum ----------------
// x staged as single fp16 tile; W as fp16 hi/lo -> 2 MFMAs per tile.
// Output fp16, lane-permuted: half_idx = (wR*4+lq)*32 + g*8 + p*4 + e.
__global__ __launch_bounds__(512) void gx_kernel(
    unsigned short* __restrict__ GxH, const float* __restrict__ fs,
    const unsigned short* __restrict__ WIhi, const unsigned short* __restrict__ WIlo,
    const float* __restrict__ bsum)
{
  __shared__ unsigned short xF[64*136];
  const int tid = threadIdx.x;
  const int w = tid >> 6;          // writer wave 0..7
  const int lane = tid & 63;
  const int ln16 = lane & 15;
  const int lq = lane >> 4;
  const int rb = blockIdx.x * 64;

  {
    const int r = tid >> 3;
    const int cf = (tid & 7) * 16;
    const float* src = fs + (size_t)(rb + r)*128 + cf;
    u16x8 pk0, pk1;
#pragma unroll
    for (int q=0; q<2; ++q) {
      float4 v0 = *(const float4*)(src + q*8);
      float4 v1 = *(const float4*)(src + q*8 + 4);
      u16x8 pk;
      pk[0]=__half_as_ushort(__float2half_rn(v0.x));
      pk[1]=__half_as_ushort(__float2half_rn(v0.y));
      pk[2]=__half_as_ushort(__float2half_rn(v0.z));
      pk[3]=__half_as_ushort(__float2half_rn(v0.w));
      pk[4]=__half_as_ushort(__float2half_rn(v1.x));
      pk[5]=__half_as_ushort(__float2half_rn(v1.y));
      pk[6]=__half_as_ushort(__float2half_rn(v1.z));
      pk[7]=__half_as_ushort(__float2half_rn(v1.w));
      if (q==0) pk0 = pk; else pk1 = pk;
    }
    *(u16x8*)(xF + r*136 + cf) = pk0;
    *(u16x8*)(xF + r*136 + cf + 8) = pk1;
  }
  f32x4 acc[4][4];   // [gate][nt]
#pragma unroll
  for (int g=0; g<4; ++g) {
    f32x4 bv = *(const f32x4*)(bsum + g*128 + w*16 + lq*4);
#pragma unroll
    for (int nt=0; nt<4; ++nt) acc[g][nt] = bv;
  }
  __syncthreads();

#pragma unroll
  for (int kt=0; kt<4; ++kt) {
    const int bo = kt*32 + lq*8;
    f16x8 bx[4];
#pragma unroll
    for (int nt=0; nt<4; ++nt)
      bx[nt] = *(const f16x8*)(xF + (nt*16+ln16)*136 + bo);
#pragma unroll
    for (int g=0; g<4; ++g) {
      const int co = (g*128 + w*16 + ln16)*128 + kt*32 + lq*8;
      f16x8 ah = *(const f16x8*)(WIhi + co);
      f16x8 al = *(const f16x8*)(WIlo + co);
#pragma unroll
      for (int nt=0; nt<4; ++nt) {
        acc[g][nt] = __builtin_amdgcn_mfma_f32_16x16x32_f16(ah, bx[nt], acc[g][nt], 0,0,0);
        acc[g][nt] = __builtin_amdgcn_mfma_f32_16x16x32_f16(al, bx[nt], acc[g][nt], 0,0,0);
      }
    }
  }
  const int lbase = ((w>>1)*4 + lq)*32 + (w&1)*4;
#pragma unroll
  for (int nt=0; nt<4; ++nt) {
    unsigned short* rowp = GxH + (size_t)(rb + nt*16 + ln16)*512 + lbase;
#pragma unroll
    for (int g=0; g<4; ++g) {
      f32x4 v = acc[g][nt];
      u16x4 pk;
#pragma unroll
      for (int e=0; e<4; ++e)
        pk[e] = __half_as_ushort(__float2half_rn(v[e]));
      *(u16x4*)(rowp + g*8) = pk;
    }
  }
}

// ---------------- LSTM recurrence v3: fp16 operands, 16-node tile, 1 barrier/step ----------------
// 2048 blocks x 16 nodes, 4 waves (256 thr). Wave w owns cols w*32..w*32+31.
// h double-buffered in LDS as fp16 -> single barrier per step.
// Per step: gather 4x16B (permuted fp16 Gx) into gxq; recurrent Whh.h via
// fp16 hi/lo MFMA (2/tile, 64/wave/step) into zero-init racc; act = gx+racc.
__global__ __launch_bounds__(256) void lstm_seq_kernel(
    float* __restrict__ hL, const unsigned short* __restrict__ GxH,
    const int* __restrict__ nbr,
    const unsigned short* __restrict__ WHhi, const unsigned short* __restrict__ WHlo)
{
  __shared__ unsigned short hF[2*16*136];   // double-buffered fp16 h tile
  const int tid = threadIdx.x;
  const int w = tid >> 6;          // wave 0..3
  const int lane = tid & 63;
  const int ln16 = lane & 15;
  const int lq = lane >> 4;
  const int nb = blockIdx.x * 16;
  const int lbase = (w*4 + lq)*32;

  u16x8 gxq[4];         // [gate] packed fp16 (p0 e0..3 | p1 e0..3)
  f32x4 cst[2];         // [p]
#pragma unroll
  for (int p=0;p<2;++p)
#pragma unroll
    for (int e=0;e<4;++e) cst[p][e] = 0.0f;

  const int* nrow = nbr + (size_t)(nb + ln16)*DD;
  int gidx = nrow[0];

#pragma unroll 1
  for (int t=0; t<16; ++t) {
    // ---- (1) issue gathers (independent of MFMA chain) ----
    {
      const unsigned short* r0 = GxH + (size_t)gidx*512 + lbase;
#pragma unroll
      for (int g=0; g<4; ++g)
        gxq[g] = *(const u16x8*)(r0 + g*8);
    }
    if (t < 15) gidx = nrow[t+1];

    // ---- (2) recurrent term into zero-init racc ----
    f32x4 racc[4][2];
#pragma unroll
    for (int g=0;g<4;++g)
#pragma unroll
      for (int p=0;p<2;++p)
#pragma unroll
        for (int e=0;e<4;++e) racc[g][p][e] = 0.0f;
    if (t > 0) {
      const unsigned short* hRd = hF + ((t&1)^1)*16*136;
#pragma unroll
      for (int kt=0; kt<4; ++kt) {
        const int bo = kt*32 + lq*8;
        f16x8 bh = *(const f16x8*)(hRd + ln16*136 + bo);
#pragma unroll
        for (int g=0; g<4; ++g) {
#pragma unroll
          for (int p=0; p<2; ++p) {
            const int co = (g*128 + w*32 + p*16 + ln16)*128 + kt*32 + lq*8;
            f16x8 ah = *(const f16x8*)(WHhi + co);
            f16x8 al = *(const f16x8*)(WHlo + co);
            racc[g][p] = __builtin_amdgcn_mfma_f32_16x16x32_f16(ah, bh, racc[g][p], 0,0,0);
            racc[g][p] = __builtin_amdgcn_mfma_f32_16x16x32_f16(al, bh, racc[g][p], 0,0,0);
          }
        }
      }
    }

    // ---- (3) activations: pre = half2float(gx) + racc; write h(t) to buf[t&1] ----
    unsigned short* hWr = hF + (t&1)*16*136;
#pragma unroll
    for (int p=0; p<2; ++p) {
      float hv[4];
#pragma unroll
      for (int e=0; e<4; ++e) {
        float ig = fsig(__half2float(__ushort_as_half(gxq[0][p*4+e])) + racc[0][p][e]);
        float fg = fsig(__half2float(__ushort_as_half(gxq[1][p*4+e])) + racc[1][p][e]);
        float gg = ftanh(__half2float(__ushort_as_half(gxq[2][p*4+e])) + racc[2][p][e]);
        float og = fsig(__half2float(__ushort_as_half(gxq[3][p*4+e])) + racc[3][p][e]);
        float cc = fg*cst[p][e] + ig*gg;
        cst[p][e] = cc;
        hv[e] = og*ftanh(cc);
      }
      const int col0 = w*32 + p*16 + lq*4;
      if (t < 15) {
        u16x4 hw;
#pragma unroll
        for (int e=0; e<4; ++e) hw[e] = __half_as_ushort(__float2half_rn(hv[e]));
        *(u16x4*)(hWr + ln16*136 + col0) = hw;
      } else {
        *(float4*)(hL + (size_t)(nb + ln16)*128 + col0) =
            make_float4(hv[0], hv[1], hv[2], hv[3]);
      }
    }
    __syncthreads();   // h(t) visible; buf[(t+1)&1] safe to overwrite next step
  }
}

// ---------------- GGC scatter-add: a[dst] += m[src] (128 floats/edge) ----------------
__global__ void scatter_add_kernel(float* __restrict__ a, const float* __restrict__ m,
                                   const int* __restrict__ src, const int* __restrict__ dst) {
  int wid = (blockIdx.x*256 + threadIdx.x) >> 6;
  int lane = threadIdx.x & 63;
  int s = src[wid], d = dst[wid];
  const float* mr = m + (size_t)s*128;
  float* ar = a + (size_t)d*128;
  atomicAdd(ar + lane, mr[lane]);
  atomicAdd(ar + 64 + lane, mr[64 + lane]);
}

// ---------------- GRU pointwise ----------------
__global__ void gru_update_kernel(float* __restrict__ hh, const float* __restrict__ gi,
                                  const float* __restrict__ gh) {
  int idx = blockIdx.x*256 + threadIdx.x;
  int n = idx >> 7, j = idx & 127;
  const float* gin = gi + (size_t)n*384;
  const float* ghn = gh + (size_t)n*384;
  float r  = fsig(gin[j] + ghn[j]);
  float z  = fsig(gin[128+j] + ghn[128+j]);
  float nn2 = ftanh(gin[256+j] + r*ghn[256+j]);
  float h = hh[idx];
  hh[idx] = (1.0f - z)*nn2 + z*h;
}

// ---------------- LayerNorm (+optional residual add) + leaky relu ----------------
__global__ void ln_lrelu_kernel(float* __restrict__ out, const float* __restrict__ x,
                                const float* __restrict__ add,
                                const float* __restrict__ g, const float* __restrict__ b) {
  int n = blockIdx.x, j = threadIdx.x;   // 128 threads
  size_t base = (size_t)n*128;
  float v = x[base+j];
  if (add) v += add[base+j];
  __shared__ float sh[4];
  float s = v;
#pragma unroll
  for (int m=32; m>=1; m>>=1) s += __shfl_xor(s, m, 64);
  if ((j&63)==0) sh[j>>6] = s;
  __syncthreads();
  float mean = (sh[0]+sh[1]) * 0.0078125f;
  float d = v - mean;
  float q = d*d;
#pragma unroll
  for (int m=32; m>=1; m>>=1) q += __shfl_xor(q, m, 64);
  if ((j&63)==0) sh[2+(j>>6)] = q;
  __syncthreads();
  float var = (sh[2]+sh[3]) * 0.0078125f;
  float y = d * rsqrtf(var + 1e-5f) * g[j] + b[j];
  out[base+j] = (y >= 0.0f) ? y : 0.01f*y;
}

// ---------------- segment mean (contiguous 128-node segments) ----------------
__global__ void segmean_kernel(float* __restrict__ out, const float* __restrict__ x,
                               const float* __restrict__ y) {
  int b = blockIdx.x, j = threadIdx.x;   // 128 threads, 256 blocks
  float s = 0.0f;
  for (int r=0; r<128; ++r) {
    size_t n = (size_t)(b*128 + r)*128 + j;
    s += x[n];
    if (y) s += y[n];
  }
  out[(size_t)b*128 + j] = s * 0.0078125f;
}

// ---------------- classifier head ----------------
__global__ void cls_kernel(float* __restrict__ out, const float* __restrict__ h2,
                           const float* __restrict__ Wc, const float* __restrict__ bc) {
  int gid = blockIdx.x*256 + threadIdx.x;
  if (gid >= BB*10) return;
  int mrow = gid/10, c = gid - mrow*10;
  const float* arow = h2 + (size_t)mrow*128;
  const float* wrow = Wc + (size_t)c*128;
  float s = bc[c];
  for (int k=0;k<128;++k) s += arow[k]*wrow[k];
  out[gid] = s;
}

__global__ void bail_kernel(float* out, float v) {
  if (threadIdx.x==0 && blockIdx.x==0) out[0] = v;
}

// ---------------- host orchestration ----------------
extern "C" void kernel_launch(void* const* d_in, const int* in_sizes, int n_in,
                              void* d_out, int out_size, void* d_ws, size_t ws_size,
                              hipStream_t stream)
{
  const int* act_ids  = (const int*)d_in[0];
  const int* dur_ids  = (const int*)d_in[1];
  const int* act2_ids = (const int*)d_in[2];
  const int* nbr_a2d  = (const int*)d_in[3];
  const int* nbr_d2a  = (const int*)d_in[4];
  const int* src2     = (const int*)d_in[5];
  const int* dst2     = (const int*)d_in[6];
  const float* emb_act     = (const float*)d_in[8];
  const float* emb_dur     = (const float*)d_in[9];
  const float* emb_act2    = (const float*)d_in[10];
  const float* transform_W = (const float*)d_in[11];
  const float* transform_b = (const float*)d_in[12];
  const float* ggc_W   = (const float*)d_in[13];
  const float* ggc_b   = (const float*)d_in[14];
  const float* gru_Wih = (const float*)d_in[15];
  const float* gru_Whh = (const float*)d_in[16];
  const float* gru_bih = (const float*)d_in[17];
  const float* gru_bhh = (const float*)d_in[18];
  const float* hn_g    = (const float*)d_in[19];
  const float* hn_b    = (const float*)d_in[20];
  const float* lstm_Wih = (const float*)d_in[21];
  const float* lstm_Whh = (const float*)d_in[22];
  const float* lstm_bih = (const float*)d_in[23];
  const float* lstm_bhh = (const float*)d_in[24];
  const float* fcs_W = (const float*)d_in[25];
  const float* fcs_b = (const float*)d_in[26];
  const float* fcn_W = (const float*)d_in[27];
  const float* fcn_b = (const float*)d_in[28];
  const float* n1_g = (const float*)d_in[29];
  const float* n1_b = (const float*)d_in[30];
  const float* n3_g = (const float*)d_in[31];
  const float* n3_b = (const float*)d_in[32];
  const float* mh_W1 = (const float*)d_in[33];
  const float* mh_b1 = (const float*)d_in[34];
  const float* mh_W2 = (const float*)d_in[35];
  const float* mh_b2 = (const float*)d_in[36];
  const float* mo_W1 = (const float*)d_in[37];
  const float* mo_b1 = (const float*)d_in[38];
  const float* mo_W2 = (const float*)d_in[39];
  const float* mo_b2 = (const float*)d_in[40];
  const float* mlp_W1 = (const float*)d_in[41];
  const float* mlp_b1 = (const float*)d_in[42];
  const float* mlp_W2 = (const float*)d_in[43];
  const float* mlp_b2 = (const float*)d_in[44];
  const float* cls_W = (const float*)d_in[45];
  const float* cls_b = (const float*)d_in[46];

  float* ws = (float*)d_ws;
  float* ha   = ws;
  float* hd   = ws + (size_t)NF;
  float* hg2  = ws + 2*(size_t)NF;
  float* res  = ws + 3*(size_t)NF;
  float* hh   = ws + 4*(size_t)NF;
  float* SCR  = ws + 5*(size_t)NF;
  float* mb   = SCR;
  float* abuf = SCR + (size_t)NF;
  float* gi   = SCR + 2*(size_t)NF;
  float* gh   = SCR + 5*(size_t)NF;
  float* hnf  = mb;
  float* Gx   = SCR;                       // fp16 [N][512]
  float* hLb  = SCR + 8*(size_t)NF;
  float* SMALL = ws + 15*(size_t)NF;
  float* hg2m = SMALL;
  float* hgm  = SMALL + 32768;
  float* o1b  = SMALL + 65536;
  float* o2b  = SMALL + 98304;
  float* t1b  = SMALL + 131072;
  float* t2b  = SMALL + 163840;
  float* h1b  = SMALL + 196608;
  float* h2b  = SMALL + 262144;
  float* bsum = SMALL + 294912;
  float* WTb  = SMALL + 296960;
  const size_t NEED_BYTES = (size_t)(15*(size_t)NF + 296960 + 1032192) * 4;
  if (ws_size < NEED_BYTES) {
    hipMemsetAsync(d_out, 0, (size_t)out_size*sizeof(float), stream);
    bail_kernel<<<1,64,0,stream>>>((float*)d_out, (float)ws_size);
    return;
  }
  float* na = hg2;
  float* nd = res;
  unsigned short* GxH = (unsigned short*)Gx;

  const int O_TRANSFORM = 0;
  const int O_GGC      = 32768;
  const int O_GRUWIH   = 49152;
  const int O_GRUWHH   = 98304;
  const int O_SPLIT    = 147456;
  const int O_FCS      = 671744;
  const int O_FCN      = 737280;
  const int O_MH1      = 802816;
  const int O_MH2      = 819200;
  const int O_MO1      = 835584;
  const int O_MO2      = 851968;
  const int O_MLP1     = 868352;
  const int O_MLP2     = 999424;

  unsigned short* SPL = (unsigned short*)(WTb + O_SPLIT);
  unsigned short* WIhi = SPL;
  unsigned short* WIlo = SPL + 4*65536;
  unsigned short* WHhi = SPL + 8*65536;
  unsigned short* WHlo = SPL + 12*65536;

  TDescArr da;
  int di = 0;
  auto addT = [&](const float* s, float* d, int R, int C){ da.d[di].src=s; da.d[di].dst=d; da.d[di].R=R; da.d[di].C=C; ++di; };
  addT(transform_W, WTb + O_TRANSFORM, 128, 256);
  addT(ggc_W,   WTb + O_GGC,    128, 128);
  addT(gru_Wih, WTb + O_GRUWIH, 384, 128);
  addT(gru_Whh, WTb + O_GRUWHH, 384, 128);
  for (int i=0;i<4;++i) addT(fcs_W + (size_t)i*16384, WTb + O_FCS + i*16384, 128, 128);
  for (int i=0;i<4;++i) addT(fcn_W + (size_t)i*16384, WTb + O_FCN + i*16384, 128, 128);
  addT(mh_W1, WTb + O_MH1, 128, 128);
  addT(mh_W2, WTb + O_MH2, 128, 128);
  addT(mo_W1, WTb + O_MO1, 128, 128);
  addT(mo_W2, WTb + O_MO2, 128, 128);
  addT(mlp_W1, WTb + O_MLP1, 256, 512);
  addT(mlp_W2, WTb + O_MLP2, 128, 256);
  transpose_many<<<dim3(512, di), 256, 0, stream>>>(da);
  bias_sum_kernel<<<8, 256, 0, stream>>>(lstm_bih, lstm_bhh, bsum);
  wsplit16_kernel<<<(4*512*128)/256, 256, 0, stream>>>(lstm_Wih, WIhi, WIlo);
  wsplit16_kernel<<<(4*512*128)/256, 256, 0, stream>>>(lstm_Whh, WHhi, WHlo);

  auto smemK = [](int K, int BN){ return (size_t)(32*(K+4) + 16*BN)*4; };
  const int gN = NN/32;
  const int gB = BB/32;

  embed3_kernel<<<dim3(NF/256, 3), 256, 0, stream>>>(act_ids, dur_ids, act2_ids,
      emb_act, emb_dur, emb_act2, ha, hd, hg2);
  gemm_nt<128,0><<<gN, 256, smemK(256,128), stream>>>(hg2, hd, nullptr, nullptr, 128,
      WTb + O_TRANSFORM, transform_b, res, 256, 0);
  hipMemcpyAsync(hh, res, (size_t)NF*4, hipMemcpyDeviceToDevice, stream);

  for (int it=0; it<2; ++it) {
    gemm_nt<128,0><<<gN, 256, smemK(128,128), stream>>>(hh, nullptr, nullptr, nullptr, 128,
        WTb + O_GGC, ggc_b, mb, 128, 0);
    hipMemsetAsync(abuf, 0, (size_t)NF*4, stream);
    scatter_add_kernel<<<E2N/4, 256, 0, stream>>>(abuf, mb, src2, dst2);
    gemm_nt<384,0><<<gN, 256, smemK(128,384), stream>>>(abuf, nullptr, nullptr, nullptr, 128,
        WTb + O_GRUWIH, gru_bih, gi, 128, 0);
    gemm_nt<384,0><<<gN, 256, smemK(128,384), stream>>>(hh, nullptr, nullptr, nullptr, 128,
        WTb + O_GRUWHH, gru_bhh, gh, 128, 0);
    gru_update_kernel<<<NF/256, 256, 0, stream>>>(hh, gi, gh);
  }
  ln_lrelu_kernel<<<NN, 128, 0, stream>>>(hnf, hh, res, hn_g, hn_b);
  segmean_kernel<<<BB, 128, 0, stream>>>(hg2m, hnf, nullptr);

  for (int l=0; l<2; ++l) {
    const int i0 = l*2 + 0, i1 = l*2 + 1;
    gx_kernel<<<512, 512, 0, stream>>>(GxH, ha,
        WIhi + i0*65536, WIlo + i0*65536, bsum + i0*512);
    lstm_seq_kernel<<<NN/16, 256, 0, stream>>>(hLb, GxH, nbr_a2d,
        WHhi + i0*65536, WHlo + i0*65536);
    gx_kernel<<<512, 512, 0, stream>>>(GxH, hd,
        WIhi + i1*65536, WIlo + i1*65536, bsum + i1*512);
    lstm_seq_kernel<<<NN/16, 256, 0, stream>>>(hLb + (size_t)NN*128, GxH, nbr_d2a,
        WHhi + i1*65536, WHlo + i1*65536);

    gemm_nt<128,0><<<gN, 256, smemK(128,128), stream>>>(hd, nullptr, nullptr, nullptr, 128,
        WTb + O_FCS + i0*16384, fcs_b + i0*128, nd, 128, 0);
    gemm_nt<128,0><<<gN, 256, smemK(128,128), stream>>>(hLb, nullptr, nullptr, nullptr, 128,
        WTb + O_FCN + i0*16384, fcn_b + i0*128, nd, 128, 1);
    gemm_nt<128,0><<<gN, 256, smemK(128,128), stream>>>(ha, nullptr, nullptr, nullptr, 128,
        WTb + O_FCS + i1*16384, fcs_b + i1*128, na, 128, 0);
    gemm_nt<128,0><<<gN, 256, smemK(128,128), stream>>>(hLb + (size_t)NN*128, nullptr, nullptr, nullptr, 128,
        WTb + O_FCN + i1*16384, fcn_b + i1*128, na, 128, 1);
    ln_lrelu_kernel<<<NN, 128, 0, stream>>>(na, na, nullptr, n1_g + i0*128, n1_b + i0*128);
    ln_lrelu_kernel<<<NN, 128, 0, stream>>>(nd, nd, nullptr, n1_g + i1*128, n1_b + i1*128);
    ln_lrelu_kernel<<<NN, 128, 0, stream>>>(ha, ha, na, n3_g + i0*128, n3_b + i0*128);
    ln_lrelu_kernel<<<NN, 128, 0, stream>>>(hd, hd, nd, n3_g + i1*128, n3_b + i1*128);
  }
  segmean_kernel<<<BB, 128, 0, stream>>>(hgm, ha, hd);

  gemm_nt<128,1><<<gB, 256, smemK(128,128), stream>>>(hg2m, nullptr, nullptr, nullptr, 128,
      WTb + O_MO1, mo_b1, t1b, 128, 0);
  gemm_nt<128,1><<<gB, 256, smemK(128,128), stream>>>(t1b, nullptr, nullptr, nullptr, 128,
      WTb + O_MO2, mo_b2, o1b, 128, 0);
  gemm_nt<128,1><<<gB, 256, smemK(128,128), stream>>>(hgm, nullptr, nullptr, nullptr, 128,
      WTb + O_MH1, mh_b1, t2b, 128, 0);
  gemm_nt<128,1><<<gB, 256, smemK(128,128), stream>>>(t2b, nullptr, nullptr, nullptr, 128,
      WTb + O_MH2, mh_b2, o2b, 128, 0);
  gemm_nt<256,0><<<gB, 256, smemK(256,256), stream>>>(o1b, hg2m, nullptr, nullptr, 128,
      WTb + O_MLP1, nullptr, h1b, 256, 0);
  gemm_nt<256,1><<<gB, 256, smemK(256,256), stream>>>(o2b, hgm, nullptr, nullptr, 128,
      WTb + O_MLP1 + 256*256, mlp_b1, h1b, 256, 1);
  gemm_nt<128,1><<<gB, 256, smemK(256,128), stream>>>(h1b, h1b + 128, nullptr, nullptr, 256,
      WTb + O_MLP2, mlp_b2, h2b, 256, 0);
  cls_kernel<<<10, 256, 0, stream>>>((float*)d_out, h2b, cls_W, cls_b);
}

// Round 12
// 3146.320 us; speedup vs baseline: 1.6976x; 1.6976x over previous
//
#include <hip/hip_runtime.h>
#include <hip/hip_fp16.h>
#include <math.h>

#define NN 32768
#define HH 128
#define DD 16
#define BB 256
#define E2N (NN*DD)
#define NF (NN*HH)

typedef __attribute__((ext_vector_type(4))) float f32x4;
typedef __attribute__((ext_vector_type(4))) unsigned short u16x4;
typedef __attribute__((ext_vector_type(8))) unsigned short u16x8;
typedef _Float16 f16x8 __attribute__((ext_vector_type(8)));

__device__ __forceinline__ float fsig(float x) { return 1.0f/(1.0f + __expf(-x)); }
__device__ __forceinline__ float ftanh(float x) {
  float cx = fminf(fmaxf(x, -15.0f), 15.0f);
  float e = __expf(2.0f*cx);
  return 1.0f - 2.0f/(e + 1.0f);
}

// ---------------- transpose prep (weights -> [K][Nout] layout) ----------------
struct TDesc { const float* src; float* dst; int R; int C; };
struct TDescArr { TDesc d[26]; };

__global__ void transpose_many(TDescArr da) {
  TDesc t = da.d[blockIdx.y];
  int idx = blockIdx.x*256 + threadIdx.x;
  if (idx < t.R*t.C) {
    int r = idx / t.C, c = idx - r*t.C;
    t.dst[(size_t)c*t.R + r] = t.src[idx];
  }
}

__global__ void bias_sum_kernel(const float* __restrict__ bih, const float* __restrict__ bhh,
                                float* __restrict__ bsum) {
  int i = blockIdx.x*256 + threadIdx.x;
  if (i < 2048) bsum[i] = bih[i] + bhh[i];
}

// fp32 -> fp16 convert (vectorized, 4/thread)
__global__ void f32to16_kernel(const float* __restrict__ in, unsigned short* __restrict__ out) {
  int base = (blockIdx.x*256 + threadIdx.x) * 4;
  float4 v = *(const float4*)(in + base);
  u16x4 p;
  p[0] = __half_as_ushort(__float2half_rn(v.x));
  p[1] = __half_as_ushort(__float2half_rn(v.y));
  p[2] = __half_as_ushort(__float2half_rn(v.z));
  p[3] = __half_as_ushort(__float2half_rn(v.w));
  *(u16x4*)(out + base) = p;
}

// ---------------- embeddings ----------------
__global__ void embed3_kernel(const int* __restrict__ a_ids, const int* __restrict__ d_ids,
                              const int* __restrict__ a2_ids,
                              const float* __restrict__ ea, const float* __restrict__ ed,
                              const float* __restrict__ ea2,
                              float* __restrict__ ha, float* __restrict__ hd,
                              float* __restrict__ hg2) {
  int idx = blockIdx.x*256 + threadIdx.x;
  int n = idx >> 7, j = idx & 127;
  int w = blockIdx.y;
  if (w == 0)      ha[idx]  = ea[(size_t)a_ids[n]*128 + j];
  else if (w == 1) hd[idx]  = ed[(size_t)d_ids[n]*128 + j];
  else             hg2[idx] = ea2[(size_t)a2_ids[n]*128 + j];
}

// ---------------- generic GEMM: C = act(A @ W^T + bias + beta*C) ----------------
template<int BN, int ACT>
__global__ __launch_bounds__(256) void gemm_nt(
    const float* __restrict__ A0, const float* __restrict__ A1,
    const float* __restrict__ A2, const float* __restrict__ A3,
    int lda, const float* __restrict__ WT, const float* __restrict__ bias,
    float* __restrict__ C, int K, int beta)
{
  extern __shared__ float sm[];
  const int KP = K + 4;
  float* At = sm;             // [32][KP]
  float* Bc = sm + 32*KP;     // [16][BN]
  const int tid = threadIdx.x;
  const int m0 = blockIdx.x*32;
  const int ng = tid >> 5, cg = tid & 31;
  const int n0 = ng*4, c4 = cg*4;
  constexpr int G = BN/128;
  float acc[G][4][4];
#pragma unroll
  for (int g=0; g<G; ++g)
#pragma unroll
    for (int i=0;i<4;++i)
#pragma unroll
      for (int e=0;e<4;++e) acc[g][i][e] = 0.0f;

  const int nf4 = K >> 2;
  for (int idx = tid; idx < 32*nf4; idx += 256) {
    int row = idx / nf4;
    int kk = (idx - row*nf4) << 2;
    const float* Ap = (kk < 128) ? A0 : (kk < 256) ? A1 : (kk < 384) ? A2 : A3;
    float4 v = *(const float4*)(Ap + (size_t)(m0+row)*lda + (kk & 127));
    *(float4*)(At + row*KP + kk) = v;
  }
  const int nchunk = K >> 4;
  for (int kc = 0; kc < nchunk; ++kc) {
    __syncthreads();
    for (int idx = tid; idx < 16*(BN/4); idx += 256) {
      int kk = idx / (BN/4);
      int jq = idx - kk*(BN/4);
      *(float4*)(Bc + kk*BN + jq*4) = *(const float4*)(WT + (size_t)(kc*16+kk)*BN + jq*4);
    }
    __syncthreads();
    for (int k=0;k<16;++k) {
      const int kk = kc*16 + k;
      float av[4];
#pragma unroll
      for (int i=0;i<4;++i) av[i] = At[(n0+i)*KP + kk];
#pragma unroll
      for (int g=0; g<G; ++g) {
        float4 bv = *(const float4*)(Bc + k*BN + g*128 + c4);
        float bb[4] = {bv.x, bv.y, bv.z, bv.w};
#pragma unroll
        for (int i=0;i<4;++i)
#pragma unroll
          for (int e=0;e<4;++e)
            acc[g][i][e] += av[i]*bb[e];
      }
    }
  }
#pragma unroll
  for (int g=0; g<G; ++g) {
#pragma unroll
    for (int i=0;i<4;++i) {
      float* dst = C + (size_t)(m0+n0+i)*BN + g*128 + c4;
      float o[4];
#pragma unroll
      for (int e=0;e<4;++e) o[e] = acc[g][i][e];
      if (bias) {
#pragma unroll
        for (int e=0;e<4;++e) o[e] += bias[g*128 + c4 + e];
      }
      if (beta) {
        float4 p = *(const float4*)dst;
        o[0]+=p.x; o[1]+=p.y; o[2]+=p.z; o[3]+=p.w;
      }
      if (ACT==1) {
#pragma unroll
        for (int e=0;e<4;++e) o[e] = fmaxf(o[e], 0.0f);
      }
      *(float4*)dst = make_float4(o[0],o[1],o[2],o[3]);
    }
  }
}

// ---------------- fused LSTM v3: fp16 fs gather (256B rows), fp16-single weights ----------------
// 512 thr (8 waves), 64 nodes/block, grid N/64 per direction. Wave w owns
// outcols w*16..w*16+15 per gate. Per step: stage gathered x(t) regs->LDS,
// one barrier, pass1 = WI.x (64 MFMA), issue gather t+1, pass2 = WH.h(t-1)
// (64 MFMA), activations -> h LDS (dbuf). Weight stream 256KB/block/step from
// L2; gather 128MB/dispatch from ~L2-resident 8MB fs16 table.
__global__ __launch_bounds__(512) void lstm_fused3(
    float* __restrict__ hL, const unsigned short* __restrict__ fs16,
    const int* __restrict__ nbr,
    const unsigned short* __restrict__ WI, const unsigned short* __restrict__ WH,
    const float* __restrict__ bsum)
{
  extern __shared__ unsigned short smem16[];
  unsigned short* xb0 = smem16;            // [64][132]
  unsigned short* xb1 = smem16 + 8448;
  unsigned short* hb0 = smem16 + 16896;
  unsigned short* hb1 = smem16 + 25344;
  const int tid = threadIdx.x;
  const int w = tid >> 6;          // wave 0..7
  const int lane = tid & 63;
  const int ln16 = lane & 15;
  const int lq = lane >> 4;
  const int nb = blockIdx.x * 64;

  // gather duty: 8 threads/row, 16 halfs each
  const int gr = tid >> 3;
  const int gc = (tid & 7) * 16;
  const int* nrow = nbr + (size_t)(nb + gr)*DD;

  f32x4 bias[4];
#pragma unroll
  for (int g=0; g<4; ++g)
    bias[g] = *(const f32x4*)(bsum + g*128 + w*16 + lq*4);

  f32x4 cst[4];
#pragma unroll
  for (int nt=0; nt<4; ++nt)
#pragma unroll
    for (int e=0; e<4; ++e) cst[nt][e] = 0.0f;

  // prologue: gather x(0)
  u16x8 xg0, xg1;
  {
    int gidx = nrow[0];
    const unsigned short* src = fs16 + (size_t)gidx*128 + gc;
    xg0 = *(const u16x8*)(src);
    xg1 = *(const u16x8*)(src + 8);
  }
  int gnext = nrow[1];

#pragma unroll 1
  for (int t=0; t<16; ++t) {
    // phase 1: write x(t) regs -> LDS (dbuf)
    {
      unsigned short* d = ((t&1) ? xb1 : xb0) + gr*132 + gc;
      *(u16x8*)d = xg0;
      *(u16x8*)(d+8) = xg1;
    }
    __syncthreads();   // x(t) visible; h(t-1) writes visible

    f32x4 racc[4][4];   // [gate][nt]
#pragma unroll
    for (int g=0; g<4; ++g)
#pragma unroll
      for (int nt=0; nt<4; ++nt)
        racc[g][nt] = bias[g];

    // pass 1: WI . x(t)
    {
      const unsigned short* xR = (t&1) ? xb1 : xb0;
#pragma unroll
      for (int kt=0; kt<4; ++kt) {
        const int bo = kt*32 + lq*8;
        f16x8 bx[4];
#pragma unroll
        for (int nt=0; nt<4; ++nt)
          bx[nt] = *(const f16x8*)(xR + (nt*16+ln16)*132 + bo);
#pragma unroll
        for (int g=0; g<4; ++g) {
          f16x8 aI = *(const f16x8*)(WI + (size_t)(g*128 + w*16 + ln16)*128 + kt*32 + lq*8);
#pragma unroll
          for (int nt=0; nt<4; ++nt)
            racc[g][nt] = __builtin_amdgcn_mfma_f32_16x16x32_f16(aI, bx[nt], racc[g][nt], 0,0,0);
        }
      }
    }
    // issue gather for t+1 (hidden under pass 2)
    if (t < 15) {
      const unsigned short* src = fs16 + (size_t)gnext*128 + gc;
      xg0 = *(const u16x8*)(src);
      xg1 = *(const u16x8*)(src + 8);
      if (t < 14) gnext = nrow[t+2];
    }
    // pass 2: WH . h(t-1)
    if (t > 0) {
      const unsigned short* hR = (t&1) ? hb0 : hb1;   // h(t-1) is in buf (t-1)&1
#pragma unroll
      for (int kt=0; kt<4; ++kt) {
        const int bo = kt*32 + lq*8;
        f16x8 bh[4];
#pragma unroll
        for (int nt=0; nt<4; ++nt)
          bh[nt] = *(const f16x8*)(hR + (nt*16+ln16)*132 + bo);
#pragma unroll
        for (int g=0; g<4; ++g) {
          f16x8 aH = *(const f16x8*)(WH + (size_t)(g*128 + w*16 + ln16)*128 + kt*32 + lq*8);
#pragma unroll
          for (int nt=0; nt<4; ++nt)
            racc[g][nt] = __builtin_amdgcn_mfma_f32_16x16x32_f16(aH, bh[nt], racc[g][nt], 0,0,0);
        }
      }
    }

    // activations + cell update; write h(t) to buf t&1
    unsigned short* hW = (t&1) ? hb1 : hb0;
#pragma unroll
    for (int nt=0; nt<4; ++nt) {
      float hv[4];
#pragma unroll
      for (int e=0; e<4; ++e) {
        float ig = fsig(racc[0][nt][e]);
        float fg = fsig(racc[1][nt][e]);
        float gg = ftanh(racc[2][nt][e]);
        float og = fsig(racc[3][nt][e]);
        float cc = fg*cst[nt][e] + ig*gg;
        cst[nt][e] = cc;
        hv[e] = og*ftanh(cc);
      }
      const int node = nt*16 + ln16;
      const int col = w*16 + lq*4;
      if (t < 15) {
        u16x4 hw;
#pragma unroll
        for (int e=0; e<4; ++e) hw[e] = __half_as_ushort(__float2half_rn(hv[e]));
        *(u16x4*)(hW + node*132 + col) = hw;
      } else {
        *(float4*)(hL + (size_t)(nb + node)*128 + col) =
            make_float4(hv[0], hv[1], hv[2], hv[3]);
      }
    }
  }
}

// ---------------- GGC scatter-add: a[dst] += m[src] (128 floats/edge) ----------------
__global__ void scatter_add_kernel(float* __restrict__ a, const float* __restrict__ m,
                                   const int* __restrict__ src, const int* __restrict__ dst) {
  int wid = (blockIdx.x*256 + threadIdx.x) >> 6;
  int lane = threadIdx.x & 63;
  int s = src[wid], d = dst[wid];
  const float* mr = m + (size_t)s*128;
  float* ar = a + (size_t)d*128;
  atomicAdd(ar + lane, mr[lane]);
  atomicAdd(ar + 64 + lane, mr[64 + lane]);
}

// ---------------- GRU pointwise ----------------
__global__ void gru_update_kernel(float* __restrict__ hh, const float* __restrict__ gi,
                                  const float* __restrict__ gh) {
  int idx = blockIdx.x*256 + threadIdx.x;
  int n = idx >> 7, j = idx & 127;
  const float* gin = gi + (size_t)n*384;
  const float* ghn = gh + (size_t)n*384;
  float r  = fsig(gin[j] + ghn[j]);
  float z  = fsig(gin[128+j] + ghn[128+j]);
  float nn2 = ftanh(gin[256+j] + r*ghn[256+j]);
  float h = hh[idx];
  hh[idx] = (1.0f - z)*nn2 + z*h;
}

// ---------------- LayerNorm (+optional residual add) + leaky relu ----------------
__global__ void ln_lrelu_kernel(float* __restrict__ out, const float* __restrict__ x,
                                const float* __restrict__ add,
                                const float* __restrict__ g, const float* __restrict__ b) {
  int n = blockIdx.x, j = threadIdx.x;   // 128 threads
  size_t base = (size_t)n*128;
  float v = x[base+j];
  if (add) v += add[base+j];
  __shared__ float sh[4];
  float s = v;
#pragma unroll
  for (int m=32; m>=1; m>>=1) s += __shfl_xor(s, m, 64);
  if ((j&63)==0) sh[j>>6] = s;
  __syncthreads();
  float mean = (sh[0]+sh[1]) * 0.0078125f;
  float d = v - mean;
  float q = d*d;
#pragma unroll
  for (int m=32; m>=1; m>>=1) q += __shfl_xor(q, m, 64);
  if ((j&63)==0) sh[2+(j>>6)] = q;
  __syncthreads();
  float var = (sh[2]+sh[3]) * 0.0078125f;
  float y = d * rsqrtf(var + 1e-5f) * g[j] + b[j];
  out[base+j] = (y >= 0.0f) ? y : 0.01f*y;
}

// ---------------- segment mean (contiguous 128-node segments) ----------------
__global__ void segmean_kernel(float* __restrict__ out, const float* __restrict__ x,
                               const float* __restrict__ y) {
  int b = blockIdx.x, j = threadIdx.x;   // 128 threads, 256 blocks
  float s = 0.0f;
  for (int r=0; r<128; ++r) {
    size_t n = (size_t)(b*128 + r)*128 + j;
    s += x[n];
    if (y) s += y[n];
  }
  out[(size_t)b*128 + j] = s * 0.0078125f;
}

// ---------------- classifier head ----------------
__global__ void cls_kernel(float* __restrict__ out, const float* __restrict__ h2,
                           const float* __restrict__ Wc, const float* __restrict__ bc) {
  int gid = blockIdx.x*256 + threadIdx.x;
  if (gid >= BB*10) return;
  int mrow = gid/10, c = gid - mrow*10;
  const float* arow = h2 + (size_t)mrow*128;
  const float* wrow = Wc + (size_t)c*128;
  float s = bc[c];
  for (int k=0;k<128;++k) s += arow[k]*wrow[k];
  out[gid] = s;
}

__global__ void bail_kernel(float* out, float v) {
  if (threadIdx.x==0 && blockIdx.x==0) out[0] = v;
}

// ---------------- host orchestration ----------------
extern "C" void kernel_launch(void* const* d_in, const int* in_sizes, int n_in,
                              void* d_out, int out_size, void* d_ws, size_t ws_size,
                              hipStream_t stream)
{
  const int* act_ids  = (const int*)d_in[0];
  const int* dur_ids  = (const int*)d_in[1];
  const int* act2_ids = (const int*)d_in[2];
  const int* nbr_a2d  = (const int*)d_in[3];
  const int* nbr_d2a  = (const int*)d_in[4];
  const int* src2     = (const int*)d_in[5];
  const int* dst2     = (const int*)d_in[6];
  const float* emb_act     = (const float*)d_in[8];
  const float* emb_dur     = (const float*)d_in[9];
  const float* emb_act2    = (const float*)d_in[10];
  const float* transform_W = (const float*)d_in[11];
  const float* transform_b = (const float*)d_in[12];
  const float* ggc_W   = (const float*)d_in[13];
  const float* ggc_b   = (const float*)d_in[14];
  const float* gru_Wih = (const float*)d_in[15];
  const float* gru_Whh = (const float*)d_in[16];
  const float* gru_bih = (const float*)d_in[17];
  const float* gru_bhh = (const float*)d_in[18];
  const float* hn_g    = (const float*)d_in[19];
  const float* hn_b    = (const float*)d_in[20];
  const float* lstm_Wih = (const float*)d_in[21];
  const float* lstm_Whh = (const float*)d_in[22];
  const float* lstm_bih = (const float*)d_in[23];
  const float* lstm_bhh = (const float*)d_in[24];
  const float* fcs_W = (const float*)d_in[25];
  const float* fcs_b = (const float*)d_in[26];
  const float* fcn_W = (const float*)d_in[27];
  const float* fcn_b = (const float*)d_in[28];
  const float* n1_g = (const float*)d_in[29];
  const float* n1_b = (const float*)d_in[30];
  const float* n3_g = (const float*)d_in[31];
  const float* n3_b = (const float*)d_in[32];
  const float* mh_W1 = (const float*)d_in[33];
  const float* mh_b1 = (const float*)d_in[34];
  const float* mh_W2 = (const float*)d_in[35];
  const float* mh_b2 = (const float*)d_in[36];
  const float* mo_W1 = (const float*)d_in[37];
  const float* mo_b1 = (const float*)d_in[38];
  const float* mo_W2 = (const float*)d_in[39];
  const float* mo_b2 = (const float*)d_in[40];
  const float* mlp_W1 = (const float*)d_in[41];
  const float* mlp_b1 = (const float*)d_in[42];
  const float* mlp_W2 = (const float*)d_in[43];
  const float* mlp_b2 = (const float*)d_in[44];
  const float* cls_W = (const float*)d_in[45];
  const float* cls_b = (const float*)d_in[46];

  float* ws = (float*)d_ws;
  float* ha   = ws;
  float* hd   = ws + (size_t)NF;
  float* hg2  = ws + 2*(size_t)NF;
  float* res  = ws + 3*(size_t)NF;
  float* hh   = ws + 4*(size_t)NF;
  float* SCR  = ws + 5*(size_t)NF;
  float* mb   = SCR;
  float* abuf = SCR + (size_t)NF;
  float* gi   = SCR + 2*(size_t)NF;
  float* gh   = SCR + 5*(size_t)NF;
  float* hnf  = mb;
  float* hLb  = SCR + 8*(size_t)NF;
  float* SMALL = ws + 15*(size_t)NF;
  float* hg2m = SMALL;
  float* hgm  = SMALL + 32768;
  float* o1b  = SMALL + 65536;
  float* o2b  = SMALL + 98304;
  float* t1b  = SMALL + 131072;
  float* t2b  = SMALL + 163840;
  float* h1b  = SMALL + 196608;
  float* h2b  = SMALL + 262144;
  float* bsum = SMALL + 294912;
  float* WTb  = SMALL + 296960;
  const size_t NEED_BYTES = (size_t)(15*(size_t)NF + 296960 + 1032192) * 4;
  if (ws_size < NEED_BYTES) {
    hipMemsetAsync(d_out, 0, (size_t)out_size*sizeof(float), stream);
    bail_kernel<<<1,64,0,stream>>>((float*)d_out, (float)ws_size);
    return;
  }
  float* na = hg2;
  float* nd = res;
  // fp16 fs tables in the (free) SCR front region
  unsigned short* fs16a = (unsigned short*)SCR;                     // NF halfs
  unsigned short* fs16d = (unsigned short*)(SCR + (size_t)NF/2);    // NF halfs

  const int O_TRANSFORM = 0;
  const int O_GGC      = 32768;
  const int O_GRUWIH   = 49152;
  const int O_GRUWHH   = 98304;
  const int O_SPLIT    = 147456;
  const int O_FCS      = 671744;
  const int O_FCN      = 737280;
  const int O_MH1      = 802816;
  const int O_MH2      = 819200;
  const int O_MO1      = 835584;
  const int O_MO2      = 851968;
  const int O_MLP1     = 868352;
  const int O_MLP2     = 999424;

  // fp16-single weights: WI16 (4 mats) then WH16 (4 mats), 65536 halfs each
  unsigned short* WI16 = (unsigned short*)(WTb + O_SPLIT);
  unsigned short* WH16 = WI16 + 4*65536;

  TDescArr da;
  int di = 0;
  auto addT = [&](const float* s, float* d, int R, int C){ da.d[di].src=s; da.d[di].dst=d; da.d[di].R=R; da.d[di].C=C; ++di; };
  addT(transform_W, WTb + O_TRANSFORM, 128, 256);
  addT(ggc_W,   WTb + O_GGC,    128, 128);
  addT(gru_Wih, WTb + O_GRUWIH, 384, 128);
  addT(gru_Whh, WTb + O_GRUWHH, 384, 128);
  for (int i=0;i<4;++i) addT(fcs_W + (size_t)i*16384, WTb + O_FCS + i*16384, 128, 128);
  for (int i=0;i<4;++i) addT(fcn_W + (size_t)i*16384, WTb + O_FCN + i*16384, 128, 128);
  addT(mh_W1, WTb + O_MH1, 128, 128);
  addT(mh_W2, WTb + O_MH2, 128, 128);
  addT(mo_W1, WTb + O_MO1, 128, 128);
  addT(mo_W2, WTb + O_MO2, 128, 128);
  addT(mlp_W1, WTb + O_MLP1, 256, 512);
  addT(mlp_W2, WTb + O_MLP2, 128, 256);
  transpose_many<<<dim3(512, di), 256, 0, stream>>>(da);
  bias_sum_kernel<<<8, 256, 0, stream>>>(lstm_bih, lstm_bhh, bsum);
  f32to16_kernel<<<(4*512*128)/1024, 256, 0, stream>>>(lstm_Wih, WI16);
  f32to16_kernel<<<(4*512*128)/1024, 256, 0, stream>>>(lstm_Whh, WH16);

  auto smemK = [](int K, int BN){ return (size_t)(32*(K+4) + 16*BN)*4; };
  const int gN = NN/32;
  const int gB = BB/32;

  embed3_kernel<<<dim3(NF/256, 3), 256, 0, stream>>>(act_ids, dur_ids, act2_ids,
      emb_act, emb_dur, emb_act2, ha, hd, hg2);
  gemm_nt<128,0><<<gN, 256, smemK(256,128), stream>>>(hg2, hd, nullptr, nullptr, 128,
      WTb + O_TRANSFORM, transform_b, res, 256, 0);
  hipMemcpyAsync(hh, res, (size_t)NF*4, hipMemcpyDeviceToDevice, stream);

  for (int it=0; it<2; ++it) {
    gemm_nt<128,0><<<gN, 256, smemK(128,128), stream>>>(hh, nullptr, nullptr, nullptr, 128,
        WTb + O_GGC, ggc_b, mb, 128, 0);
    hipMemsetAsync(abuf, 0, (size_t)NF*4, stream);
    scatter_add_kernel<<<E2N/4, 256, 0, stream>>>(abuf, mb, src2, dst2);
    gemm_nt<384,0><<<gN, 256, smemK(128,384), stream>>>(abuf, nullptr, nullptr, nullptr, 128,
        WTb + O_GRUWIH, gru_bih, gi, 128, 0);
    gemm_nt<384,0><<<gN, 256, smemK(128,384), stream>>>(hh, nullptr, nullptr, nullptr, 128,
        WTb + O_GRUWHH, gru_bhh, gh, 128, 0);
    gru_update_kernel<<<NF/256, 256, 0, stream>>>(hh, gi, gh);
  }
  ln_lrelu_kernel<<<NN, 128, 0, stream>>>(hnf, hh, res, hn_g, hn_b);
  segmean_kernel<<<BB, 128, 0, stream>>>(hg2m, hnf, nullptr);

  const size_t LSTM_LDS = (size_t)4*8448*2;   // 67584 B
  for (int l=0; l<2; ++l) {
    const int i0 = l*2 + 0, i1 = l*2 + 1;
    f32to16_kernel<<<NF/1024, 256, 0, stream>>>(ha, fs16a);
    f32to16_kernel<<<NF/1024, 256, 0, stream>>>(hd, fs16d);
    lstm_fused3<<<NN/64, 512, LSTM_LDS, stream>>>(hLb, fs16a, nbr_a2d,
        WI16 + i0*65536, WH16 + i0*65536, bsum + i0*512);
    lstm_fused3<<<NN/64, 512, LSTM_LDS, stream>>>(hLb + (size_t)NN*128, fs16d, nbr_d2a,
        WI16 + i1*65536, WH16 + i1*65536, bsum + i1*512);

    gemm_nt<128,0><<<gN, 256, smemK(128,128), stream>>>(hd, nullptr, nullptr, nullptr, 128,
        WTb + O_FCS + i0*16384, fcs_b + i0*128, nd, 128, 0);
    gemm_nt<128,0><<<gN, 256, smemK(128,128), stream>>>(hLb, nullptr, nullptr, nullptr, 128,
        WTb + O_FCN + i0*16384, fcn_b + i0*128, nd, 128, 1);
    gemm_nt<128,0><<<gN, 256, smemK(128,128), stream>>>(ha, nullptr, nullptr, nullptr, 128,
        WTb + O_FCS + i1*16384, fcs_b + i1*128, na, 128, 0);
    gemm_nt<128,0><<<gN, 256, smemK(128,128), stream>>>(hLb + (size_t)NN*128, nullptr, nullptr, nullptr, 128,
        WTb + O_FCN + i1*16384, fcn_b + i1*128, na, 128, 1);
    ln_lrelu_kernel<<<NN, 128, 0, stream>>>(na, na, nullptr, n1_g + i0*128, n1_b + i0*128);
    ln_lrelu_kernel<<<NN, 128, 0, stream>>>(nd, nd, nullptr, n1_g + i1*128, n1_b + i1*128);
    ln_lrelu_kernel<<<NN, 128, 0, stream>>>(ha, ha, na, n3_g + i0*128, n3_b + i0*128);
    ln_lrelu_kernel<<<NN, 128, 0, stream>>>(hd, hd, nd, n3_g + i1*128, n3_b + i1*128);
  }
  segmean_kernel<<<BB, 128, 0, stream>>>(hgm, ha, hd);

  gemm_nt<128,1><<<gB, 256, smemK(128,128), stream>>>(hg2m, nullptr, nullptr, nullptr, 128,
      WTb + O_MO1, mo_b1, t1b, 128, 0);
  gemm_nt<128,1><<<gB, 256, smemK(128,128), stream>>>(t1b, nullptr, nullptr, nullptr, 128,
      WTb + O_MO2, mo_b2, o1b, 128, 0);
  gemm_nt<128,1><<<gB, 256, smemK(128,128), stream>>>(hgm, nullptr, nullptr, nullptr, 128,
      WTb + O_MH1, mh_b1, t2b, 128, 0);
  gemm_nt<128,1><<<gB, 256, smemK(128,128), stream>>>(t2b, nullptr, nullptr, nullptr, 128,
      WTb + O_MH2, mh_b2, o2b, 128, 0);
  gemm_nt<256,0><<<gB, 256, smemK(256,256), stream>>>(o1b, hg2m, nullptr, nullptr, 128,
      WTb + O_MLP1, nullptr, h1b, 256, 0);
  gemm_nt<256,1><<<gB, 256, smemK(256,256), stream>>>(o2b, hgm, nullptr, nullptr, 128,
      WTb + O_MLP1 + 256*256, mlp_b1, h1b, 256, 1);
  gemm_nt<128,1><<<gB, 256, smemK(256,128), stream>>>(h1b, h1b + 128, nullptr, nullptr, 256,
      WTb + O_MLP2, mlp_b2, h2b, 256, 0);
  cls_kernel<<<10, 256, 0, stream>>>((float*)d_out, h2b, cls_W, cls_b);
}

// Round 13
// 3075.172 us; speedup vs baseline: 1.7369x; 1.0231x over previous
//
#include <hip/hip_runtime.h>
#include <hip/hip_fp16.h>
#include <math.h>

#define NN 32768
#define HH 128
#define DD 16
#define BB 256
#define E2N (NN*DD)
#define NF (NN*HH)

typedef __attribute__((ext_vector_type(4))) float f32x4;
typedef __attribute__((ext_vector_type(4))) unsigned short u16x4;
typedef __attribute__((ext_vector_type(8))) unsigned short u16x8;
typedef _Float16 f16x8 __attribute__((ext_vector_type(8)));

__device__ __forceinline__ float fsig(float x) { return 1.0f/(1.0f + __expf(-x)); }
__device__ __forceinline__ float ftanh(float x) {
  float cx = fminf(fmaxf(x, -15.0f), 15.0f);
  float e = __expf(2.0f*cx);
  return 1.0f - 2.0f/(e + 1.0f);
}

// ---------------- transpose prep (weights -> [K][Nout] layout) ----------------
struct TDesc { const float* src; float* dst; int R; int C; };
struct TDescArr { TDesc d[26]; };

__global__ void transpose_many(TDescArr da) {
  TDesc t = da.d[blockIdx.y];
  int idx = blockIdx.x*256 + threadIdx.x;
  if (idx < t.R*t.C) {
    int r = idx / t.C, c = idx - r*t.C;
    t.dst[(size_t)c*t.R + r] = t.src[idx];
  }
}

__global__ void bias_sum_kernel(const float* __restrict__ bih, const float* __restrict__ bhh,
                                float* __restrict__ bsum) {
  int i = blockIdx.x*256 + threadIdx.x;
  if (i < 2048) bsum[i] = bih[i] + bhh[i];
}

// fp32 -> fp16 convert (vectorized, 4/thread)
__global__ void f32to16_kernel(const float* __restrict__ in, unsigned short* __restrict__ out) {
  int base = (blockIdx.x*256 + threadIdx.x) * 4;
  float4 v = *(const float4*)(in + base);
  u16x4 p;
  p[0] = __half_as_ushort(__float2half_rn(v.x));
  p[1] = __half_as_ushort(__float2half_rn(v.y));
  p[2] = __half_as_ushort(__float2half_rn(v.z));
  p[3] = __half_as_ushort(__float2half_rn(v.w));
  *(u16x4*)(out + base) = p;
}

// ---------------- embeddings ----------------
__global__ void embed3_kernel(const int* __restrict__ a_ids, const int* __restrict__ d_ids,
                              const int* __restrict__ a2_ids,
                              const float* __restrict__ ea, const float* __restrict__ ed,
                              const float* __restrict__ ea2,
                              float* __restrict__ ha, float* __restrict__ hd,
                              float* __restrict__ hg2) {
  int idx = blockIdx.x*256 + threadIdx.x;
  int n = idx >> 7, j = idx & 127;
  int w = blockIdx.y;
  if (w == 0)      ha[idx]  = ea[(size_t)a_ids[n]*128 + j];
  else if (w == 1) hd[idx]  = ed[(size_t)d_ids[n]*128 + j];
  else             hg2[idx] = ea2[(size_t)a2_ids[n]*128 + j];
}

// ---------------- generic GEMM: C = act(A @ W^T + bias + beta*C) ----------------
template<int BN, int ACT>
__global__ __launch_bounds__(256) void gemm_nt(
    const float* __restrict__ A0, const float* __restrict__ A1,
    const float* __restrict__ A2, const float* __restrict__ A3,
    int lda, const float* __restrict__ WT, const float* __restrict__ bias,
    float* __restrict__ C, int K, int beta)
{
  extern __shared__ float sm[];
  const int KP = K + 4;
  float* At = sm;             // [32][KP]
  float* Bc = sm + 32*KP;     // [16][BN]
  const int tid = threadIdx.x;
  const int m0 = blockIdx.x*32;
  const int ng = tid >> 5, cg = tid & 31;
  const int n0 = ng*4, c4 = cg*4;
  constexpr int G = BN/128;
  float acc[G][4][4];
#pragma unroll
  for (int g=0; g<G; ++g)
#pragma unroll
    for (int i=0;i<4;++i)
#pragma unroll
      for (int e=0;e<4;++e) acc[g][i][e] = 0.0f;

  const int nf4 = K >> 2;
  for (int idx = tid; idx < 32*nf4; idx += 256) {
    int row = idx / nf4;
    int kk = (idx - row*nf4) << 2;
    const float* Ap = (kk < 128) ? A0 : (kk < 256) ? A1 : (kk < 384) ? A2 : A3;
    float4 v = *(const float4*)(Ap + (size_t)(m0+row)*lda + (kk & 127));
    *(float4*)(At + row*KP + kk) = v;
  }
  const int nchunk = K >> 4;
  for (int kc = 0; kc < nchunk; ++kc) {
    __syncthreads();
    for (int idx = tid; idx < 16*(BN/4); idx += 256) {
      int kk = idx / (BN/4);
      int jq = idx - kk*(BN/4);
      *(float4*)(Bc + kk*BN + jq*4) = *(const float4*)(WT + (size_t)(kc*16+kk)*BN + jq*4);
    }
    __syncthreads();
    for (int k=0;k<16;++k) {
      const int kk = kc*16 + k;
      float av[4];
#pragma unroll
      for (int i=0;i<4;++i) av[i] = At[(n0+i)*KP + kk];
#pragma unroll
      for (int g=0; g<G; ++g) {
        float4 bv = *(const float4*)(Bc + k*BN + g*128 + c4);
        float bb[4] = {bv.x, bv.y, bv.z, bv.w};
#pragma unroll
        for (int i=0;i<4;++i)
#pragma unroll
          for (int e=0;e<4;++e)
            acc[g][i][e] += av[i]*bb[e];
      }
    }
  }
#pragma unroll
  for (int g=0; g<G; ++g) {
#pragma unroll
    for (int i=0;i<4;++i) {
      float* dst = C + (size_t)(m0+n0+i)*BN + g*128 + c4;
      float o[4];
#pragma unroll
      for (int e=0;e<4;++e) o[e] = acc[g][i][e];
      if (bias) {
#pragma unroll
        for (int e=0;e<4;++e) o[e] += bias[g*128 + c4 + e];
      }
      if (beta) {
        float4 p = *(const float4*)dst;
        o[0]+=p.x; o[1]+=p.y; o[2]+=p.z; o[3]+=p.w;
      }
      if (ACT==1) {
#pragma unroll
        for (int e=0;e<4;++e) o[e] = fmaxf(o[e], 0.0f);
      }
      *(float4*)dst = make_float4(o[0],o[1],o[2],o[3]);
    }
  }
}

// ---------------- fused LSTM v4: weights hoisted to registers, merged directions ----------------
// 1024 blocks (b<512: a2d, else d2a) x 64 nodes, 8 waves (512 thr).
// Loop-invariant WI/WH fragments (32 x f16x8 = 128 VGPR) preloaded once;
// __launch_bounds__(512,2) targets the 256-VGPR/2-wave budget. Per step:
// stage x(t) regs->LDS (dbuf), 1 barrier, pass1 WI.x, issue gather t+1,
// pass2 WH.h(t-1) (h dbuf), activations.
__global__ __launch_bounds__(512, 2) void lstm_fused4(
    float* __restrict__ hL,
    const unsigned short* __restrict__ fs16a, const unsigned short* __restrict__ fs16d,
    const int* __restrict__ nbrA, const int* __restrict__ nbrD,
    const unsigned short* __restrict__ WI0, const unsigned short* __restrict__ WH0,
    const unsigned short* __restrict__ WI1, const unsigned short* __restrict__ WH1,
    const float* __restrict__ bsum0, const float* __restrict__ bsum1)
{
  extern __shared__ unsigned short smem16[];
  unsigned short* xb0 = smem16;            // [64][132]
  unsigned short* xb1 = smem16 + 8448;
  unsigned short* hb0 = smem16 + 16896;
  unsigned short* hb1 = smem16 + 25344;
  const int tid = threadIdx.x;
  const int w = tid >> 6;          // wave 0..7
  const int lane = tid & 63;
  const int ln16 = lane & 15;
  const int lq = lane >> 4;
  const int b = blockIdx.x;
  const bool dir = (b >= 512);
  const int nb = (dir ? (b - 512) : b) * 64;
  const unsigned short* fs16 = dir ? fs16d : fs16a;
  const int* nbr = dir ? nbrD : nbrA;
  const unsigned short* WI = dir ? WI1 : WI0;
  const unsigned short* WH = dir ? WH1 : WH0;
  const float* bsum = dir ? bsum1 : bsum0;

  // ---- hoist loop-invariant weight fragments into registers ----
  f16x8 wI[4][4], wH[4][4];   // [kt][g]
#pragma unroll
  for (int kt=0; kt<4; ++kt)
#pragma unroll
    for (int g=0; g<4; ++g) {
      const size_t off = (size_t)(g*128 + w*16 + ln16)*128 + kt*32 + lq*8;
      wI[kt][g] = *(const f16x8*)(WI + off);
      wH[kt][g] = *(const f16x8*)(WH + off);
    }

  // gather duty: 8 threads/row, 16 halfs each
  const int gr = tid >> 3;
  const int gc = (tid & 7) * 16;
  const int* nrow = nbr + (size_t)(nb + gr)*DD;

  f32x4 bias[4];
#pragma unroll
  for (int g=0; g<4; ++g)
    bias[g] = *(const f32x4*)(bsum + g*128 + w*16 + lq*4);

  f32x4 cst[4];
#pragma unroll
  for (int nt=0; nt<4; ++nt)
#pragma unroll
    for (int e=0; e<4; ++e) cst[nt][e] = 0.0f;

  // prologue: gather x(0)
  u16x8 xg0, xg1;
  {
    int gidx = nrow[0];
    const unsigned short* src = fs16 + (size_t)gidx*128 + gc;
    xg0 = *(const u16x8*)(src);
    xg1 = *(const u16x8*)(src + 8);
  }
  int gnext = nrow[1];

#pragma unroll 1
  for (int t=0; t<16; ++t) {
    // stage x(t) regs -> LDS (dbuf)
    {
      unsigned short* d = ((t&1) ? xb1 : xb0) + gr*132 + gc;
      *(u16x8*)d = xg0;
      *(u16x8*)(d+8) = xg1;
    }
    __syncthreads();   // x(t) visible; h(t-1) writes visible

    f32x4 racc[4][4];   // [gate][nt]
#pragma unroll
    for (int g=0; g<4; ++g)
#pragma unroll
      for (int nt=0; nt<4; ++nt)
        racc[g][nt] = bias[g];

    // pass 1: WI . x(t)  (weights in regs)
    {
      const unsigned short* xR = (t&1) ? xb1 : xb0;
#pragma unroll
      for (int kt=0; kt<4; ++kt) {
        const int bo = kt*32 + lq*8;
        f16x8 bx[4];
#pragma unroll
        for (int nt=0; nt<4; ++nt)
          bx[nt] = *(const f16x8*)(xR + (nt*16+ln16)*132 + bo);
#pragma unroll
        for (int g=0; g<4; ++g)
#pragma unroll
          for (int nt=0; nt<4; ++nt)
            racc[g][nt] = __builtin_amdgcn_mfma_f32_16x16x32_f16(wI[kt][g], bx[nt], racc[g][nt], 0,0,0);
      }
    }
    // issue gather for t+1 (hidden under pass 2)
    if (t < 15) {
      const unsigned short* src = fs16 + (size_t)gnext*128 + gc;
      xg0 = *(const u16x8*)(src);
      xg1 = *(const u16x8*)(src + 8);
      if (t < 14) gnext = nrow[t+2];
    }
    // pass 2: WH . h(t-1)  (weights in regs)
    if (t > 0) {
      const unsigned short* hR = (t&1) ? hb0 : hb1;   // h(t-1) in buf (t-1)&1
#pragma unroll
      for (int kt=0; kt<4; ++kt) {
        const int bo = kt*32 + lq*8;
        f16x8 bh[4];
#pragma unroll
        for (int nt=0; nt<4; ++nt)
          bh[nt] = *(const f16x8*)(hR + (nt*16+ln16)*132 + bo);
#pragma unroll
        for (int g=0; g<4; ++g)
#pragma unroll
          for (int nt=0; nt<4; ++nt)
            racc[g][nt] = __builtin_amdgcn_mfma_f32_16x16x32_f16(wH[kt][g], bh[nt], racc[g][nt], 0,0,0);
      }
    }

    // activations + cell update; write h(t) to buf t&1
    unsigned short* hW = (t&1) ? hb1 : hb0;
#pragma unroll
    for (int nt=0; nt<4; ++nt) {
      float hv[4];
#pragma unroll
      for (int e=0; e<4; ++e) {
        float ig = fsig(racc[0][nt][e]);
        float fg = fsig(racc[1][nt][e]);
        float gg = ftanh(racc[2][nt][e]);
        float og = fsig(racc[3][nt][e]);
        float cc = fg*cst[nt][e] + ig*gg;
        cst[nt][e] = cc;
        hv[e] = og*ftanh(cc);
      }
      const int node = nt*16 + ln16;
      const int col = w*16 + lq*4;
      if (t < 15) {
        u16x4 hw;
#pragma unroll
        for (int e=0; e<4; ++e) hw[e] = __half_as_ushort(__float2half_rn(hv[e]));
        *(u16x4*)(hW + node*132 + col) = hw;
      } else {
        *(float4*)(hL + (size_t)((dir?NN:0) + nb + node)*128 + col) =
            make_float4(hv[0], hv[1], hv[2], hv[3]);
      }
    }
  }
}

// ---------------- GGC scatter-add: a[dst] += m[src] (128 floats/edge) ----------------
__global__ void scatter_add_kernel(float* __restrict__ a, const float* __restrict__ m,
                                   const int* __restrict__ src, const int* __restrict__ dst) {
  int wid = (blockIdx.x*256 + threadIdx.x) >> 6;
  int lane = threadIdx.x & 63;
  int s = src[wid], d = dst[wid];
  const float* mr = m + (size_t)s*128;
  float* ar = a + (size_t)d*128;
  atomicAdd(ar + lane, mr[lane]);
  atomicAdd(ar + 64 + lane, mr[64 + lane]);
}

// ---------------- GRU pointwise ----------------
__global__ void gru_update_kernel(float* __restrict__ hh, const float* __restrict__ gi,
                                  const float* __restrict__ gh) {
  int idx = blockIdx.x*256 + threadIdx.x;
  int n = idx >> 7, j = idx & 127;
  const float* gin = gi + (size_t)n*384;
  const float* ghn = gh + (size_t)n*384;
  float r  = fsig(gin[j] + ghn[j]);
  float z  = fsig(gin[128+j] + ghn[128+j]);
  float nn2 = ftanh(gin[256+j] + r*ghn[256+j]);
  float h = hh[idx];
  hh[idx] = (1.0f - z)*nn2 + z*h;
}

// ---------------- LayerNorm (+optional residual add) + leaky relu ----------------
__global__ void ln_lrelu_kernel(float* __restrict__ out, const float* __restrict__ x,
                                const float* __restrict__ add,
                                const float* __restrict__ g, const float* __restrict__ b) {
  int n = blockIdx.x, j = threadIdx.x;   // 128 threads
  size_t base = (size_t)n*128;
  float v = x[base+j];
  if (add) v += add[base+j];
  __shared__ float sh[4];
  float s = v;
#pragma unroll
  for (int m=32; m>=1; m>>=1) s += __shfl_xor(s, m, 64);
  if ((j&63)==0) sh[j>>6] = s;
  __syncthreads();
  float mean = (sh[0]+sh[1]) * 0.0078125f;
  float d = v - mean;
  float q = d*d;
#pragma unroll
  for (int m=32; m>=1; m>>=1) q += __shfl_xor(q, m, 64);
  if ((j&63)==0) sh[2+(j>>6)] = q;
  __syncthreads();
  float var = (sh[2]+sh[3]) * 0.0078125f;
  float y = d * rsqrtf(var + 1e-5f) * g[j] + b[j];
  out[base+j] = (y >= 0.0f) ? y : 0.01f*y;
}

// ---------------- segment mean (contiguous 128-node segments) ----------------
__global__ void segmean_kernel(float* __restrict__ out, const float* __restrict__ x,
                               const float* __restrict__ y) {
  int b = blockIdx.x, j = threadIdx.x;   // 128 threads, 256 blocks
  float s = 0.0f;
  for (int r=0; r<128; ++r) {
    size_t n = (size_t)(b*128 + r)*128 + j;
    s += x[n];
    if (y) s += y[n];
  }
  out[(size_t)b*128 + j] = s * 0.0078125f;
}

// ---------------- classifier head ----------------
__global__ void cls_kernel(float* __restrict__ out, const float* __restrict__ h2,
                           const float* __restrict__ Wc, const float* __restrict__ bc) {
  int gid = blockIdx.x*256 + threadIdx.x;
  if (gid >= BB*10) return;
  int mrow = gid/10, c = gid - mrow*10;
  const float* arow = h2 + (size_t)mrow*128;
  const float* wrow = Wc + (size_t)c*128;
  float s = bc[c];
  for (int k=0;k<128;++k) s += arow[k]*wrow[k];
  out[gid] = s;
}

__global__ void bail_kernel(float* out, float v) {
  if (threadIdx.x==0 && blockIdx.x==0) out[0] = v;
}

// ---------------- host orchestration ----------------
extern "C" void kernel_launch(void* const* d_in, const int* in_sizes, int n_in,
                              void* d_out, int out_size, void* d_ws, size_t ws_size,
                              hipStream_t stream)
{
  const int* act_ids  = (const int*)d_in[0];
  const int* dur_ids  = (const int*)d_in[1];
  const int* act2_ids = (const int*)d_in[2];
  const int* nbr_a2d  = (const int*)d_in[3];
  const int* nbr_d2a  = (const int*)d_in[4];
  const int* src2     = (const int*)d_in[5];
  const int* dst2     = (const int*)d_in[6];
  const float* emb_act     = (const float*)d_in[8];
  const float* emb_dur     = (const float*)d_in[9];
  const float* emb_act2    = (const float*)d_in[10];
  const float* transform_W = (const float*)d_in[11];
  const float* transform_b = (const float*)d_in[12];
  const float* ggc_W   = (const float*)d_in[13];
  const float* ggc_b   = (const float*)d_in[14];
  const float* gru_Wih = (const float*)d_in[15];
  const float* gru_Whh = (const float*)d_in[16];
  const float* gru_bih = (const float*)d_in[17];
  const float* gru_bhh = (const float*)d_in[18];
  const float* hn_g    = (const float*)d_in[19];
  const float* hn_b    = (const float*)d_in[20];
  const float* lstm_Wih = (const float*)d_in[21];
  const float* lstm_Whh = (const float*)d_in[22];
  const float* lstm_bih = (const float*)d_in[23];
  const float* lstm_bhh = (const float*)d_in[24];
  const float* fcs_W = (const float*)d_in[25];
  const float* fcs_b = (const float*)d_in[26];
  const float* fcn_W = (const float*)d_in[27];
  const float* fcn_b = (const float*)d_in[28];
  const float* n1_g = (const float*)d_in[29];
  const float* n1_b = (const float*)d_in[30];
  const float* n3_g = (const float*)d_in[31];
  const float* n3_b = (const float*)d_in[32];
  const float* mh_W1 = (const float*)d_in[33];
  const float* mh_b1 = (const float*)d_in[34];
  const float* mh_W2 = (const float*)d_in[35];
  const float* mh_b2 = (const float*)d_in[36];
  const float* mo_W1 = (const float*)d_in[37];
  const float* mo_b1 = (const float*)d_in[38];
  const float* mo_W2 = (const float*)d_in[39];
  const float* mo_b2 = (const float*)d_in[40];
  const float* mlp_W1 = (const float*)d_in[41];
  const float* mlp_b1 = (const float*)d_in[42];
  const float* mlp_W2 = (const float*)d_in[43];
  const float* mlp_b2 = (const float*)d_in[44];
  const float* cls_W = (const float*)d_in[45];
  const float* cls_b = (const float*)d_in[46];

  float* ws = (float*)d_ws;
  float* ha   = ws;
  float* hd   = ws + (size_t)NF;
  float* hg2  = ws + 2*(size_t)NF;
  float* res  = ws + 3*(size_t)NF;
  float* hh   = ws + 4*(size_t)NF;
  float* SCR  = ws + 5*(size_t)NF;
  float* mb   = SCR;
  float* abuf = SCR + (size_t)NF;
  float* gi   = SCR + 2*(size_t)NF;
  float* gh   = SCR + 5*(size_t)NF;
  float* hnf  = mb;
  float* hLb  = SCR + 8*(size_t)NF;
  float* SMALL = ws + 15*(size_t)NF;
  float* hg2m = SMALL;
  float* hgm  = SMALL + 32768;
  float* o1b  = SMALL + 65536;
  float* o2b  = SMALL + 98304;
  float* t1b  = SMALL + 131072;
  float* t2b  = SMALL + 163840;
  float* h1b  = SMALL + 196608;
  float* h2b  = SMALL + 262144;
  float* bsum = SMALL + 294912;
  float* WTb  = SMALL + 296960;
  const size_t NEED_BYTES = (size_t)(15*(size_t)NF + 296960 + 1032192) * 4;
  if (ws_size < NEED_BYTES) {
    hipMemsetAsync(d_out, 0, (size_t)out_size*sizeof(float), stream);
    bail_kernel<<<1,64,0,stream>>>((float*)d_out, (float)ws_size);
    return;
  }
  float* na = hg2;
  float* nd = res;
  unsigned short* fs16a = (unsigned short*)SCR;                     // NF halfs
  unsigned short* fs16d = (unsigned short*)(SCR + (size_t)NF/2);    // NF halfs

  const int O_TRANSFORM = 0;
  const int O_GGC      = 32768;
  const int O_GRUWIH   = 49152;
  const int O_GRUWHH   = 98304;
  const int O_SPLIT    = 147456;
  const int O_FCS      = 671744;
  const int O_FCN      = 737280;
  const int O_MH1      = 802816;
  const int O_MH2      = 819200;
  const int O_MO1      = 835584;
  const int O_MO2      = 851968;
  const int O_MLP1     = 868352;
  const int O_MLP2     = 999424;

  unsigned short* WI16 = (unsigned short*)(WTb + O_SPLIT);
  unsigned short* WH16 = WI16 + 4*65536;

  TDescArr da;
  int di = 0;
  auto addT = [&](const float* s, float* d, int R, int C){ da.d[di].src=s; da.d[di].dst=d; da.d[di].R=R; da.d[di].C=C; ++di; };
  addT(transform_W, WTb + O_TRANSFORM, 128, 256);
  addT(ggc_W,   WTb + O_GGC,    128, 128);
  addT(gru_Wih, WTb + O_GRUWIH, 384, 128);
  addT(gru_Whh, WTb + O_GRUWHH, 384, 128);
  for (int i=0;i<4;++i) addT(fcs_W + (size_t)i*16384, WTb + O_FCS + i*16384, 128, 128);
  for (int i=0;i<4;++i) addT(fcn_W + (size_t)i*16384, WTb + O_FCN + i*16384, 128, 128);
  addT(mh_W1, WTb + O_MH1, 128, 128);
  addT(mh_W2, WTb + O_MH2, 128, 128);
  addT(mo_W1, WTb + O_MO1, 128, 128);
  addT(mo_W2, WTb + O_MO2, 128, 128);
  addT(mlp_W1, WTb + O_MLP1, 256, 512);
  addT(mlp_W2, WTb + O_MLP2, 128, 256);
  transpose_many<<<dim3(512, di), 256, 0, stream>>>(da);
  bias_sum_kernel<<<8, 256, 0, stream>>>(lstm_bih, lstm_bhh, bsum);
  f32to16_kernel<<<(4*512*128)/1024, 256, 0, stream>>>(lstm_Wih, WI16);
  f32to16_kernel<<<(4*512*128)/1024, 256, 0, stream>>>(lstm_Whh, WH16);

  auto smemK = [](int K, int BN){ return (size_t)(32*(K+4) + 16*BN)*4; };
  const int gN = NN/32;
  const int gB = BB/32;

  embed3_kernel<<<dim3(NF/256, 3), 256, 0, stream>>>(act_ids, dur_ids, act2_ids,
      emb_act, emb_dur, emb_act2, ha, hd, hg2);
  gemm_nt<128,0><<<gN, 256, smemK(256,128), stream>>>(hg2, hd, nullptr, nullptr, 128,
      WTb + O_TRANSFORM, transform_b, res, 256, 0);
  hipMemcpyAsync(hh, res, (size_t)NF*4, hipMemcpyDeviceToDevice, stream);

  for (int it=0; it<2; ++it) {
    gemm_nt<128,0><<<gN, 256, smemK(128,128), stream>>>(hh, nullptr, nullptr, nullptr, 128,
        WTb + O_GGC, ggc_b, mb, 128, 0);
    hipMemsetAsync(abuf, 0, (size_t)NF*4, stream);
    scatter_add_kernel<<<E2N/4, 256, 0, stream>>>(abuf, mb, src2, dst2);
    gemm_nt<384,0><<<gN, 256, smemK(128,384), stream>>>(abuf, nullptr, nullptr, nullptr, 128,
        WTb + O_GRUWIH, gru_bih, gi, 128, 0);
    gemm_nt<384,0><<<gN, 256, smemK(128,384), stream>>>(hh, nullptr, nullptr, nullptr, 128,
        WTb + O_GRUWHH, gru_bhh, gh, 128, 0);
    gru_update_kernel<<<NF/256, 256, 0, stream>>>(hh, gi, gh);
  }
  ln_lrelu_kernel<<<NN, 128, 0, stream>>>(hnf, hh, res, hn_g, hn_b);
  segmean_kernel<<<BB, 128, 0, stream>>>(hg2m, hnf, nullptr);

  const size_t LSTM_LDS = (size_t)4*8448*2;   // 67584 B
  for (int l=0; l<2; ++l) {
    const int i0 = l*2 + 0, i1 = l*2 + 1;
    f32to16_kernel<<<NF/1024, 256, 0, stream>>>(ha, fs16a);
    f32to16_kernel<<<NF/1024, 256, 0, stream>>>(hd, fs16d);
    lstm_fused4<<<1024, 512, LSTM_LDS, stream>>>(hLb, fs16a, fs16d, nbr_a2d, nbr_d2a,
        WI16 + i0*65536, WH16 + i0*65536,
        WI16 + i1*65536, WH16 + i1*65536,
        bsum + i0*512, bsum + i1*512);

    gemm_nt<128,0><<<gN, 256, smemK(128,128), stream>>>(hd, nullptr, nullptr, nullptr, 128,
        WTb + O_FCS + i0*16384, fcs_b + i0*128, nd, 128, 0);
    gemm_nt<128,0><<<gN, 256, smemK(128,128), stream>>>(hLb, nullptr, nullptr, nullptr, 128,
        WTb + O_FCN + i0*16384, fcn_b + i0*128, nd, 128, 1);
    gemm_nt<128,0><<<gN, 256, smemK(128,128), stream>>>(ha, nullptr, nullptr, nullptr, 128,
        WTb + O_FCS + i1*16384, fcs_b + i1*128, na, 128, 0);
    gemm_nt<128,0><<<gN, 256, smemK(128,128), stream>>>(hLb + (size_t)NN*128, nullptr, nullptr, nullptr, 128,
        WTb + O_FCN + i1*16384, fcn_b + i1*128, na, 128, 1);
    ln_lrelu_kernel<<<NN, 128, 0, stream>>>(na, na, nullptr, n1_g + i0*128, n1_b + i0*128);
    ln_lrelu_kernel<<<NN, 128, 0, stream>>>(nd, nd, nullptr, n1_g + i1*128, n1_b + i1*128);
    ln_lrelu_kernel<<<NN, 128, 0, stream>>>(ha, ha, na, n3_g + i0*128, n3_b + i0*128);
    ln_lrelu_kernel<<<NN, 128, 0, stream>>>(hd, hd, nd, n3_g + i1*128, n3_b + i1*128);
  }
  segmean_kernel<<<BB, 128, 0, stream>>>(hgm, ha, hd);

  gemm_nt<128,1><<<gB, 256, smemK(128,128), stream>>>(hg2m, nullptr, nullptr, nullptr, 128,
      WTb + O_MO1, mo_b1, t1b, 128, 0);
  gemm_nt<128,1><<<gB, 256, smemK(128,128), stream>>>(t1b, nullptr, nullptr, nullptr, 128,
      WTb + O_MO2, mo_b2, o1b, 128, 0);
  gemm_nt<128,1><<<gB, 256, smemK(128,128), stream>>>(hgm, nullptr, nullptr, nullptr, 128,
      WTb + O_MH1, mh_b1, t2b, 128, 0);
  gemm_nt<128,1><<<gB, 256, smemK(128,128), stream>>>(t2b, nullptr, nullptr, nullptr, 128,
      WTb + O_MH2, mh_b2, o2b, 128, 0);
  gemm_nt<256,0><<<gB, 256, smemK(256,256), stream>>>(o1b, hg2m, nullptr, nullptr, 128,
      WTb + O_MLP1, nullptr, h1b, 256, 0);
  gemm_nt<256,1><<<gB, 256, smemK(256,256), stream>>>(o2b, hgm, nullptr, nullptr, 128,
      WTb + O_MLP1 + 256*256, mlp_b1, h1b, 256, 1);
  gemm_nt<128,1><<<gB, 256, smemK(256,128), stream>>>(h1b, h1b + 128, nullptr, nullptr, 256,
      WTb + O_MLP2, mlp_b2, h2b, 256, 0);
  cls_kernel<<<10, 256, 0, stream>>>((float*)d_out, h2b, cls_W, cls_b);
}

// Round 14
// 2922.470 us; speedup vs baseline: 1.8277x; 1.0523x over previous
//
#include <hip/hip_runtime.h>
#include <hip/hip_fp16.h>
#include <math.h>

#define NN 32768
#define HH 128
#define DD 16
#define BB 256
#define E2N (NN*DD)
#define NF (NN*HH)

typedef __attribute__((ext_vector_type(4))) float f32x4;
typedef __attribute__((ext_vector_type(4))) unsigned short u16x4;
typedef __attribute__((ext_vector_type(8))) unsigned short u16x8;
typedef _Float16 f16x8 __attribute__((ext_vector_type(8)));

__device__ __forceinline__ float fsig(float x) { return 1.0f/(1.0f + __expf(-x)); }
__device__ __forceinline__ float ftanh(float x) {
  float cx = fminf(fmaxf(x, -15.0f), 15.0f);
  float e = __expf(2.0f*cx);
  return 1.0f - 2.0f/(e + 1.0f);
}
__device__ __forceinline__ void hsplit(float x, unsigned short& h, unsigned short& l) {
  __half hh_ = __float2half_rn(x);
  h = __half_as_ushort(hh_);
  l = __half_as_ushort(__float2half_rn(x - __half2float(hh_)));
}

// ---------------- transpose prep (weights -> [K][Nout] layout) ----------------
struct TDesc { const float* src; float* dst; int R; int C; };
struct TDescArr { TDesc d[8]; };

__global__ void transpose_many(TDescArr da) {
  TDesc t = da.d[blockIdx.y];
  int idx = blockIdx.x*256 + threadIdx.x;
  if (idx < t.R*t.C) {
    int r = idx / t.C, c = idx - r*t.C;
    t.dst[(size_t)c*t.R + r] = t.src[idx];
  }
}

__global__ void bias_sum_kernel(const float* __restrict__ bih, const float* __restrict__ bhh,
                                float* __restrict__ bsum) {
  int i = blockIdx.x*256 + threadIdx.x;
  if (i < 2048) bsum[i] = bih[i] + bhh[i];
}

// fp32 -> fp16 convert (vectorized, 4/thread)
__global__ void f32to16_kernel(const float* __restrict__ in, unsigned short* __restrict__ out) {
  int base = (blockIdx.x*256 + threadIdx.x) * 4;
  float4 v = *(const float4*)(in + base);
  u16x4 p;
  p[0] = __half_as_ushort(__float2half_rn(v.x));
  p[1] = __half_as_ushort(__float2half_rn(v.y));
  p[2] = __half_as_ushort(__float2half_rn(v.z));
  p[3] = __half_as_ushort(__float2half_rn(v.w));
  *(u16x4*)(out + base) = p;
}

// fp32 -> fp16 hi/lo split
__global__ void wsplit16_kernel(const float* __restrict__ W,
                                unsigned short* __restrict__ hi,
                                unsigned short* __restrict__ lo) {
  int i = blockIdx.x*256 + threadIdx.x;
  unsigned short h, l;
  hsplit(W[i], h, l);
  hi[i] = h; lo[i] = l;
}

// ---------------- embeddings ----------------
__global__ void embed3_kernel(const int* __restrict__ a_ids, const int* __restrict__ d_ids,
                              const int* __restrict__ a2_ids,
                              const float* __restrict__ ea, const float* __restrict__ ed,
                              const float* __restrict__ ea2,
                              float* __restrict__ ha, float* __restrict__ hd,
                              float* __restrict__ hg2) {
  int idx = blockIdx.x*256 + threadIdx.x;
  int n = idx >> 7, j = idx & 127;
  int w = blockIdx.y;
  if (w == 0)      ha[idx]  = ea[(size_t)a_ids[n]*128 + j];
  else if (w == 1) hd[idx]  = ed[(size_t)d_ids[n]*128 + j];
  else             hg2[idx] = ea2[(size_t)a2_ids[n]*128 + j];
}

// ---------------- generic fp32 GEMM (kept for transform + heads) ----------------
template<int BN, int ACT>
__global__ __launch_bounds__(256) void gemm_nt(
    const float* __restrict__ A0, const float* __restrict__ A1,
    const float* __restrict__ A2, const float* __restrict__ A3,
    int lda, const float* __restrict__ WT, const float* __restrict__ bias,
    float* __restrict__ C, int K, int beta)
{
  extern __shared__ float sm[];
  const int KP = K + 4;
  float* At = sm;
  float* Bc = sm + 32*KP;
  const int tid = threadIdx.x;
  const int m0 = blockIdx.x*32;
  const int ng = tid >> 5, cg = tid & 31;
  const int n0 = ng*4, c4 = cg*4;
  constexpr int G = BN/128;
  float acc[G][4][4];
#pragma unroll
  for (int g=0; g<G; ++g)
#pragma unroll
    for (int i=0;i<4;++i)
#pragma unroll
      for (int e=0;e<4;++e) acc[g][i][e] = 0.0f;

  const int nf4 = K >> 2;
  for (int idx = tid; idx < 32*nf4; idx += 256) {
    int row = idx / nf4;
    int kk = (idx - row*nf4) << 2;
    const float* Ap = (kk < 128) ? A0 : (kk < 256) ? A1 : (kk < 384) ? A2 : A3;
    float4 v = *(const float4*)(Ap + (size_t)(m0+row)*lda + (kk & 127));
    *(float4*)(At + row*KP + kk) = v;
  }
  const int nchunk = K >> 4;
  for (int kc = 0; kc < nchunk; ++kc) {
    __syncthreads();
    for (int idx = tid; idx < 16*(BN/4); idx += 256) {
      int kk = idx / (BN/4);
      int jq = idx - kk*(BN/4);
      *(float4*)(Bc + kk*BN + jq*4) = *(const float4*)(WT + (size_t)(kc*16+kk)*BN + jq*4);
    }
    __syncthreads();
    for (int k=0;k<16;++k) {
      const int kk = kc*16 + k;
      float av[4];
#pragma unroll
      for (int i=0;i<4;++i) av[i] = At[(n0+i)*KP + kk];
#pragma unroll
      for (int g=0; g<G; ++g) {
        float4 bv = *(const float4*)(Bc + k*BN + g*128 + c4);
        float bb[4] = {bv.x, bv.y, bv.z, bv.w};
#pragma unroll
        for (int i=0;i<4;++i)
#pragma unroll
          for (int e=0;e<4;++e)
            acc[g][i][e] += av[i]*bb[e];
      }
    }
  }
#pragma unroll
  for (int g=0; g<G; ++g) {
#pragma unroll
    for (int i=0;i<4;++i) {
      float* dst = C + (size_t)(m0+n0+i)*BN + g*128 + c4;
      float o[4];
#pragma unroll
      for (int e=0;e<4;++e) o[e] = acc[g][i][e];
      if (bias) {
#pragma unroll
        for (int e=0;e<4;++e) o[e] += bias[g*128 + c4 + e];
      }
      if (beta) {
        float4 p = *(const float4*)dst;
        o[0]+=p.x; o[1]+=p.y; o[2]+=p.z; o[3]+=p.w;
      }
      if (ACT==1) {
#pragma unroll
        for (int e=0;e<4;++e) o[e] = fmaxf(o[e], 0.0f);
      }
      *(float4*)dst = make_float4(o[0],o[1],o[2],o[3]);
    }
  }
}

// ---------------- MFMA GEMM: C[N,BN] = A[N,128] @ W[BN,128]^T + bias (+beta C) ----------------
// fp32-accurate via fp16 hi/lo on BOTH operands (3 MFMA terms, err ~2^-21).
// 64 rows/block, 8 waves; wave w does tiles {w, w+8, ...} (BN/128 tiles).
// Uses m89-verified D mapping: row(outcol)=lq*4+e, col(node)=lane&15.
__global__ __launch_bounds__(512) void mgemm(
    const float* __restrict__ A,
    const unsigned short* __restrict__ Whi, const unsigned short* __restrict__ Wlo,
    const float* __restrict__ bias, float* __restrict__ C, int BN, int ntpw, int beta)
{
  __shared__ unsigned short xhi[64*136];
  __shared__ unsigned short xlo[64*136];
  const int tid = threadIdx.x;
  const int w = tid >> 6;
  const int lane = tid & 63;
  const int ln16 = lane & 15;
  const int lq = lane >> 4;
  const int rb = blockIdx.x * 64;

  {
    const int r = tid >> 3;
    const int cf = (tid & 7) * 16;
    const float* src = A + (size_t)(rb + r)*128 + cf;
    unsigned short* dh = xhi + r*136 + cf;
    unsigned short* dl = xlo + r*136 + cf;
#pragma unroll
    for (int q=0; q<4; ++q) {
      float4 v = *(const float4*)(src + q*4);
      float vs[4] = {v.x, v.y, v.z, v.w};
      u16x4 ph, pl;
#pragma unroll
      for (int e=0;e<4;++e){ unsigned short h_,l_; hsplit(vs[e],h_,l_); ph[e]=h_; pl[e]=l_; }
      *(u16x4*)(dh + q*4) = ph;
      *(u16x4*)(dl + q*4) = pl;
    }
  }
  __syncthreads();

  for (int j=0; j<ntpw; ++j) {
    const int tile = w + j*8;
    f32x4 acc[4];
    if (bias) {
      f32x4 bv = *(const f32x4*)(bias + tile*16 + lq*4);
#pragma unroll
      for (int nt=0; nt<4; ++nt) acc[nt] = bv;
    } else {
#pragma unroll
      for (int nt=0; nt<4; ++nt)
#pragma unroll
        for (int e=0;e<4;++e) acc[nt][e] = 0.0f;
    }
#pragma unroll
    for (int kt=0; kt<4; ++kt) {
      const int bo = kt*32 + lq*8;
      f16x8 bxh[4], bxl[4];
#pragma unroll
      for (int nt=0; nt<4; ++nt) {
        bxh[nt] = *(const f16x8*)(xhi + (nt*16+ln16)*136 + bo);
        bxl[nt] = *(const f16x8*)(xlo + (nt*16+ln16)*136 + bo);
      }
      const size_t co = (size_t)(tile*16 + ln16)*128 + kt*32 + lq*8;
      f16x8 ah = *(const f16x8*)(Whi + co);
      f16x8 al = *(const f16x8*)(Wlo + co);
#pragma unroll
      for (int nt=0; nt<4; ++nt) {
        acc[nt] = __builtin_amdgcn_mfma_f32_16x16x32_f16(ah, bxh[nt], acc[nt], 0,0,0);
        acc[nt] = __builtin_amdgcn_mfma_f32_16x16x32_f16(ah, bxl[nt], acc[nt], 0,0,0);
        acc[nt] = __builtin_amdgcn_mfma_f32_16x16x32_f16(al, bxh[nt], acc[nt], 0,0,0);
      }
    }
#pragma unroll
    for (int nt=0; nt<4; ++nt) {
      float* dst = C + (size_t)(rb + nt*16 + ln16)*BN + tile*16 + lq*4;
      f32x4 o = acc[nt];
      if (beta) {
        float4 p = *(const float4*)dst;
        o[0]+=p.x; o[1]+=p.y; o[2]+=p.z; o[3]+=p.w;
      }
      *(float4*)dst = make_float4(o[0],o[1],o[2],o[3]);
    }
  }
}

// ---------------- fused LSTM v5: merged dirs, streamed fp16 weights (no hoist) ----------------
__global__ __launch_bounds__(512) void lstm_fused5(
    float* __restrict__ hL,
    const unsigned short* __restrict__ fs16a, const unsigned short* __restrict__ fs16d,
    const int* __restrict__ nbrA, const int* __restrict__ nbrD,
    const unsigned short* __restrict__ WI0, const unsigned short* __restrict__ WH0,
    const unsigned short* __restrict__ WI1, const unsigned short* __restrict__ WH1,
    const float* __restrict__ bsum0, const float* __restrict__ bsum1)
{
  extern __shared__ unsigned short smem16[];
  unsigned short* xb0 = smem16;            // [64][132]
  unsigned short* xb1 = smem16 + 8448;
  unsigned short* hb0 = smem16 + 16896;
  unsigned short* hb1 = smem16 + 25344;
  const int tid = threadIdx.x;
  const int w = tid >> 6;
  const int lane = tid & 63;
  const int ln16 = lane & 15;
  const int lq = lane >> 4;
  const int b = blockIdx.x;
  const bool dir = (b >= 512);
  const int nb = (dir ? (b - 512) : b) * 64;
  const unsigned short* fs16 = dir ? fs16d : fs16a;
  const int* nbr = dir ? nbrD : nbrA;
  const unsigned short* WI = dir ? WI1 : WI0;
  const unsigned short* WH = dir ? WH1 : WH0;
  const float* bsum = dir ? bsum1 : bsum0;

  const int gr = tid >> 3;
  const int gc = (tid & 7) * 16;
  const int* nrow = nbr + (size_t)(nb + gr)*DD;

  f32x4 bias[4];
#pragma unroll
  for (int g=0; g<4; ++g)
    bias[g] = *(const f32x4*)(bsum + g*128 + w*16 + lq*4);

  f32x4 cst[4];
#pragma unroll
  for (int nt=0; nt<4; ++nt)
#pragma unroll
    for (int e=0; e<4; ++e) cst[nt][e] = 0.0f;

  u16x8 xg0, xg1;
  {
    int gidx = nrow[0];
    const unsigned short* src = fs16 + (size_t)gidx*128 + gc;
    xg0 = *(const u16x8*)(src);
    xg1 = *(const u16x8*)(src + 8);
  }
  int gnext = nrow[1];

#pragma unroll 1
  for (int t=0; t<16; ++t) {
    {
      unsigned short* d = ((t&1) ? xb1 : xb0) + gr*132 + gc;
      *(u16x8*)d = xg0;
      *(u16x8*)(d+8) = xg1;
    }
    __syncthreads();

    f32x4 racc[4][4];
#pragma unroll
    for (int g=0; g<4; ++g)
#pragma unroll
      for (int nt=0; nt<4; ++nt)
        racc[g][nt] = bias[g];

    // pass 1: WI . x(t)  (weights streamed from L2)
    {
      const unsigned short* xR = (t&1) ? xb1 : xb0;
#pragma unroll
      for (int kt=0; kt<4; ++kt) {
        const int bo = kt*32 + lq*8;
        f16x8 bx[4];
#pragma unroll
        for (int nt=0; nt<4; ++nt)
          bx[nt] = *(const f16x8*)(xR + (nt*16+ln16)*132 + bo);
#pragma unroll
        for (int g=0; g<4; ++g) {
          f16x8 aI = *(const f16x8*)(WI + (size_t)(g*128 + w*16 + ln16)*128 + kt*32 + lq*8);
#pragma unroll
          for (int nt=0; nt<4; ++nt)
            racc[g][nt] = __builtin_amdgcn_mfma_f32_16x16x32_f16(aI, bx[nt], racc[g][nt], 0,0,0);
        }
      }
    }
    if (t < 15) {
      const unsigned short* src = fs16 + (size_t)gnext*128 + gc;
      xg0 = *(const u16x8*)(src);
      xg1 = *(const u16x8*)(src + 8);
      if (t < 14) gnext = nrow[t+2];
    }
    // pass 2: WH . h(t-1)
    if (t > 0) {
      const unsigned short* hR = (t&1) ? hb0 : hb1;
#pragma unroll
      for (int kt=0; kt<4; ++kt) {
        const int bo = kt*32 + lq*8;
        f16x8 bh[4];
#pragma unroll
        for (int nt=0; nt<4; ++nt)
          bh[nt] = *(const f16x8*)(hR + (nt*16+ln16)*132 + bo);
#pragma unroll
        for (int g=0; g<4; ++g) {
          f16x8 aH = *(const f16x8*)(WH + (size_t)(g*128 + w*16 + ln16)*128 + kt*32 + lq*8);
#pragma unroll
          for (int nt=0; nt<4; ++nt)
            racc[g][nt] = __builtin_amdgcn_mfma_f32_16x16x32_f16(aH, bh[nt], racc[g][nt], 0,0,0);
        }
      }
    }

    unsigned short* hW = (t&1) ? hb1 : hb0;
#pragma unroll
    for (int nt=0; nt<4; ++nt) {
      float hv[4];
#pragma unroll
      for (int e=0; e<4; ++e) {
        float ig = fsig(racc[0][nt][e]);
        float fg = fsig(racc[1][nt][e]);
        float gg = ftanh(racc[2][nt][e]);
        float og = fsig(racc[3][nt][e]);
        float cc = fg*cst[nt][e] + ig*gg;
        cst[nt][e] = cc;
        hv[e] = og*ftanh(cc);
      }
      const int node = nt*16 + ln16;
      const int col = w*16 + lq*4;
      if (t < 15) {
        u16x4 hw;
#pragma unroll
        for (int e=0; e<4; ++e) hw[e] = __half_as_ushort(__float2half_rn(hv[e]));
        *(u16x4*)(hW + node*132 + col) = hw;
      } else {
        *(float4*)(hL + (size_t)((dir?NN:0) + nb + node)*128 + col) =
            make_float4(hv[0], hv[1], hv[2], hv[3]);
      }
    }
  }
}

// ---------------- GGC scatter-add ----------------
__global__ void scatter_add_kernel(float* __restrict__ a, const float* __restrict__ m,
                                   const int* __restrict__ src, const int* __restrict__ dst) {
  int wid = (blockIdx.x*256 + threadIdx.x) >> 6;
  int lane = threadIdx.x & 63;
  int s = src[wid], d = dst[wid];
  const float* mr = m + (size_t)s*128;
  float* ar = a + (size_t)d*128;
  atomicAdd(ar + lane, mr[lane]);
  atomicAdd(ar + 64 + lane, mr[64 + lane]);
}

// ---------------- GRU pointwise ----------------
__global__ void gru_update_kernel(float* __restrict__ hh, const float* __restrict__ gi,
                                  const float* __restrict__ gh) {
  int idx = blockIdx.x*256 + threadIdx.x;
  int n = idx >> 7, j = idx & 127;
  const float* gin = gi + (size_t)n*384;
  const float* ghn = gh + (size_t)n*384;
  float r  = fsig(gin[j] + ghn[j]);
  float z  = fsig(gin[128+j] + ghn[128+j]);
  float nn2 = ftanh(gin[256+j] + r*ghn[256+j]);
  float h = hh[idx];
  hh[idx] = (1.0f - z)*nn2 + z*h;
}

// ---------------- LayerNorm + leaky relu ----------------
__global__ void ln_lrelu_kernel(float* __restrict__ out, const float* __restrict__ x,
                                const float* __restrict__ add,
                                const float* __restrict__ g, const float* __restrict__ b) {
  int n = blockIdx.x, j = threadIdx.x;
  size_t base = (size_t)n*128;
  float v = x[base+j];
  if (add) v += add[base+j];
  __shared__ float sh[4];
  float s = v;
#pragma unroll
  for (int m=32; m>=1; m>>=1) s += __shfl_xor(s, m, 64);
  if ((j&63)==0) sh[j>>6] = s;
  __syncthreads();
  float mean = (sh[0]+sh[1]) * 0.0078125f;
  float d = v - mean;
  float q = d*d;
#pragma unroll
  for (int m=32; m>=1; m>>=1) q += __shfl_xor(q, m, 64);
  if ((j&63)==0) sh[2+(j>>6)] = q;
  __syncthreads();
  float var = (sh[2]+sh[3]) * 0.0078125f;
  float y = d * rsqrtf(var + 1e-5f) * g[j] + b[j];
  out[base+j] = (y >= 0.0f) ? y : 0.01f*y;
}

// ---------------- segment mean ----------------
__global__ void segmean_kernel(float* __restrict__ out, const float* __restrict__ x,
                               const float* __restrict__ y) {
  int b = blockIdx.x, j = threadIdx.x;
  float s = 0.0f;
  for (int r=0; r<128; ++r) {
    size_t n = (size_t)(b*128 + r)*128 + j;
    s += x[n];
    if (y) s += y[n];
  }
  out[(size_t)b*128 + j] = s * 0.0078125f;
}

// ---------------- classifier head ----------------
__global__ void cls_kernel(float* __restrict__ out, const float* __restrict__ h2,
                           const float* __restrict__ Wc, const float* __restrict__ bc) {
  int gid = blockIdx.x*256 + threadIdx.x;
  if (gid >= BB*10) return;
  int mrow = gid/10, c = gid - mrow*10;
  const float* arow = h2 + (size_t)mrow*128;
  const float* wrow = Wc + (size_t)c*128;
  float s = bc[c];
  for (int k=0;k<128;++k) s += arow[k]*wrow[k];
  out[gid] = s;
}

__global__ void bail_kernel(float* out, float v) {
  if (threadIdx.x==0 && blockIdx.x==0) out[0] = v;
}

// ---------------- host orchestration ----------------
extern "C" void kernel_launch(void* const* d_in, const int* in_sizes, int n_in,
                              void* d_out, int out_size, void* d_ws, size_t ws_size,
                              hipStream_t stream)
{
  const int* act_ids  = (const int*)d_in[0];
  const int* dur_ids  = (const int*)d_in[1];
  const int* act2_ids = (const int*)d_in[2];
  const int* nbr_a2d  = (const int*)d_in[3];
  const int* nbr_d2a  = (const int*)d_in[4];
  const int* src2     = (const int*)d_in[5];
  const int* dst2     = (const int*)d_in[6];
  const float* emb_act     = (const float*)d_in[8];
  const float* emb_dur     = (const float*)d_in[9];
  const float* emb_act2    = (const float*)d_in[10];
  const float* transform_W = (const float*)d_in[11];
  const float* transform_b = (const float*)d_in[12];
  const float* ggc_W   = (const float*)d_in[13];
  const float* ggc_b   = (const float*)d_in[14];
  const float* gru_Wih = (const float*)d_in[15];
  const float* gru_Whh = (const float*)d_in[16];
  const float* gru_bih = (const float*)d_in[17];
  const float* gru_bhh = (const float*)d_in[18];
  const float* hn_g    = (const float*)d_in[19];
  const float* hn_b    = (const float*)d_in[20];
  const float* lstm_Wih = (const float*)d_in[21];
  const float* lstm_Whh = (const float*)d_in[22];
  const float* lstm_bih = (const float*)d_in[23];
  const float* lstm_bhh = (const float*)d_in[24];
  const float* fcs_W = (const float*)d_in[25];
  const float* fcs_b = (const float*)d_in[26];
  const float* fcn_W = (const float*)d_in[27];
  const float* fcn_b = (const float*)d_in[28];
  const float* n1_g = (const float*)d_in[29];
  const float* n1_b = (const float*)d_in[30];
  const float* n3_g = (const float*)d_in[31];
  const float* n3_b = (const float*)d_in[32];
  const float* mh_W1 = (const float*)d_in[33];
  const float* mh_b1 = (const float*)d_in[34];
  const float* mh_W2 = (const float*)d_in[35];
  const float* mh_b2 = (const float*)d_in[36];
  const float* mo_W1 = (const float*)d_in[37];
  const float* mo_b1 = (const float*)d_in[38];
  const float* mo_W2 = (const float*)d_in[39];
  const float* mo_b2 = (const float*)d_in[40];
  const float* mlp_W1 = (const float*)d_in[41];
  const float* mlp_b1 = (const float*)d_in[42];
  const float* mlp_W2 = (const float*)d_in[43];
  const float* mlp_b2 = (const float*)d_in[44];
  const float* cls_W = (const float*)d_in[45];
  const float* cls_b = (const float*)d_in[46];

  float* ws = (float*)d_ws;
  float* ha   = ws;
  float* hd   = ws + (size_t)NF;
  float* hg2  = ws + 2*(size_t)NF;
  float* res  = ws + 3*(size_t)NF;
  float* hh   = ws + 4*(size_t)NF;
  float* SCR  = ws + 5*(size_t)NF;
  float* mb   = SCR;
  float* abuf = SCR + (size_t)NF;
  float* gi   = SCR + 2*(size_t)NF;
  float* gh   = SCR + 5*(size_t)NF;
  float* hnf  = mb;
  float* hLb  = SCR + 8*(size_t)NF;
  float* SMALL = ws + 15*(size_t)NF;
  float* hg2m = SMALL;
  float* hgm  = SMALL + 32768;
  float* o1b  = SMALL + 65536;
  float* o2b  = SMALL + 98304;
  float* t1b  = SMALL + 131072;
  float* t2b  = SMALL + 163840;
  float* h1b  = SMALL + 196608;
  float* h2b  = SMALL + 262144;
  float* bsum = SMALL + 294912;
  float* WTb  = SMALL + 296960;
  const size_t NEED_BYTES = (size_t)(15*(size_t)NF + 296960 + 1032192) * 4;
  if (ws_size < NEED_BYTES) {
    hipMemsetAsync(d_out, 0, (size_t)out_size*sizeof(float), stream);
    bail_kernel<<<1,64,0,stream>>>((float*)d_out, (float)ws_size);
    return;
  }
  float* na = hg2;
  float* nd = res;
  unsigned short* fs16a = (unsigned short*)SCR;
  unsigned short* fs16d = (unsigned short*)(SCR + (size_t)NF/2);

  const int O_TRANSFORM = 0;
  const int O_SPLIT    = 147456;    // lstm WI/WH fp16: 8 x 65536 halfs
  const int O_SPLIT2   = 409600;    // mgemm weight hi/lo arena (halfs base)
  const int O_MH1      = 802816;
  const int O_MH2      = 819200;
  const int O_MO1      = 835584;
  const int O_MO2      = 851968;
  const int O_MLP1     = 868352;
  const int O_MLP2     = 999424;

  unsigned short* WI16 = (unsigned short*)(WTb + O_SPLIT);
  unsigned short* WH16 = WI16 + 4*65536;

  // mgemm split arena (halfs): ggc 16384, gih 49152, ghh 49152, fcs 65536, fcn 65536 (x2 hi/lo)
  unsigned short* SP2 = (unsigned short*)(WTb + O_SPLIT2);
  unsigned short* GGChi = SP2;                 unsigned short* GGClo = GGChi + 16384;
  unsigned short* GIHhi = GGClo + 16384;       unsigned short* GIHlo = GIHhi + 49152;
  unsigned short* GHHhi = GIHlo + 49152;       unsigned short* GHHlo = GHHhi + 49152;
  unsigned short* FCShi = GHHlo + 49152;       unsigned short* FCSlo = FCShi + 65536;
  unsigned short* FCNhi = FCSlo + 65536;       unsigned short* FCNlo = FCNhi + 65536;

  TDescArr da;
  int di = 0;
  auto addT = [&](const float* s, float* d, int R, int C){ da.d[di].src=s; da.d[di].dst=d; da.d[di].R=R; da.d[di].C=C; ++di; };
  addT(transform_W, WTb + O_TRANSFORM, 128, 256);
  addT(mh_W1, WTb + O_MH1, 128, 128);
  addT(mh_W2, WTb + O_MH2, 128, 128);
  addT(mo_W1, WTb + O_MO1, 128, 128);
  addT(mo_W2, WTb + O_MO2, 128, 128);
  addT(mlp_W1, WTb + O_MLP1, 256, 512);
  addT(mlp_W2, WTb + O_MLP2, 128, 256);
  transpose_many<<<dim3(512, di), 256, 0, stream>>>(da);
  bias_sum_kernel<<<8, 256, 0, stream>>>(lstm_bih, lstm_bhh, bsum);
  f32to16_kernel<<<(4*512*128)/1024, 256, 0, stream>>>(lstm_Wih, WI16);
  f32to16_kernel<<<(4*512*128)/1024, 256, 0, stream>>>(lstm_Whh, WH16);
  wsplit16_kernel<<<16384/256, 256, 0, stream>>>(ggc_W, GGChi, GGClo);
  wsplit16_kernel<<<49152/256, 256, 0, stream>>>(gru_Wih, GIHhi, GIHlo);
  wsplit16_kernel<<<49152/256, 256, 0, stream>>>(gru_Whh, GHHhi, GHHlo);
  wsplit16_kernel<<<65536/256, 256, 0, stream>>>(fcs_W, FCShi, FCSlo);
  wsplit16_kernel<<<65536/256, 256, 0, stream>>>(fcn_W, FCNhi, FCNlo);

  auto smemK = [](int K, int BN){ return (size_t)(32*(K+4) + 16*BN)*4; };
  const int gN = NN/32;
  const int gB = BB/32;
  const int gM = NN/64;   // 512 blocks for mgemm

  embed3_kernel<<<dim3(NF/256, 3), 256, 0, stream>>>(act_ids, dur_ids, act2_ids,
      emb_act, emb_dur, emb_act2, ha, hd, hg2);
  gemm_nt<128,0><<<gN, 256, smemK(256,128), stream>>>(hg2, hd, nullptr, nullptr, 128,
      WTb + O_TRANSFORM, transform_b, res, 256, 0);
  hipMemcpyAsync(hh, res, (size_t)NF*4, hipMemcpyDeviceToDevice, stream);

  for (int it=0; it<2; ++it) {
    mgemm<<<gM, 512, 0, stream>>>(hh, GGChi, GGClo, ggc_b, mb, 128, 1, 0);
    hipMemsetAsync(abuf, 0, (size_t)NF*4, stream);
    scatter_add_kernel<<<E2N/4, 256, 0, stream>>>(abuf, mb, src2, dst2);
    mgemm<<<gM, 512, 0, stream>>>(abuf, GIHhi, GIHlo, gru_bih, gi, 384, 3, 0);
    mgemm<<<gM, 512, 0, stream>>>(hh, GHHhi, GHHlo, gru_bhh, gh, 384, 3, 0);
    gru_update_kernel<<<NF/256, 256, 0, stream>>>(hh, gi, gh);
  }
  ln_lrelu_kernel<<<NN, 128, 0, stream>>>(hnf, hh, res, hn_g, hn_b);
  segmean_kernel<<<BB, 128, 0, stream>>>(hg2m, hnf, nullptr);

  const size_t LSTM_LDS = (size_t)4*8448*2;   // 67584 B
  for (int l=0; l<2; ++l) {
    const int i0 = l*2 + 0, i1 = l*2 + 1;
    f32to16_kernel<<<NF/1024, 256, 0, stream>>>(ha, fs16a);
    f32to16_kernel<<<NF/1024, 256, 0, stream>>>(hd, fs16d);
    lstm_fused5<<<1024, 512, LSTM_LDS, stream>>>(hLb, fs16a, fs16d, nbr_a2d, nbr_d2a,
        WI16 + i0*65536, WH16 + i0*65536,
        WI16 + i1*65536, WH16 + i1*65536,
        bsum + i0*512, bsum + i1*512);

    mgemm<<<gM, 512, 0, stream>>>(hd, FCShi + i0*16384, FCSlo + i0*16384, fcs_b + i0*128, nd, 128, 1, 0);
    mgemm<<<gM, 512, 0, stream>>>(hLb, FCNhi + i0*16384, FCNlo + i0*16384, fcn_b + i0*128, nd, 128, 1, 1);
    mgemm<<<gM, 512, 0, stream>>>(ha, FCShi + i1*16384, FCSlo + i1*16384, fcs_b + i1*128, na, 128, 1, 0);
    mgemm<<<gM, 512, 0, stream>>>(hLb + (size_t)NN*128, FCNhi + i1*16384, FCNlo + i1*16384, fcn_b + i1*128, na, 128, 1, 1);
    ln_lrelu_kernel<<<NN, 128, 0, stream>>>(na, na, nullptr, n1_g + i0*128, n1_b + i0*128);
    ln_lrelu_kernel<<<NN, 128, 0, stream>>>(nd, nd, nullptr, n1_g + i1*128, n1_b + i1*128);
    ln_lrelu_kernel<<<NN, 128, 0, stream>>>(ha, ha, na, n3_g + i0*128, n3_b + i0*128);
    ln_lrelu_kernel<<<NN, 128, 0, stream>>>(hd, hd, nd, n3_g + i1*128, n3_b + i1*128);
  }
  segmean_kernel<<<BB, 128, 0, stream>>>(hgm, ha, hd);

  gemm_nt<128,1><<<gB, 256, smemK(128,128), stream>>>(hg2m, nullptr, nullptr, nullptr, 128,
      WTb + O_MO1, mo_b1, t1b, 128, 0);
  gemm_nt<128,1><<<gB, 256, smemK(128,128), stream>>>(t1b, nullptr, nullptr, nullptr, 128,
      WTb + O_MO2, mo_b2, o1b, 128, 0);
  gemm_nt<128,1><<<gB, 256, smemK(128,128), stream>>>(hgm, nullptr, nullptr, nullptr, 128,
      WTb + O_MH1, mh_b1, t2b, 128, 0);
  gemm_nt<128,1><<<gB, 256, smemK(128,128), stream>>>(t2b, nullptr, nullptr, nullptr, 128,
      WTb + O_MH2, mh_b2, o2b, 128, 0);
  gemm_nt<256,0><<<gB, 256, smemK(256,256), stream>>>(o1b, hg2m, nullptr, nullptr, 128,
      WTb + O_MLP1, nullptr, h1b, 256, 0);
  gemm_nt<256,1><<<gB, 256, smemK(256,256), stream>>>(o2b, hgm, nullptr, nullptr, 128,
      WTb + O_MLP1 + 256*256, mlp_b1, h1b, 256, 1);
  gemm_nt<128,1><<<gB, 256, smemK(256,128), stream>>>(h1b, h1b + 128, nullptr, nullptr, 256,
      WTb + O_MLP2, mlp_b2, h2b, 256, 0);
  cls_kernel<<<10, 256, 0, stream>>>((float*)d_out, h2b, cls_W, cls_b);
}

// Round 15
// 2091.268 us; speedup vs baseline: 2.5541x; 1.3975x over previous
//
#include <hip/hip_runtime.h>
#include <hip/hip_fp16.h>
#include <math.h>

#define NN 32768
#define HH 128
#define DD 16
#define BB 256
#define E2N (NN*DD)
#define NF (NN*HH)

typedef __attribute__((ext_vector_type(4))) float f32x4;
typedef __attribute__((ext_vector_type(4))) unsigned short u16x4;
typedef __attribute__((ext_vector_type(8))) unsigned short u16x8;
typedef _Float16 f16x8 __attribute__((ext_vector_type(8)));

// raw-HW activations: v_exp_f32 computes 2^x; v_rcp_f32 ~1ulp.
// sigma(x) = 1/(1+e^-x) = rcp(1 + exp2(-x*log2e)); saturates correctly (inf->0, 0->1).
// tanh(x) = 1 - 2/(1+e^{2x}) = 1 - 2*rcp(1 + exp2(x*2*log2e)); inf-safe both ends.
__device__ __forceinline__ float fsig(float x) {
  return __builtin_amdgcn_rcpf(1.0f + __builtin_amdgcn_exp2f(-1.442695041f*x));
}
__device__ __forceinline__ float ftanh(float x) {
  return 1.0f - 2.0f*__builtin_amdgcn_rcpf(1.0f + __builtin_amdgcn_exp2f(2.885390082f*x));
}
__device__ __forceinline__ void hsplit(float x, unsigned short& h, unsigned short& l) {
  __half hh_ = __float2half_rn(x);
  h = __half_as_ushort(hh_);
  l = __half_as_ushort(__float2half_rn(x - __half2float(hh_)));
}

// ---------------- transpose prep (weights -> [K][Nout] layout) ----------------
struct TDesc { const float* src; float* dst; int R; int C; };
struct TDescArr { TDesc d[8]; };

__global__ void transpose_many(TDescArr da) {
  TDesc t = da.d[blockIdx.y];
  int idx = blockIdx.x*256 + threadIdx.x;
  if (idx < t.R*t.C) {
    int r = idx / t.C, c = idx - r*t.C;
    t.dst[(size_t)c*t.R + r] = t.src[idx];
  }
}

__global__ void bias_sum_kernel(const float* __restrict__ bih, const float* __restrict__ bhh,
                                float* __restrict__ bsum) {
  int i = blockIdx.x*256 + threadIdx.x;
  if (i < 2048) bsum[i] = bih[i] + bhh[i];
}

// fp32 -> fp16 convert (vectorized, 4/thread)
__global__ void f32to16_kernel(const float* __restrict__ in, unsigned short* __restrict__ out) {
  int base = (blockIdx.x*256 + threadIdx.x) * 4;
  float4 v = *(const float4*)(in + base);
  u16x4 p;
  p[0] = __half_as_ushort(__float2half_rn(v.x));
  p[1] = __half_as_ushort(__float2half_rn(v.y));
  p[2] = __half_as_ushort(__float2half_rn(v.z));
  p[3] = __half_as_ushort(__float2half_rn(v.w));
  *(u16x4*)(out + base) = p;
}

// fp32 -> fp16 hi/lo split
__global__ void wsplit16_kernel(const float* __restrict__ W,
                                unsigned short* __restrict__ hi,
                                unsigned short* __restrict__ lo) {
  int i = blockIdx.x*256 + threadIdx.x;
  unsigned short h, l;
  hsplit(W[i], h, l);
  hi[i] = h; lo[i] = l;
}

// ---------------- embeddings ----------------
__global__ void embed3_kernel(const int* __restrict__ a_ids, const int* __restrict__ d_ids,
                              const int* __restrict__ a2_ids,
                              const float* __restrict__ ea, const float* __restrict__ ed,
                              const float* __restrict__ ea2,
                              float* __restrict__ ha, float* __restrict__ hd,
                              float* __restrict__ hg2) {
  int idx = blockIdx.x*256 + threadIdx.x;
  int n = idx >> 7, j = idx & 127;
  int w = blockIdx.y;
  if (w == 0)      ha[idx]  = ea[(size_t)a_ids[n]*128 + j];
  else if (w == 1) hd[idx]  = ed[(size_t)d_ids[n]*128 + j];
  else             hg2[idx] = ea2[(size_t)a2_ids[n]*128 + j];
}

// ---------------- generic fp32 GEMM (kept for transform + heads) ----------------
template<int BN, int ACT>
__global__ __launch_bounds__(256) void gemm_nt(
    const float* __restrict__ A0, const float* __restrict__ A1,
    const float* __restrict__ A2, const float* __restrict__ A3,
    int lda, const float* __restrict__ WT, const float* __restrict__ bias,
    float* __restrict__ C, int K, int beta)
{
  extern __shared__ float sm[];
  const int KP = K + 4;
  float* At = sm;
  float* Bc = sm + 32*KP;
  const int tid = threadIdx.x;
  const int m0 = blockIdx.x*32;
  const int ng = tid >> 5, cg = tid & 31;
  const int n0 = ng*4, c4 = cg*4;
  constexpr int G = BN/128;
  float acc[G][4][4];
#pragma unroll
  for (int g=0; g<G; ++g)
#pragma unroll
    for (int i=0;i<4;++i)
#pragma unroll
      for (int e=0;e<4;++e) acc[g][i][e] = 0.0f;

  const int nf4 = K >> 2;
  for (int idx = tid; idx < 32*nf4; idx += 256) {
    int row = idx / nf4;
    int kk = (idx - row*nf4) << 2;
    const float* Ap = (kk < 128) ? A0 : (kk < 256) ? A1 : (kk < 384) ? A2 : A3;
    float4 v = *(const float4*)(Ap + (size_t)(m0+row)*lda + (kk & 127));
    *(float4*)(At + row*KP + kk) = v;
  }
  const int nchunk = K >> 4;
  for (int kc = 0; kc < nchunk; ++kc) {
    __syncthreads();
    for (int idx = tid; idx < 16*(BN/4); idx += 256) {
      int kk = idx / (BN/4);
      int jq = idx - kk*(BN/4);
      *(float4*)(Bc + kk*BN + jq*4) = *(const float4*)(WT + (size_t)(kc*16+kk)*BN + jq*4);
    }
    __syncthreads();
    for (int k=0;k<16;++k) {
      const int kk = kc*16 + k;
      float av[4];
#pragma unroll
      for (int i=0;i<4;++i) av[i] = At[(n0+i)*KP + kk];
#pragma unroll
      for (int g=0; g<G; ++g) {
        float4 bv = *(const float4*)(Bc + k*BN + g*128 + c4);
        float bb[4] = {bv.x, bv.y, bv.z, bv.w};
#pragma unroll
        for (int i=0;i<4;++i)
#pragma unroll
          for (int e=0;e<4;++e)
            acc[g][i][e] += av[i]*bb[e];
      }
    }
  }
#pragma unroll
  for (int g=0; g<G; ++g) {
#pragma unroll
    for (int i=0;i<4;++i) {
      float* dst = C + (size_t)(m0+n0+i)*BN + g*128 + c4;
      float o[4];
#pragma unroll
      for (int e=0;e<4;++e) o[e] = acc[g][i][e];
      if (bias) {
#pragma unroll
        for (int e=0;e<4;++e) o[e] += bias[g*128 + c4 + e];
      }
      if (beta) {
        float4 p = *(const float4*)dst;
        o[0]+=p.x; o[1]+=p.y; o[2]+=p.z; o[3]+=p.w;
      }
      if (ACT==1) {
#pragma unroll
        for (int e=0;e<4;++e) o[e] = fmaxf(o[e], 0.0f);
      }
      *(float4*)dst = make_float4(o[0],o[1],o[2],o[3]);
    }
  }
}

// ---------------- MFMA GEMM: C[N,BN] = A[N,128] @ W[BN,128]^T + bias (+beta C) ----------------
__global__ __launch_bounds__(512) void mgemm(
    const float* __restrict__ A,
    const unsigned short* __restrict__ Whi, const unsigned short* __restrict__ Wlo,
    const float* __restrict__ bias, float* __restrict__ C, int BN, int ntpw, int beta)
{
  __shared__ unsigned short xhi[64*136];
  __shared__ unsigned short xlo[64*136];
  const int tid = threadIdx.x;
  const int w = tid >> 6;
  const int lane = tid & 63;
  const int ln16 = lane & 15;
  const int lq = lane >> 4;
  const int rb = blockIdx.x * 64;

  {
    const int r = tid >> 3;
    const int cf = (tid & 7) * 16;
    const float* src = A + (size_t)(rb + r)*128 + cf;
    unsigned short* dh = xhi + r*136 + cf;
    unsigned short* dl = xlo + r*136 + cf;
#pragma unroll
    for (int q=0; q<4; ++q) {
      float4 v = *(const float4*)(src + q*4);
      float vs[4] = {v.x, v.y, v.z, v.w};
      u16x4 ph, pl;
#pragma unroll
      for (int e=0;e<4;++e){ unsigned short h_,l_; hsplit(vs[e],h_,l_); ph[e]=h_; pl[e]=l_; }
      *(u16x4*)(dh + q*4) = ph;
      *(u16x4*)(dl + q*4) = pl;
    }
  }
  __syncthreads();

  for (int j=0; j<ntpw; ++j) {
    const int tile = w + j*8;
    f32x4 acc[4];
    if (bias) {
      f32x4 bv = *(const f32x4*)(bias + tile*16 + lq*4);
#pragma unroll
      for (int nt=0; nt<4; ++nt) acc[nt] = bv;
    } else {
#pragma unroll
      for (int nt=0; nt<4; ++nt)
#pragma unroll
        for (int e=0;e<4;++e) acc[nt][e] = 0.0f;
    }
#pragma unroll
    for (int kt=0; kt<4; ++kt) {
      const int bo = kt*32 + lq*8;
      f16x8 bxh[4], bxl[4];
#pragma unroll
      for (int nt=0; nt<4; ++nt) {
        bxh[nt] = *(const f16x8*)(xhi + (nt*16+ln16)*136 + bo);
        bxl[nt] = *(const f16x8*)(xlo + (nt*16+ln16)*136 + bo);
      }
      const size_t co = (size_t)(tile*16 + ln16)*128 + kt*32 + lq*8;
      f16x8 ah = *(const f16x8*)(Whi + co);
      f16x8 al = *(const f16x8*)(Wlo + co);
#pragma unroll
      for (int nt=0; nt<4; ++nt) {
        acc[nt] = __builtin_amdgcn_mfma_f32_16x16x32_f16(ah, bxh[nt], acc[nt], 0,0,0);
        acc[nt] = __builtin_amdgcn_mfma_f32_16x16x32_f16(ah, bxl[nt], acc[nt], 0,0,0);
        acc[nt] = __builtin_amdgcn_mfma_f32_16x16x32_f16(al, bxh[nt], acc[nt], 0,0,0);
      }
    }
#pragma unroll
    for (int nt=0; nt<4; ++nt) {
      float* dst = C + (size_t)(rb + nt*16 + ln16)*BN + tile*16 + lq*4;
      f32x4 o = acc[nt];
      if (beta) {
        float4 p = *(const float4*)dst;
        o[0]+=p.x; o[1]+=p.y; o[2]+=p.z; o[3]+=p.w;
      }
      *(float4*)dst = make_float4(o[0],o[1],o[2],o[3]);
    }
  }
}

// ---------------- fused LSTM v6: single-buffered LDS (33.8KB), 2 barriers/step ----------------
// 1024 blocks (b<512: a2d else d2a) x 64 nodes, 8 waves. Static shared.
// Per step: [A] barrier (x(t)+h(t-1) visible) -> pass1 WI.x -> issue gather t+1
// -> pass2 WH.h(t-1) -> [B] barrier (reads drained) -> activations -> write h(t)
// over h(t-1), stage x(t+1) over x(t).
__global__ __launch_bounds__(512) void lstm_fused6(
    float* __restrict__ hL,
    const unsigned short* __restrict__ fs16a, const unsigned short* __restrict__ fs16d,
    const int* __restrict__ nbrA, const int* __restrict__ nbrD,
    const unsigned short* __restrict__ WI0, const unsigned short* __restrict__ WH0,
    const unsigned short* __restrict__ WI1, const unsigned short* __restrict__ WH1,
    const float* __restrict__ bsum0, const float* __restrict__ bsum1)
{
  __shared__ unsigned short xb[64*132];
  __shared__ unsigned short hb[64*132];
  const int tid = threadIdx.x;
  const int w = tid >> 6;
  const int lane = tid & 63;
  const int ln16 = lane & 15;
  const int lq = lane >> 4;
  const int b = blockIdx.x;
  const bool dir = (b >= 512);
  const int nb = (dir ? (b - 512) : b) * 64;
  const unsigned short* fs16 = dir ? fs16d : fs16a;
  const int* nbr = dir ? nbrD : nbrA;
  const unsigned short* WI = dir ? WI1 : WI0;
  const unsigned short* WH = dir ? WH1 : WH0;
  const float* bsum = dir ? bsum1 : bsum0;

  const int gr = tid >> 3;
  const int gc = (tid & 7) * 16;
  const int* nrow = nbr + (size_t)(nb + gr)*DD;

  f32x4 bias[4];
#pragma unroll
  for (int g=0; g<4; ++g)
    bias[g] = *(const f32x4*)(bsum + g*128 + w*16 + lq*4);

  f32x4 cst[4];
#pragma unroll
  for (int nt=0; nt<4; ++nt)
#pragma unroll
    for (int e=0; e<4; ++e) cst[nt][e] = 0.0f;

  // prologue: gather + stage x(0)
  u16x8 xg0, xg1;
  {
    int gidx = nrow[0];
    const unsigned short* src = fs16 + (size_t)gidx*128 + gc;
    xg0 = *(const u16x8*)(src);
    xg1 = *(const u16x8*)(src + 8);
    unsigned short* d = xb + gr*132 + gc;
    *(u16x8*)d = xg0;
    *(u16x8*)(d+8) = xg1;
  }
  int gnext = nrow[1];

#pragma unroll 1
  for (int t=0; t<16; ++t) {
    __syncthreads();   // [A] x(t) staged + h(t-1) writes visible

    f32x4 racc[4][4];
#pragma unroll
    for (int g=0; g<4; ++g)
#pragma unroll
      for (int nt=0; nt<4; ++nt)
        racc[g][nt] = bias[g];

    // pass 1: WI . x(t)
#pragma unroll
    for (int kt=0; kt<4; ++kt) {
      const int bo = kt*32 + lq*8;
      f16x8 bx[4];
#pragma unroll
      for (int nt=0; nt<4; ++nt)
        bx[nt] = *(const f16x8*)(xb + (nt*16+ln16)*132 + bo);
#pragma unroll
      for (int g=0; g<4; ++g) {
        f16x8 aI = *(const f16x8*)(WI + (size_t)(g*128 + w*16 + ln16)*128 + kt*32 + lq*8);
#pragma unroll
        for (int nt=0; nt<4; ++nt)
          racc[g][nt] = __builtin_amdgcn_mfma_f32_16x16x32_f16(aI, bx[nt], racc[g][nt], 0,0,0);
      }
    }
    // issue gather for t+1 (latency hidden under pass 2)
    if (t < 15) {
      const unsigned short* src = fs16 + (size_t)gnext*128 + gc;
      xg0 = *(const u16x8*)(src);
      xg1 = *(const u16x8*)(src + 8);
      if (t < 14) gnext = nrow[t+2];
    }
    // pass 2: WH . h(t-1)
    if (t > 0) {
#pragma unroll
      for (int kt=0; kt<4; ++kt) {
        const int bo = kt*32 + lq*8;
        f16x8 bh[4];
#pragma unroll
        for (int nt=0; nt<4; ++nt)
          bh[nt] = *(const f16x8*)(hb + (nt*16+ln16)*132 + bo);
#pragma unroll
        for (int g=0; g<4; ++g) {
          f16x8 aH = *(const f16x8*)(WH + (size_t)(g*128 + w*16 + ln16)*128 + kt*32 + lq*8);
#pragma unroll
          for (int nt=0; nt<4; ++nt)
            racc[g][nt] = __builtin_amdgcn_mfma_f32_16x16x32_f16(aH, bh[nt], racc[g][nt], 0,0,0);
        }
      }
    }
    __syncthreads();   // [B] all x(t)/h(t-1) LDS reads drained

    // activations + cell update; overwrite h, stage x(t+1)
#pragma unroll
    for (int nt=0; nt<4; ++nt) {
      float hv[4];
#pragma unroll
      for (int e=0; e<4; ++e) {
        float ig = fsig(racc[0][nt][e]);
        float fg = fsig(racc[1][nt][e]);
        float gg = ftanh(racc[2][nt][e]);
        float og = fsig(racc[3][nt][e]);
        float cc = fg*cst[nt][e] + ig*gg;
        cst[nt][e] = cc;
        hv[e] = og*ftanh(cc);
      }
      const int node = nt*16 + ln16;
      const int col = w*16 + lq*4;
      if (t < 15) {
        u16x4 hw;
#pragma unroll
        for (int e=0; e<4; ++e) hw[e] = __half_as_ushort(__float2half_rn(hv[e]));
        *(u16x4*)(hb + node*132 + col) = hw;
      } else {
        *(float4*)(hL + (size_t)((dir?NN:0) + nb + node)*128 + col) =
            make_float4(hv[0], hv[1], hv[2], hv[3]);
      }
    }
    if (t < 15) {
      unsigned short* d = xb + gr*132 + gc;
      *(u16x8*)d = xg0;
      *(u16x8*)(d+8) = xg1;
    }
  }
}

// ---------------- GGC scatter-add ----------------
__global__ void scatter_add_kernel(float* __restrict__ a, const float* __restrict__ m,
                                   const int* __restrict__ src, const int* __restrict__ dst) {
  int wid = (blockIdx.x*256 + threadIdx.x) >> 6;
  int lane = threadIdx.x & 63;
  int s = src[wid], d = dst[wid];
  const float* mr = m + (size_t)s*128;
  float* ar = a + (size_t)d*128;
  atomicAdd(ar + lane, mr[lane]);
  atomicAdd(ar + 64 + lane, mr[64 + lane]);
}

// ---------------- GRU pointwise ----------------
__global__ void gru_update_kernel(float* __restrict__ hh, const float* __restrict__ gi,
                                  const float* __restrict__ gh) {
  int idx = blockIdx.x*256 + threadIdx.x;
  int n = idx >> 7, j = idx & 127;
  const float* gin = gi + (size_t)n*384;
  const float* ghn = gh + (size_t)n*384;
  float r  = fsig(gin[j] + ghn[j]);
  float z  = fsig(gin[128+j] + ghn[128+j]);
  float nn2 = ftanh(gin[256+j] + r*ghn[256+j]);
  float h = hh[idx];
  hh[idx] = (1.0f - z)*nn2 + z*h;
}

// ---------------- LayerNorm + leaky relu (optional fp16 shadow out) ----------------
__global__ void ln_lrelu_kernel(float* __restrict__ out, const float* __restrict__ x,
                                const float* __restrict__ add,
                                const float* __restrict__ g, const float* __restrict__ b,
                                unsigned short* __restrict__ out16) {
  int n = blockIdx.x, j = threadIdx.x;
  size_t base = (size_t)n*128;
  float v = x[base+j];
  if (add) v += add[base+j];
  __shared__ float sh[4];
  float s = v;
#pragma unroll
  for (int m=32; m>=1; m>>=1) s += __shfl_xor(s, m, 64);
  if ((j&63)==0) sh[j>>6] = s;
  __syncthreads();
  float mean = (sh[0]+sh[1]) * 0.0078125f;
  float d = v - mean;
  float q = d*d;
#pragma unroll
  for (int m=32; m>=1; m>>=1) q += __shfl_xor(q, m, 64);
  if ((j&63)==0) sh[2+(j>>6)] = q;
  __syncthreads();
  float var = (sh[2]+sh[3]) * 0.0078125f;
  float y = d * rsqrtf(var + 1e-5f) * g[j] + b[j];
  float o = (y >= 0.0f) ? y : 0.01f*y;
  out[base+j] = o;
  if (out16) out16[base+j] = __half_as_ushort(__float2half_rn(o));
}

// ---------------- segment mean ----------------
__global__ void segmean_kernel(float* __restrict__ out, const float* __restrict__ x,
                               const float* __restrict__ y) {
  int b = blockIdx.x, j = threadIdx.x;
  float s = 0.0f;
  for (int r=0; r<128; ++r) {
    size_t n = (size_t)(b*128 + r)*128 + j;
    s += x[n];
    if (y) s += y[n];
  }
  out[(size_t)b*128 + j] = s * 0.0078125f;
}

// ---------------- classifier head ----------------
__global__ void cls_kernel(float* __restrict__ out, const float* __restrict__ h2,
                           const float* __restrict__ Wc, const float* __restrict__ bc) {
  int gid = blockIdx.x*256 + threadIdx.x;
  if (gid >= BB*10) return;
  int mrow = gid/10, c = gid - mrow*10;
  const float* arow = h2 + (size_t)mrow*128;
  const float* wrow = Wc + (size_t)c*128;
  float s = bc[c];
  for (int k=0;k<128;++k) s += arow[k]*wrow[k];
  out[gid] = s;
}

__global__ void bail_kernel(float* out, float v) {
  if (threadIdx.x==0 && blockIdx.x==0) out[0] = v;
}

// ---------------- host orchestration ----------------
extern "C" void kernel_launch(void* const* d_in, const int* in_sizes, int n_in,
                              void* d_out, int out_size, void* d_ws, size_t ws_size,
                              hipStream_t stream)
{
  const int* act_ids  = (const int*)d_in[0];
  const int* dur_ids  = (const int*)d_in[1];
  const int* act2_ids = (const int*)d_in[2];
  const int* nbr_a2d  = (const int*)d_in[3];
  const int* nbr_d2a  = (const int*)d_in[4];
  const int* src2     = (const int*)d_in[5];
  const int* dst2     = (const int*)d_in[6];
  const float* emb_act     = (const float*)d_in[8];
  const float* emb_dur     = (const float*)d_in[9];
  const float* emb_act2    = (const float*)d_in[10];
  const float* transform_W = (const float*)d_in[11];
  const float* transform_b = (const float*)d_in[12];
  const float* ggc_W   = (const float*)d_in[13];
  const float* ggc_b   = (const float*)d_in[14];
  const float* gru_Wih = (const float*)d_in[15];
  const float* gru_Whh = (const float*)d_in[16];
  const float* gru_bih = (const float*)d_in[17];
  const float* gru_bhh = (const float*)d_in[18];
  const float* hn_g    = (const float*)d_in[19];
  const float* hn_b    = (const float*)d_in[20];
  const float* lstm_Wih = (const float*)d_in[21];
  const float* lstm_Whh = (const float*)d_in[22];
  const float* lstm_bih = (const float*)d_in[23];
  const float* lstm_bhh = (const float*)d_in[24];
  const float* fcs_W = (const float*)d_in[25];
  const float* fcs_b = (const float*)d_in[26];
  const float* fcn_W = (const float*)d_in[27];
  const float* fcn_b = (const float*)d_in[28];
  const float* n1_g = (const float*)d_in[29];
  const float* n1_b = (const float*)d_in[30];
  const float* n3_g = (const float*)d_in[31];
  const float* n3_b = (const float*)d_in[32];
  const float* mh_W1 = (const float*)d_in[33];
  const float* mh_b1 = (const float*)d_in[34];
  const float* mh_W2 = (const float*)d_in[35];
  const float* mh_b2 = (const float*)d_in[36];
  const float* mo_W1 = (const float*)d_in[37];
  const float* mo_b1 = (const float*)d_in[38];
  const float* mo_W2 = (const float*)d_in[39];
  const float* mo_b2 = (const float*)d_in[40];
  const float* mlp_W1 = (const float*)d_in[41];
  const float* mlp_b1 = (const float*)d_in[42];
  const float* mlp_W2 = (const float*)d_in[43];
  const float* mlp_b2 = (const float*)d_in[44];
  const float* cls_W = (const float*)d_in[45];
  const float* cls_b = (const float*)d_in[46];

  float* ws = (float*)d_ws;
  float* ha   = ws;
  float* hd   = ws + (size_t)NF;
  float* hg2  = ws + 2*(size_t)NF;
  float* res  = ws + 3*(size_t)NF;
  float* hh   = ws + 4*(size_t)NF;
  float* SCR  = ws + 5*(size_t)NF;
  float* mb   = SCR;
  float* abuf = SCR + (size_t)NF;
  float* gi   = SCR + 2*(size_t)NF;
  float* gh   = SCR + 5*(size_t)NF;
  float* hnf  = mb;
  float* hLb  = SCR + 8*(size_t)NF;
  float* SMALL = ws + 15*(size_t)NF;
  float* hg2m = SMALL;
  float* hgm  = SMALL + 32768;
  float* o1b  = SMALL + 65536;
  float* o2b  = SMALL + 98304;
  float* t1b  = SMALL + 131072;
  float* t2b  = SMALL + 163840;
  float* h1b  = SMALL + 196608;
  float* h2b  = SMALL + 262144;
  float* bsum = SMALL + 294912;
  float* WTb  = SMALL + 296960;
  const size_t NEED_BYTES = (size_t)(15*(size_t)NF + 296960 + 1032192) * 4;
  if (ws_size < NEED_BYTES) {
    hipMemsetAsync(d_out, 0, (size_t)out_size*sizeof(float), stream);
    bail_kernel<<<1,64,0,stream>>>((float*)d_out, (float)ws_size);
    return;
  }
  float* na = hg2;
  float* nd = res;
  // fp16 feature tables: placed in SCR+2NF..3NF (free after GGC phase)
  unsigned short* fs16a = (unsigned short*)(SCR + 2*(size_t)NF);
  unsigned short* fs16d = fs16a + (size_t)NF;

  const int O_TRANSFORM = 0;
  const int O_SPLIT    = 147456;
  const int O_SPLIT2   = 409600;
  const int O_MH1      = 802816;
  const int O_MH2      = 819200;
  const int O_MO1      = 835584;
  const int O_MO2      = 851968;
  const int O_MLP1     = 868352;
  const int O_MLP2     = 999424;

  unsigned short* WI16 = (unsigned short*)(WTb + O_SPLIT);
  unsigned short* WH16 = WI16 + 4*65536;

  unsigned short* SP2 = (unsigned short*)(WTb + O_SPLIT2);
  unsigned short* GGChi = SP2;                 unsigned short* GGClo = GGChi + 16384;
  unsigned short* GIHhi = GGClo + 16384;       unsigned short* GIHlo = GIHhi + 49152;
  unsigned short* GHHhi = GIHlo + 49152;       unsigned short* GHHlo = GHHhi + 49152;
  unsigned short* FCShi = GHHlo + 49152;       unsigned short* FCSlo = FCShi + 65536;
  unsigned short* FCNhi = FCSlo + 65536;       unsigned short* FCNlo = FCNhi + 65536;

  TDescArr da;
  int di = 0;
  auto addT = [&](const float* s, float* d, int R, int C){ da.d[di].src=s; da.d[di].dst=d; da.d[di].R=R; da.d[di].C=C; ++di; };
  addT(transform_W, WTb + O_TRANSFORM, 128, 256);
  addT(mh_W1, WTb + O_MH1, 128, 128);
  addT(mh_W2, WTb + O_MH2, 128, 128);
  addT(mo_W1, WTb + O_MO1, 128, 128);
  addT(mo_W2, WTb + O_MO2, 128, 128);
  addT(mlp_W1, WTb + O_MLP1, 256, 512);
  addT(mlp_W2, WTb + O_MLP2, 128, 256);
  transpose_many<<<dim3(512, di), 256, 0, stream>>>(da);
  bias_sum_kernel<<<8, 256, 0, stream>>>(lstm_bih, lstm_bhh, bsum);
  f32to16_kernel<<<(4*512*128)/1024, 256, 0, stream>>>(lstm_Wih, WI16);
  f32to16_kernel<<<(4*512*128)/1024, 256, 0, stream>>>(lstm_Whh, WH16);
  wsplit16_kernel<<<16384/256, 256, 0, stream>>>(ggc_W, GGChi, GGClo);
  wsplit16_kernel<<<49152/256, 256, 0, stream>>>(gru_Wih, GIHhi, GIHlo);
  wsplit16_kernel<<<49152/256, 256, 0, stream>>>(gru_Whh, GHHhi, GHHlo);
  wsplit16_kernel<<<65536/256, 256, 0, stream>>>(fcs_W, FCShi, FCSlo);
  wsplit16_kernel<<<65536/256, 256, 0, stream>>>(fcn_W, FCNhi, FCNlo);

  auto smemK = [](int K, int BN){ return (size_t)(32*(K+4) + 16*BN)*4; };
  const int gN = NN/32;
  const int gB = BB/32;
  const int gM = NN/64;

  embed3_kernel<<<dim3(NF/256, 3), 256, 0, stream>>>(act_ids, dur_ids, act2_ids,
      emb_act, emb_dur, emb_act2, ha, hd, hg2);
  gemm_nt<128,0><<<gN, 256, smemK(256,128), stream>>>(hg2, hd, nullptr, nullptr, 128,
      WTb + O_TRANSFORM, transform_b, res, 256, 0);
  hipMemcpyAsync(hh, res, (size_t)NF*4, hipMemcpyDeviceToDevice, stream);

  for (int it=0; it<2; ++it) {
    mgemm<<<gM, 512, 0, stream>>>(hh, GGChi, GGClo, ggc_b, mb, 128, 1, 0);
    hipMemsetAsync(abuf, 0, (size_t)NF*4, stream);
    scatter_add_kernel<<<E2N/4, 256, 0, stream>>>(abuf, mb, src2, dst2);
    mgemm<<<gM, 512, 0, stream>>>(abuf, GIHhi, GIHlo, gru_bih, gi, 384, 3, 0);
    mgemm<<<gM, 512, 0, stream>>>(hh, GHHhi, GHHlo, gru_bhh, gh, 384, 3, 0);
    gru_update_kernel<<<NF/256, 256, 0, stream>>>(hh, gi, gh);
  }
  ln_lrelu_kernel<<<NN, 128, 0, stream>>>(hnf, hh, res, hn_g, hn_b, nullptr);
  segmean_kernel<<<BB, 128, 0, stream>>>(hg2m, hnf, nullptr);

  // layer-0 fp16 feature tables (layer-1 tables are written by ln3's epilogue)
  f32to16_kernel<<<NF/1024, 256, 0, stream>>>(ha, fs16a);
  f32to16_kernel<<<NF/1024, 256, 0, stream>>>(hd, fs16d);

  for (int l=0; l<2; ++l) {
    const int i0 = l*2 + 0, i1 = l*2 + 1;
    lstm_fused6<<<1024, 512, 0, stream>>>(hLb, fs16a, fs16d, nbr_a2d, nbr_d2a,
        WI16 + i0*65536, WH16 + i0*65536,
        WI16 + i1*65536, WH16 + i1*65536,
        bsum + i0*512, bsum + i1*512);

    mgemm<<<gM, 512, 0, stream>>>(hd, FCShi + i0*16384, FCSlo + i0*16384, fcs_b + i0*128, nd, 128, 1, 0);
    mgemm<<<gM, 512, 0, stream>>>(hLb, FCNhi + i0*16384, FCNlo + i0*16384, fcn_b + i0*128, nd, 128, 1, 1);
    mgemm<<<gM, 512, 0, stream>>>(ha, FCShi + i1*16384, FCSlo + i1*16384, fcs_b + i1*128, na, 128, 1, 0);
    mgemm<<<gM, 512, 0, stream>>>(hLb + (size_t)NN*128, FCNhi + i1*16384, FCNlo + i1*16384, fcn_b + i1*128, na, 128, 1, 1);
    ln_lrelu_kernel<<<NN, 128, 0, stream>>>(na, na, nullptr, n1_g + i0*128, n1_b + i0*128, nullptr);
    ln_lrelu_kernel<<<NN, 128, 0, stream>>>(nd, nd, nullptr, n1_g + i1*128, n1_b + i1*128, nullptr);
    ln_lrelu_kernel<<<NN, 128, 0, stream>>>(ha, ha, na, n3_g + i0*128, n3_b + i0*128,
        (l==0) ? fs16a : nullptr);
    ln_lrelu_kernel<<<NN, 128, 0, stream>>>(hd, hd, nd, n3_g + i1*128, n3_b + i1*128,
        (l==0) ? fs16d : nullptr);
  }
  segmean_kernel<<<BB, 128, 0, stream>>>(hgm, ha, hd);

  gemm_nt<128,1><<<gB, 256, smemK(128,128), stream>>>(hg2m, nullptr, nullptr, nullptr, 128,
      WTb + O_MO1, mo_b1, t1b, 128, 0);
  gemm_nt<128,1><<<gB, 256, smemK(128,128), stream>>>(t1b, nullptr, nullptr, nullptr, 128,
      WTb + O_MO2, mo_b2, o1b, 128, 0);
  gemm_nt<128,1><<<gB, 256, smemK(128,128), stream>>>(hgm, nullptr, nullptr, nullptr, 128,
      WTb + O_MH1, mh_b1, t2b, 128, 0);
  gemm_nt<128,1><<<gB, 256, smemK(128,128), stream>>>(t2b, nullptr, nullptr, nullptr, 128,
      WTb + O_MH2, mh_b2, o2b, 128, 0);
  gemm_nt<256,0><<<gB, 256, smemK(256,256), stream>>>(o1b, hg2m, nullptr, nullptr, 128,
      WTb + O_MLP1, nullptr, h1b, 256, 0);
  gemm_nt<256,1><<<gB, 256, smemK(256,256), stream>>>(o2b, hgm, nullptr, nullptr, 128,
      WTb + O_MLP1 + 256*256, mlp_b1, h1b, 256, 1);
  gemm_nt<128,1><<<gB, 256, smemK(256,128), stream>>>(h1b, h1b + 128, nullptr, nullptr, 256,
      WTb + O_MLP2, mlp_b2, h2b, 256, 0);
  cls_kernel<<<10, 256, 0, stream>>>((float*)d_out, h2b, cls_W, cls_b);
}

// Round 16
// 1923.992 us; speedup vs baseline: 2.7761x; 1.0869x over previous
//
#include <hip/hip_runtime.h>
#include <hip/hip_fp16.h>
#include <math.h>

#define NN 32768
#define HH 128
#define DD 16
#define BB 256
#define E2N (NN*DD)
#define NF (NN*HH)

typedef __attribute__((ext_vector_type(4))) float f32x4;
typedef __attribute__((ext_vector_type(4))) unsigned short u16x4;
typedef __attribute__((ext_vector_type(8))) unsigned short u16x8;
typedef _Float16 f16x8 __attribute__((ext_vector_type(8)));

__device__ __forceinline__ float fsig(float x) {
  return __builtin_amdgcn_rcpf(1.0f + __builtin_amdgcn_exp2f(-1.442695041f*x));
}
__device__ __forceinline__ float ftanh(float x) {
  return 1.0f - 2.0f*__builtin_amdgcn_rcpf(1.0f + __builtin_amdgcn_exp2f(2.885390082f*x));
}
__device__ __forceinline__ void hsplit(float x, unsigned short& h, unsigned short& l) {
  __half hh_ = __float2half_rn(x);
  h = __half_as_ushort(hh_);
  l = __half_as_ushort(__float2half_rn(x - __half2float(hh_)));
}

// ---------------- transpose prep (head weights -> [K][Nout]) ----------------
struct TDesc { const float* src; float* dst; int R; int C; };
struct TDescArr { TDesc d[8]; };

__global__ void transpose_many(TDescArr da) {
  TDesc t = da.d[blockIdx.y];
  int idx = blockIdx.x*256 + threadIdx.x;
  if (idx < t.R*t.C) {
    int r = idx / t.C, c = idx - r*t.C;
    t.dst[(size_t)c*t.R + r] = t.src[idx];
  }
}

__global__ void bias_sum_kernel(const float* __restrict__ bih, const float* __restrict__ bhh,
                                float* __restrict__ bsum) {
  int i = blockIdx.x*256 + threadIdx.x;
  if (i < 2048) bsum[i] = bih[i] + bhh[i];
}

__global__ void f32to16_kernel(const float* __restrict__ in, unsigned short* __restrict__ out) {
  int base = (blockIdx.x*256 + threadIdx.x) * 4;
  float4 v = *(const float4*)(in + base);
  u16x4 p;
  p[0] = __half_as_ushort(__float2half_rn(v.x));
  p[1] = __half_as_ushort(__float2half_rn(v.y));
  p[2] = __half_as_ushort(__float2half_rn(v.z));
  p[3] = __half_as_ushort(__float2half_rn(v.w));
  *(u16x4*)(out + base) = p;
}

__global__ void wsplit16_kernel(const float* __restrict__ W,
                                unsigned short* __restrict__ hi,
                                unsigned short* __restrict__ lo) {
  int i = blockIdx.x*256 + threadIdx.x;
  unsigned short h, l;
  hsplit(W[i], h, l);
  hi[i] = h; lo[i] = l;
}

// ---------------- embeddings ----------------
__global__ void embed3_kernel(const int* __restrict__ a_ids, const int* __restrict__ d_ids,
                              const int* __restrict__ a2_ids,
                              const float* __restrict__ ea, const float* __restrict__ ed,
                              const float* __restrict__ ea2,
                              float* __restrict__ ha, float* __restrict__ hd,
                              float* __restrict__ hg2) {
  int idx = blockIdx.x*256 + threadIdx.x;
  int n = idx >> 7, j = idx & 127;
  int w = blockIdx.y;
  if (w == 0)      ha[idx]  = ea[(size_t)a_ids[n]*128 + j];
  else if (w == 1) hd[idx]  = ed[(size_t)d_ids[n]*128 + j];
  else             hg2[idx] = ea2[(size_t)a2_ids[n]*128 + j];
}

// ---------------- generic fp32 GEMM (heads only) ----------------
template<int BN, int ACT>
__global__ __launch_bounds__(256) void gemm_nt(
    const float* __restrict__ A0, const float* __restrict__ A1,
    const float* __restrict__ A2, const float* __restrict__ A3,
    int lda, const float* __restrict__ WT, const float* __restrict__ bias,
    float* __restrict__ C, int K, int beta)
{
  extern __shared__ float sm[];
  const int KP = K + 4;
  float* At = sm;
  float* Bc = sm + 32*KP;
  const int tid = threadIdx.x;
  const int m0 = blockIdx.x*32;
  const int ng = tid >> 5, cg = tid & 31;
  const int n0 = ng*4, c4 = cg*4;
  constexpr int G = BN/128;
  float acc[G][4][4];
#pragma unroll
  for (int g=0; g<G; ++g)
#pragma unroll
    for (int i=0;i<4;++i)
#pragma unroll
      for (int e=0;e<4;++e) acc[g][i][e] = 0.0f;

  const int nf4 = K >> 2;
  for (int idx = tid; idx < 32*nf4; idx += 256) {
    int row = idx / nf4;
    int kk = (idx - row*nf4) << 2;
    const float* Ap = (kk < 128) ? A0 : (kk < 256) ? A1 : (kk < 384) ? A2 : A3;
    float4 v = *(const float4*)(Ap + (size_t)(m0+row)*lda + (kk & 127));
    *(float4*)(At + row*KP + kk) = v;
  }
  const int nchunk = K >> 4;
  for (int kc = 0; kc < nchunk; ++kc) {
    __syncthreads();
    for (int idx = tid; idx < 16*(BN/4); idx += 256) {
      int kk = idx / (BN/4);
      int jq = idx - kk*(BN/4);
      *(float4*)(Bc + kk*BN + jq*4) = *(const float4*)(WT + (size_t)(kc*16+kk)*BN + jq*4);
    }
    __syncthreads();
    for (int k=0;k<16;++k) {
      const int kk = kc*16 + k;
      float av[4];
#pragma unroll
      for (int i=0;i<4;++i) av[i] = At[(n0+i)*KP + kk];
#pragma unroll
      for (int g=0; g<G; ++g) {
        float4 bv = *(const float4*)(Bc + k*BN + g*128 + c4);
        float bb[4] = {bv.x, bv.y, bv.z, bv.w};
#pragma unroll
        for (int i=0;i<4;++i)
#pragma unroll
          for (int e=0;e<4;++e)
            acc[g][i][e] += av[i]*bb[e];
      }
    }
  }
#pragma unroll
  for (int g=0; g<G; ++g) {
#pragma unroll
    for (int i=0;i<4;++i) {
      float* dst = C + (size_t)(m0+n0+i)*BN + g*128 + c4;
      float o[4];
#pragma unroll
      for (int e=0;e<4;++e) o[e] = acc[g][i][e];
      if (bias) {
#pragma unroll
        for (int e=0;e<4;++e) o[e] += bias[g*128 + c4 + e];
      }
      if (beta) {
        float4 p = *(const float4*)dst;
        o[0]+=p.x; o[1]+=p.y; o[2]+=p.z; o[3]+=p.w;
      }
      if (ACT==1) {
#pragma unroll
        for (int e=0;e<4;++e) o[e] = fmaxf(o[e], 0.0f);
      }
      *(float4*)dst = make_float4(o[0],o[1],o[2],o[3]);
    }
  }
}

// ---------------- LDS staging helper (fp32 rows -> fp16 hi/lo tiles) ----------------
__device__ __forceinline__ void stage_hi_lo(const float* __restrict__ A, int rb, int tid,
                                            unsigned short* xhi, unsigned short* xlo) {
  const int r = tid >> 3;
  const int cf = (tid & 7) * 16;
  const float* src = A + (size_t)(rb + r)*128 + cf;
  unsigned short* dh = xhi + r*136 + cf;
  unsigned short* dl = xlo + r*136 + cf;
#pragma unroll
  for (int q=0; q<4; ++q) {
    float4 v = *(const float4*)(src + q*4);
    float vs[4] = {v.x, v.y, v.z, v.w};
    u16x4 ph, pl;
#pragma unroll
    for (int e=0;e<4;++e){ unsigned short h_,l_; hsplit(vs[e],h_,l_); ph[e]=h_; pl[e]=l_; }
    *(u16x4*)(dh + q*4) = ph;
    *(u16x4*)(dl + q*4) = pl;
  }
}

// ---------------- MFMA GEMM single-input: C = A@W^T + bias ----------------
__global__ __launch_bounds__(512) void mgemm(
    const float* __restrict__ A,
    const unsigned short* __restrict__ Whi, const unsigned short* __restrict__ Wlo,
    const float* __restrict__ bias, float* __restrict__ C, int BN, int ntpw)
{
  __shared__ unsigned short xhi[64*136];
  __shared__ unsigned short xlo[64*136];
  const int tid = threadIdx.x;
  const int w = tid >> 6;
  const int lane = tid & 63;
  const int ln16 = lane & 15;
  const int lq = lane >> 4;
  const int rb = blockIdx.x * 64;
  stage_hi_lo(A, rb, tid, xhi, xlo);
  __syncthreads();

  for (int j=0; j<ntpw; ++j) {
    const int tile = w + j*8;
    f32x4 acc[4];
    f32x4 bv = *(const f32x4*)(bias + tile*16 + lq*4);
#pragma unroll
    for (int nt=0; nt<4; ++nt) acc[nt] = bv;
#pragma unroll
    for (int kt=0; kt<4; ++kt) {
      const int bo = kt*32 + lq*8;
      f16x8 bxh[4], bxl[4];
#pragma unroll
      for (int nt=0; nt<4; ++nt) {
        bxh[nt] = *(const f16x8*)(xhi + (nt*16+ln16)*136 + bo);
        bxl[nt] = *(const f16x8*)(xlo + (nt*16+ln16)*136 + bo);
      }
      const size_t co = (size_t)(tile*16 + ln16)*128 + kt*32 + lq*8;
      f16x8 ah = *(const f16x8*)(Whi + co);
      f16x8 al = *(const f16x8*)(Wlo + co);
#pragma unroll
      for (int nt=0; nt<4; ++nt) {
        acc[nt] = __builtin_amdgcn_mfma_f32_16x16x32_f16(ah, bxh[nt], acc[nt], 0,0,0);
        acc[nt] = __builtin_amdgcn_mfma_f32_16x16x32_f16(ah, bxl[nt], acc[nt], 0,0,0);
        acc[nt] = __builtin_amdgcn_mfma_f32_16x16x32_f16(al, bxh[nt], acc[nt], 0,0,0);
      }
    }
#pragma unroll
    for (int nt=0; nt<4; ++nt) {
      f32x4 o = acc[nt];
      *(float4*)(C + (size_t)(rb + nt*16 + ln16)*BN + tile*16 + lq*4) =
          make_float4(o[0],o[1],o[2],o[3]);
    }
  }
}

// ---------------- MFMA GEMM dual-input: C = A1@W1^T + A2@W2^T + b1 (+b2) ----------------
// BN=128. W row stride = wstride (halfs).
__global__ __launch_bounds__(512) void mgemm2(
    const float* __restrict__ A1,
    const unsigned short* __restrict__ W1hi, const unsigned short* __restrict__ W1lo,
    const float* __restrict__ A2,
    const unsigned short* __restrict__ W2hi, const unsigned short* __restrict__ W2lo,
    const float* __restrict__ bias1, const float* __restrict__ bias2,
    float* __restrict__ C, int wstride)
{
  extern __shared__ unsigned short sm16[];
  unsigned short* x1hi = sm16;
  unsigned short* x1lo = sm16 + 8704;
  unsigned short* x2hi = sm16 + 17408;
  unsigned short* x2lo = sm16 + 26112;
  const int tid = threadIdx.x;
  const int w = tid >> 6;
  const int lane = tid & 63;
  const int ln16 = lane & 15;
  const int lq = lane >> 4;
  const int rb = blockIdx.x * 64;
  stage_hi_lo(A1, rb, tid, x1hi, x1lo);
  stage_hi_lo(A2, rb, tid, x2hi, x2lo);
  __syncthreads();

  f32x4 acc[4];
  {
    f32x4 bv = *(const f32x4*)(bias1 + w*16 + lq*4);
    if (bias2) {
      f32x4 b2 = *(const f32x4*)(bias2 + w*16 + lq*4);
#pragma unroll
      for (int e=0;e<4;++e) bv[e] += b2[e];
    }
#pragma unroll
    for (int nt=0; nt<4; ++nt) acc[nt] = bv;
  }
#pragma unroll
  for (int p=0; p<2; ++p) {
    const unsigned short* xh = p ? x2hi : x1hi;
    const unsigned short* xl = p ? x2lo : x1lo;
    const unsigned short* Wh = p ? W2hi : W1hi;
    const unsigned short* Wl = p ? W2lo : W1lo;
#pragma unroll
    for (int kt=0; kt<4; ++kt) {
      const int bo = kt*32 + lq*8;
      f16x8 bxh[4], bxl[4];
#pragma unroll
      for (int nt=0; nt<4; ++nt) {
        bxh[nt] = *(const f16x8*)(xh + (nt*16+ln16)*136 + bo);
        bxl[nt] = *(const f16x8*)(xl + (nt*16+ln16)*136 + bo);
      }
      const size_t co = (size_t)(w*16 + ln16)*wstride + kt*32 + lq*8;
      f16x8 ah = *(const f16x8*)(Wh + co);
      f16x8 al = *(const f16x8*)(Wl + co);
#pragma unroll
      for (int nt=0; nt<4; ++nt) {
        acc[nt] = __builtin_amdgcn_mfma_f32_16x16x32_f16(ah, bxh[nt], acc[nt], 0,0,0);
        acc[nt] = __builtin_amdgcn_mfma_f32_16x16x32_f16(ah, bxl[nt], acc[nt], 0,0,0);
        acc[nt] = __builtin_amdgcn_mfma_f32_16x16x32_f16(al, bxh[nt], acc[nt], 0,0,0);
      }
    }
  }
#pragma unroll
  for (int nt=0; nt<4; ++nt) {
    f32x4 o = acc[nt];
    *(float4*)(C + (size_t)(rb + nt*16 + ln16)*128 + w*16 + lq*4) =
        make_float4(o[0],o[1],o[2],o[3]);
  }
}

// ---------------- fused GRU: hh = GRU(a@Wih^T+bih, hh@Whh^T+bhh, hh) ----------------
// BN=384 via 3 gate-tiles/wave; tile j has outcol 128*j + c (same c) -> all gates
// lane-local. h_old re-read from global (block owns rows exclusively).
__global__ __launch_bounds__(512) void gru_fused(
    const float* __restrict__ abuf, float* __restrict__ hh,
    const unsigned short* __restrict__ GIhi, const unsigned short* __restrict__ GIlo,
    const unsigned short* __restrict__ GHhi, const unsigned short* __restrict__ GHlo,
    const float* __restrict__ bih, const float* __restrict__ bhh)
{
  extern __shared__ unsigned short sm16[];
  unsigned short* xhi = sm16;
  unsigned short* xlo = sm16 + 8704;
  unsigned short* hhi = sm16 + 17408;
  unsigned short* hlo = sm16 + 26112;
  const int tid = threadIdx.x;
  const int w = tid >> 6;
  const int lane = tid & 63;
  const int ln16 = lane & 15;
  const int lq = lane >> 4;
  const int rb = blockIdx.x * 64;
  stage_hi_lo(abuf, rb, tid, xhi, xlo);
  stage_hi_lo(hh, rb, tid, hhi, hlo);
  __syncthreads();

  f32x4 rr[4], zz[4], nn_[4];
#pragma unroll
  for (int j=0; j<3; ++j) {
    const int tile = w + j*8;
    f32x4 ai[4], ag[4];
    f32x4 bi = *(const f32x4*)(bih + tile*16 + lq*4);
    f32x4 bg = *(const f32x4*)(bhh + tile*16 + lq*4);
#pragma unroll
    for (int nt=0; nt<4; ++nt) { ai[nt] = bi; ag[nt] = bg; }
#pragma unroll
    for (int kt=0; kt<4; ++kt) {
      const int bo = kt*32 + lq*8;
      f16x8 bxh[4], bxl[4], bhh_[4], bhl_[4];
#pragma unroll
      for (int nt=0; nt<4; ++nt) {
        bxh[nt] = *(const f16x8*)(xhi + (nt*16+ln16)*136 + bo);
        bxl[nt] = *(const f16x8*)(xlo + (nt*16+ln16)*136 + bo);
        bhh_[nt] = *(const f16x8*)(hhi + (nt*16+ln16)*136 + bo);
        bhl_[nt] = *(const f16x8*)(hlo + (nt*16+ln16)*136 + bo);
      }
      const size_t co = (size_t)(tile*16 + ln16)*128 + kt*32 + lq*8;
      f16x8 ih = *(const f16x8*)(GIhi + co);
      f16x8 il = *(const f16x8*)(GIlo + co);
      f16x8 gh = *(const f16x8*)(GHhi + co);
      f16x8 gl = *(const f16x8*)(GHlo + co);
#pragma unroll
      for (int nt=0; nt<4; ++nt) {
        ai[nt] = __builtin_amdgcn_mfma_f32_16x16x32_f16(ih, bxh[nt], ai[nt], 0,0,0);
        ai[nt] = __builtin_amdgcn_mfma_f32_16x16x32_f16(ih, bxl[nt], ai[nt], 0,0,0);
        ai[nt] = __builtin_amdgcn_mfma_f32_16x16x32_f16(il, bxh[nt], ai[nt], 0,0,0);
        ag[nt] = __builtin_amdgcn_mfma_f32_16x16x32_f16(gh, bhh_[nt], ag[nt], 0,0,0);
        ag[nt] = __builtin_amdgcn_mfma_f32_16x16x32_f16(gh, bhl_[nt], ag[nt], 0,0,0);
        ag[nt] = __builtin_amdgcn_mfma_f32_16x16x32_f16(gl, bhh_[nt], ag[nt], 0,0,0);
      }
    }
#pragma unroll
    for (int nt=0; nt<4; ++nt) {
#pragma unroll
      for (int e=0; e<4; ++e) {
        if (j == 0)      rr[nt][e] = fsig(ai[nt][e] + ag[nt][e]);
        else if (j == 1) zz[nt][e] = fsig(ai[nt][e] + ag[nt][e]);
        else             nn_[nt][e] = ftanh(ai[nt][e] + rr[nt][e]*ag[nt][e]);
      }
    }
  }
  // h' = (1-z)*n + z*h_old
#pragma unroll
  for (int nt=0; nt<4; ++nt) {
    float* hp = hh + (size_t)(rb + nt*16 + ln16)*128 + w*16 + lq*4;
    float4 ho = *(const float4*)hp;
    float hv[4] = {ho.x, ho.y, ho.z, ho.w};
    float o[4];
#pragma unroll
    for (int e=0; e<4; ++e)
      o[e] = (1.0f - zz[nt][e])*nn_[nt][e] + zz[nt][e]*hv[e];
    *(float4*)hp = make_float4(o[0],o[1],o[2],o[3]);
  }
}

// ---------------- fused LSTM v6 (unchanged from R15) ----------------
__global__ __launch_bounds__(512) void lstm_fused6(
    float* __restrict__ hL,
    const unsigned short* __restrict__ fs16a, const unsigned short* __restrict__ fs16d,
    const int* __restrict__ nbrA, const int* __restrict__ nbrD,
    const unsigned short* __restrict__ WI0, const unsigned short* __restrict__ WH0,
    const unsigned short* __restrict__ WI1, const unsigned short* __restrict__ WH1,
    const float* __restrict__ bsum0, const float* __restrict__ bsum1)
{
  __shared__ unsigned short xb[64*132];
  __shared__ unsigned short hb[64*132];
  const int tid = threadIdx.x;
  const int w = tid >> 6;
  const int lane = tid & 63;
  const int ln16 = lane & 15;
  const int lq = lane >> 4;
  const int b = blockIdx.x;
  const bool dir = (b >= 512);
  const int nb = (dir ? (b - 512) : b) * 64;
  const unsigned short* fs16 = dir ? fs16d : fs16a;
  const int* nbr = dir ? nbrD : nbrA;
  const unsigned short* WI = dir ? WI1 : WI0;
  const unsigned short* WH = dir ? WH1 : WH0;
  const float* bsum = dir ? bsum1 : bsum0;

  const int gr = tid >> 3;
  const int gc = (tid & 7) * 16;
  const int* nrow = nbr + (size_t)(nb + gr)*DD;

  f32x4 bias[4];
#pragma unroll
  for (int g=0; g<4; ++g)
    bias[g] = *(const f32x4*)(bsum + g*128 + w*16 + lq*4);

  f32x4 cst[4];
#pragma unroll
  for (int nt=0; nt<4; ++nt)
#pragma unroll
    for (int e=0; e<4; ++e) cst[nt][e] = 0.0f;

  u16x8 xg0, xg1;
  {
    int gidx = nrow[0];
    const unsigned short* src = fs16 + (size_t)gidx*128 + gc;
    xg0 = *(const u16x8*)(src);
    xg1 = *(const u16x8*)(src + 8);
    unsigned short* d = xb + gr*132 + gc;
    *(u16x8*)d = xg0;
    *(u16x8*)(d+8) = xg1;
  }
  int gnext = nrow[1];

#pragma unroll 1
  for (int t=0; t<16; ++t) {
    __syncthreads();

    f32x4 racc[4][4];
#pragma unroll
    for (int g=0; g<4; ++g)
#pragma unroll
      for (int nt=0; nt<4; ++nt)
        racc[g][nt] = bias[g];

#pragma unroll
    for (int kt=0; kt<4; ++kt) {
      const int bo = kt*32 + lq*8;
      f16x8 bx[4];
#pragma unroll
      for (int nt=0; nt<4; ++nt)
        bx[nt] = *(const f16x8*)(xb + (nt*16+ln16)*132 + bo);
#pragma unroll
      for (int g=0; g<4; ++g) {
        f16x8 aI = *(const f16x8*)(WI + (size_t)(g*128 + w*16 + ln16)*128 + kt*32 + lq*8);
#pragma unroll
        for (int nt=0; nt<4; ++nt)
          racc[g][nt] = __builtin_amdgcn_mfma_f32_16x16x32_f16(aI, bx[nt], racc[g][nt], 0,0,0);
      }
    }
    if (t < 15) {
      const unsigned short* src = fs16 + (size_t)gnext*128 + gc;
      xg0 = *(const u16x8*)(src);
      xg1 = *(const u16x8*)(src + 8);
      if (t < 14) gnext = nrow[t+2];
    }
    if (t > 0) {
#pragma unroll
      for (int kt=0; kt<4; ++kt) {
        const int bo = kt*32 + lq*8;
        f16x8 bh[4];
#pragma unroll
        for (int nt=0; nt<4; ++nt)
          bh[nt] = *(const f16x8*)(hb + (nt*16+ln16)*132 + bo);
#pragma unroll
        for (int g=0; g<4; ++g) {
          f16x8 aH = *(const f16x8*)(WH + (size_t)(g*128 + w*16 + ln16)*128 + kt*32 + lq*8);
#pragma unroll
          for (int nt=0; nt<4; ++nt)
            racc[g][nt] = __builtin_amdgcn_mfma_f32_16x16x32_f16(aH, bh[nt], racc[g][nt], 0,0,0);
        }
      }
    }
    __syncthreads();

#pragma unroll
    for (int nt=0; nt<4; ++nt) {
      float hv[4];
#pragma unroll
      for (int e=0; e<4; ++e) {
        float ig = fsig(racc[0][nt][e]);
        float fg = fsig(racc[1][nt][e]);
        float gg = ftanh(racc[2][nt][e]);
        float og = fsig(racc[3][nt][e]);
        float cc = fg*cst[nt][e] + ig*gg;
        cst[nt][e] = cc;
        hv[e] = og*ftanh(cc);
      }
      const int node = nt*16 + ln16;
      const int col = w*16 + lq*4;
      if (t < 15) {
        u16x4 hw;
#pragma unroll
        for (int e=0; e<4; ++e) hw[e] = __half_as_ushort(__float2half_rn(hv[e]));
        *(u16x4*)(hb + node*132 + col) = hw;
      } else {
        *(float4*)(hL + (size_t)((dir?NN:0) + nb + node)*128 + col) =
            make_float4(hv[0], hv[1], hv[2], hv[3]);
      }
    }
    if (t < 15) {
      unsigned short* d = xb + gr*132 + gc;
      *(u16x8*)d = xg0;
      *(u16x8*)(d+8) = xg1;
    }
  }
}

// ---------------- GGC scatter-add ----------------
__global__ void scatter_add_kernel(float* __restrict__ a, const float* __restrict__ m,
                                   const int* __restrict__ src, const int* __restrict__ dst) {
  int wid = (blockIdx.x*256 + threadIdx.x) >> 6;
  int lane = threadIdx.x & 63;
  int s = src[wid], d = dst[wid];
  const float* mr = m + (size_t)s*128;
  float* ar = a + (size_t)d*128;
  atomicAdd(ar + lane, mr[lane]);
  atomicAdd(ar + 64 + lane, mr[64 + lane]);
}

// ---------------- LayerNorm + leaky relu (single; used for GGC epilogue) ----------------
__global__ void ln_lrelu_kernel(float* __restrict__ out, const float* __restrict__ x,
                                const float* __restrict__ add,
                                const float* __restrict__ g, const float* __restrict__ b) {
  int n = blockIdx.x, j = threadIdx.x;
  size_t base = (size_t)n*128;
  float v = x[base+j];
  if (add) v += add[base+j];
  __shared__ float sh[4];
  float s = v;
#pragma unroll
  for (int m=32; m>=1; m>>=1) s += __shfl_xor(s, m, 64);
  if ((j&63)==0) sh[j>>6] = s;
  __syncthreads();
  float mean = (sh[0]+sh[1]) * 0.0078125f;
  float d = v - mean;
  float q = d*d;
#pragma unroll
  for (int m=32; m>=1; m>>=1) q += __shfl_xor(q, m, 64);
  if ((j&63)==0) sh[2+(j>>6)] = q;
  __syncthreads();
  float var = (sh[2]+sh[3]) * 0.0078125f;
  float y = d * rsqrtf(var + 1e-5f) * g[j] + b[j];
  out[base+j] = (y >= 0.0f) ? y : 0.01f*y;
}

// ---------------- fused LN1 -> residual LN3 ----------------
// y1 = lrelu(ln(nsrc; g1,b1)); h = lrelu(ln(h + y1; g3,b3)); optional fp16 shadow.
__global__ void ln13_kernel(float* __restrict__ h, const float* __restrict__ nsrc,
                            const float* __restrict__ g1, const float* __restrict__ b1,
                            const float* __restrict__ g3, const float* __restrict__ b3,
                            unsigned short* __restrict__ out16) {
  int n = blockIdx.x, j = threadIdx.x;
  size_t base = (size_t)n*128;
  __shared__ float sh[4];
  // LN1
  float v = nsrc[base+j];
  float s = v;
#pragma unroll
  for (int m=32; m>=1; m>>=1) s += __shfl_xor(s, m, 64);
  if ((j&63)==0) sh[j>>6] = s;
  __syncthreads();
  float mean = (sh[0]+sh[1]) * 0.0078125f;
  float d = v - mean;
  float q = d*d;
#pragma unroll
  for (int m=32; m>=1; m>>=1) q += __shfl_xor(q, m, 64);
  if ((j&63)==0) sh[2+(j>>6)] = q;
  __syncthreads();
  float var = (sh[2]+sh[3]) * 0.0078125f;
  float y1 = d * rsqrtf(var + 1e-5f) * g1[j] + b1[j];
  y1 = (y1 >= 0.0f) ? y1 : 0.01f*y1;
  __syncthreads();   // sh reads done before reuse
  // LN3 on h + y1
  float u = h[base+j] + y1;
  s = u;
#pragma unroll
  for (int m=32; m>=1; m>>=1) s += __shfl_xor(s, m, 64);
  if ((j&63)==0) sh[j>>6] = s;
  __syncthreads();
  mean = (sh[0]+sh[1]) * 0.0078125f;
  d = u - mean;
  q = d*d;
#pragma unroll
  for (int m=32; m>=1; m>>=1) q += __shfl_xor(q, m, 64);
  if ((j&63)==0) sh[2+(j>>6)] = q;
  __syncthreads();
  var = (sh[2]+sh[3]) * 0.0078125f;
  float y3 = d * rsqrtf(var + 1e-5f) * g3[j] + b3[j];
  float o = (y3 >= 0.0f) ? y3 : 0.01f*y3;
  h[base+j] = o;
  if (out16) out16[base+j] = __half_as_ushort(__float2half_rn(o));
}

// ---------------- segment mean ----------------
__global__ void segmean_kernel(float* __restrict__ out, const float* __restrict__ x,
                               const float* __restrict__ y) {
  int b = blockIdx.x, j = threadIdx.x;
  float s = 0.0f;
  for (int r=0; r<128; ++r) {
    size_t n = (size_t)(b*128 + r)*128 + j;
    s += x[n];
    if (y) s += y[n];
  }
  out[(size_t)b*128 + j] = s * 0.0078125f;
}

// ---------------- classifier head ----------------
__global__ void cls_kernel(float* __restrict__ out, const float* __restrict__ h2,
                           const float* __restrict__ Wc, const float* __restrict__ bc) {
  int gid = blockIdx.x*256 + threadIdx.x;
  if (gid >= BB*10) return;
  int mrow = gid/10, c = gid - mrow*10;
  const float* arow = h2 + (size_t)mrow*128;
  const float* wrow = Wc + (size_t)c*128;
  float s = bc[c];
  for (int k=0;k<128;++k) s += arow[k]*wrow[k];
  out[gid] = s;
}

__global__ void bail_kernel(float* out, float v) {
  if (threadIdx.x==0 && blockIdx.x==0) out[0] = v;
}

// ---------------- host orchestration ----------------
extern "C" void kernel_launch(void* const* d_in, const int* in_sizes, int n_in,
                              void* d_out, int out_size, void* d_ws, size_t ws_size,
                              hipStream_t stream)
{
  const int* act_ids  = (const int*)d_in[0];
  const int* dur_ids  = (const int*)d_in[1];
  const int* act2_ids = (const int*)d_in[2];
  const int* nbr_a2d  = (const int*)d_in[3];
  const int* nbr_d2a  = (const int*)d_in[4];
  const int* src2     = (const int*)d_in[5];
  const int* dst2     = (const int*)d_in[6];
  const float* emb_act     = (const float*)d_in[8];
  const float* emb_dur     = (const float*)d_in[9];
  const float* emb_act2    = (const float*)d_in[10];
  const float* transform_W = (const float*)d_in[11];
  const float* transform_b = (const float*)d_in[12];
  const float* ggc_W   = (const float*)d_in[13];
  const float* ggc_b   = (const float*)d_in[14];
  const float* gru_Wih = (const float*)d_in[15];
  const float* gru_Whh = (const float*)d_in[16];
  const float* gru_bih = (const float*)d_in[17];
  const float* gru_bhh = (const float*)d_in[18];
  const float* hn_g    = (const float*)d_in[19];
  const float* hn_b    = (const float*)d_in[20];
  const float* lstm_Wih = (const float*)d_in[21];
  const float* lstm_Whh = (const float*)d_in[22];
  const float* lstm_bih = (const float*)d_in[23];
  const float* lstm_bhh = (const float*)d_in[24];
  const float* fcs_W = (const float*)d_in[25];
  const float* fcs_b = (const float*)d_in[26];
  const float* fcn_W = (const float*)d_in[27];
  const float* fcn_b = (const float*)d_in[28];
  const float* n1_g = (const float*)d_in[29];
  const float* n1_b = (const float*)d_in[30];
  const float* n3_g = (const float*)d_in[31];
  const float* n3_b = (const float*)d_in[32];
  const float* mh_W1 = (const float*)d_in[33];
  const float* mh_b1 = (const float*)d_in[34];
  const float* mh_W2 = (const float*)d_in[35];
  const float* mh_b2 = (const float*)d_in[36];
  const float* mo_W1 = (const float*)d_in[37];
  const float* mo_b1 = (const float*)d_in[38];
  const float* mo_W2 = (const float*)d_in[39];
  const float* mo_b2 = (const float*)d_in[40];
  const float* mlp_W1 = (const float*)d_in[41];
  const float* mlp_b1 = (const float*)d_in[42];
  const float* mlp_W2 = (const float*)d_in[43];
  const float* mlp_b2 = (const float*)d_in[44];
  const float* cls_W = (const float*)d_in[45];
  const float* cls_b = (const float*)d_in[46];

  float* ws = (float*)d_ws;
  float* ha   = ws;
  float* hd   = ws + (size_t)NF;
  float* hg2  = ws + 2*(size_t)NF;
  float* res  = ws + 3*(size_t)NF;
  float* hh   = ws + 4*(size_t)NF;
  float* SCR  = ws + 5*(size_t)NF;
  float* mb   = SCR;
  float* abuf = SCR + (size_t)NF;
  float* hnf  = mb;
  float* hLb  = SCR + 8*(size_t)NF;
  float* SMALL = ws + 15*(size_t)NF;
  float* hg2m = SMALL;
  float* hgm  = SMALL + 32768;
  float* o1b  = SMALL + 65536;
  float* o2b  = SMALL + 98304;
  float* t1b  = SMALL + 131072;
  float* t2b  = SMALL + 163840;
  float* h1b  = SMALL + 196608;
  float* h2b  = SMALL + 262144;
  float* bsum = SMALL + 294912;
  float* WTb  = SMALL + 296960;
  const size_t NEED_BYTES = (size_t)(15*(size_t)NF + 296960 + 1032192) * 4;
  if (ws_size < NEED_BYTES) {
    hipMemsetAsync(d_out, 0, (size_t)out_size*sizeof(float), stream);
    bail_kernel<<<1,64,0,stream>>>((float*)d_out, (float)ws_size);
    return;
  }
  float* na = hg2;
  float* nd = res;
  unsigned short* fs16a = (unsigned short*)(SCR + 2*(size_t)NF);
  unsigned short* fs16d = fs16a + (size_t)NF;

  const int O_TRANSFORM = 0;       // THi/TLo (65536 halfs = 32768 floats)
  const int O_SPLIT    = 147456;
  const int O_SPLIT2   = 409600;
  const int O_MH1      = 802816;
  const int O_MH2      = 819200;
  const int O_MO1      = 835584;
  const int O_MO2      = 851968;
  const int O_MLP1     = 868352;
  const int O_MLP2     = 999424;

  unsigned short* THi = (unsigned short*)(WTb + O_TRANSFORM);
  unsigned short* TLo = THi + 32768;
  unsigned short* WI16 = (unsigned short*)(WTb + O_SPLIT);
  unsigned short* WH16 = WI16 + 4*65536;

  unsigned short* SP2 = (unsigned short*)(WTb + O_SPLIT2);
  unsigned short* GGChi = SP2;                 unsigned short* GGClo = GGChi + 16384;
  unsigned short* GIHhi = GGClo + 16384;       unsigned short* GIHlo = GIHhi + 49152;
  unsigned short* GHHhi = GIHlo + 49152;       unsigned short* GHHlo = GHHhi + 49152;
  unsigned short* FCShi = GHHlo + 49152;       unsigned short* FCSlo = FCShi + 65536;
  unsigned short* FCNhi = FCSlo + 65536;       unsigned short* FCNlo = FCNhi + 65536;

  TDescArr da;
  int di = 0;
  auto addT = [&](const float* s, float* d, int R, int C){ da.d[di].src=s; da.d[di].dst=d; da.d[di].R=R; da.d[di].C=C; ++di; };
  addT(mh_W1, WTb + O_MH1, 128, 128);
  addT(mh_W2, WTb + O_MH2, 128, 128);
  addT(mo_W1, WTb + O_MO1, 128, 128);
  addT(mo_W2, WTb + O_MO2, 128, 128);
  addT(mlp_W1, WTb + O_MLP1, 256, 512);
  addT(mlp_W2, WTb + O_MLP2, 128, 256);
  transpose_many<<<dim3(512, di), 256, 0, stream>>>(da);
  bias_sum_kernel<<<8, 256, 0, stream>>>(lstm_bih, lstm_bhh, bsum);
  f32to16_kernel<<<(4*512*128)/1024, 256, 0, stream>>>(lstm_Wih, WI16);
  f32to16_kernel<<<(4*512*128)/1024, 256, 0, stream>>>(lstm_Whh, WH16);
  wsplit16_kernel<<<32768/256, 256, 0, stream>>>(transform_W, THi, TLo);
  wsplit16_kernel<<<16384/256, 256, 0, stream>>>(ggc_W, GGChi, GGClo);
  wsplit16_kernel<<<49152/256, 256, 0, stream>>>(gru_Wih, GIHhi, GIHlo);
  wsplit16_kernel<<<49152/256, 256, 0, stream>>>(gru_Whh, GHHhi, GHHlo);
  wsplit16_kernel<<<65536/256, 256, 0, stream>>>(fcs_W, FCShi, FCSlo);
  wsplit16_kernel<<<65536/256, 256, 0, stream>>>(fcn_W, FCNhi, FCNlo);

  auto smemK = [](int K, int BN){ return (size_t)(32*(K+4) + 16*BN)*4; };
  const int gB = BB/32;
  const int gM = NN/64;
  const size_t LDS2 = 69632;

  embed3_kernel<<<dim3(NF/256, 3), 256, 0, stream>>>(act_ids, dur_ids, act2_ids,
      emb_act, emb_dur, emb_act2, ha, hd, hg2);
  // transform: res = hg2 @ Wt[:, :128]^T + hd @ Wt[:, 128:]^T + b
  mgemm2<<<gM, 512, LDS2, stream>>>(hg2, THi, TLo, hd, THi + 128, TLo + 128,
      transform_b, nullptr, res, 256);
  hipMemcpyAsync(hh, res, (size_t)NF*4, hipMemcpyDeviceToDevice, stream);

  for (int it=0; it<2; ++it) {
    mgemm<<<gM, 512, 0, stream>>>(hh, GGChi, GGClo, ggc_b, mb, 128, 1);
    hipMemsetAsync(abuf, 0, (size_t)NF*4, stream);
    scatter_add_kernel<<<E2N/4, 256, 0, stream>>>(abuf, mb, src2, dst2);
    gru_fused<<<gM, 512, LDS2, stream>>>(abuf, hh, GIHhi, GIHlo, GHHhi, GHHlo,
        gru_bih, gru_bhh);
  }
  ln_lrelu_kernel<<<NN, 128, 0, stream>>>(hnf, hh, res, hn_g, hn_b);
  segmean_kernel<<<BB, 128, 0, stream>>>(hg2m, hnf, nullptr);

  f32to16_kernel<<<NF/1024, 256, 0, stream>>>(ha, fs16a);
  f32to16_kernel<<<NF/1024, 256, 0, stream>>>(hd, fs16d);

  for (int l=0; l<2; ++l) {
    const int i0 = l*2 + 0, i1 = l*2 + 1;
    lstm_fused6<<<1024, 512, 0, stream>>>(hLb, fs16a, fs16d, nbr_a2d, nbr_d2a,
        WI16 + i0*65536, WH16 + i0*65536,
        WI16 + i1*65536, WH16 + i1*65536,
        bsum + i0*512, bsum + i1*512);

    // nd = hd@fcs0^T + hL_a2d@fcn0^T + fcs_b0 + fcn_b0 ; na symmetric with i1
    mgemm2<<<gM, 512, LDS2, stream>>>(hd, FCShi + i0*16384, FCSlo + i0*16384,
        hLb, FCNhi + i0*16384, FCNlo + i0*16384,
        fcs_b + i0*128, fcn_b + i0*128, nd, 128);
    mgemm2<<<gM, 512, LDS2, stream>>>(ha, FCShi + i1*16384, FCSlo + i1*16384,
        hLb + (size_t)NN*128, FCNhi + i1*16384, FCNlo + i1*16384,
        fcs_b + i1*128, fcn_b + i1*128, na, 128);
    ln13_kernel<<<NN, 128, 0, stream>>>(ha, na, n1_g + i0*128, n1_b + i0*128,
        n3_g + i0*128, n3_b + i0*128, (l==0) ? fs16a : nullptr);
    ln13_kernel<<<NN, 128, 0, stream>>>(hd, nd, n1_g + i1*128, n1_b + i1*128,
        n3_g + i1*128, n3_b + i1*128, (l==0) ? fs16d : nullptr);
  }
  segmean_kernel<<<BB, 128, 0, stream>>>(hgm, ha, hd);

  gemm_nt<128,1><<<gB, 256, smemK(128,128), stream>>>(hg2m, nullptr, nullptr, nullptr, 128,
      WTb + O_MO1, mo_b1, t1b, 128, 0);
  gemm_nt<128,1><<<gB, 256, smemK(128,128), stream>>>(t1b, nullptr, nullptr, nullptr, 128,
      WTb + O_MO2, mo_b2, o1b, 128, 0);
  gemm_nt<128,1><<<gB, 256, smemK(128,128), stream>>>(hgm, nullptr, nullptr, nullptr, 128,
      WTb + O_MH1, mh_b1, t2b, 128, 0);
  gemm_nt<128,1><<<gB, 256, smemK(128,128), stream>>>(t2b, nullptr, nullptr, nullptr, 128,
      WTb + O_MH2, mh_b2, o2b, 128, 0);
  gemm_nt<256,0><<<gB, 256, smemK(256,256), stream>>>(o1b, hg2m, nullptr, nullptr, 128,
      WTb + O_MLP1, nullptr, h1b, 256, 0);
  gemm_nt<256,1><<<gB, 256, smemK(256,256), stream>>>(o2b, hgm, nullptr, nullptr, 128,
      WTb + O_MLP1 + 256*256, mlp_b1, h1b, 256, 1);
  gemm_nt<128,1><<<gB, 256, smemK(256,128), stream>>>(h1b, h1b + 128, nullptr, nullptr, 256,
      WTb + O_MLP2, mlp_b2, h2b, 256, 0);
  cls_kernel<<<10, 256, 0, stream>>>((float*)d_out, h2b, cls_W, cls_b);
}

// Round 17
// 1624.953 us; speedup vs baseline: 3.2870x; 1.1840x over previous
//
#include <hip/hip_runtime.h>
#include <hip/hip_fp16.h>
#include <math.h>

#define NN 32768
#define HH 128
#define DD 16
#define BB 256
#define E2N (NN*DD)
#define NF (NN*HH)

typedef __attribute__((ext_vector_type(4))) float f32x4;
typedef __attribute__((ext_vector_type(4))) unsigned short u16x4;
typedef __attribute__((ext_vector_type(8))) unsigned short u16x8;
typedef _Float16 f16x8 __attribute__((ext_vector_type(8)));

__device__ __forceinline__ float fsig(float x) {
  return __builtin_amdgcn_rcpf(1.0f + __builtin_amdgcn_exp2f(-1.442695041f*x));
}
__device__ __forceinline__ float ftanh(float x) {
  return 1.0f - 2.0f*__builtin_amdgcn_rcpf(1.0f + __builtin_amdgcn_exp2f(2.885390082f*x));
}
__device__ __forceinline__ void hsplit(float x, unsigned short& h, unsigned short& l) {
  __half hh_ = __float2half_rn(x);
  h = __half_as_ushort(hh_);
  l = __half_as_ushort(__float2half_rn(x - __half2float(hh_)));
}

// ---------------- transpose prep (head weights -> [K][Nout]) ----------------
struct TDesc { const float* src; float* dst; int R; int C; };
struct TDescArr { TDesc d[8]; };

__global__ void transpose_many(TDescArr da) {
  TDesc t = da.d[blockIdx.y];
  int idx = blockIdx.x*256 + threadIdx.x;
  if (idx < t.R*t.C) {
    int r = idx / t.C, c = idx - r*t.C;
    t.dst[(size_t)c*t.R + r] = t.src[idx];
  }
}

__global__ void bias_sum_kernel(const float* __restrict__ bih, const float* __restrict__ bhh,
                                float* __restrict__ bsum) {
  int i = blockIdx.x*256 + threadIdx.x;
  if (i < 2048) bsum[i] = bih[i] + bhh[i];
}

__global__ void f32to16_kernel(const float* __restrict__ in, unsigned short* __restrict__ out) {
  int base = (blockIdx.x*256 + threadIdx.x) * 4;
  float4 v = *(const float4*)(in + base);
  u16x4 p;
  p[0] = __half_as_ushort(__float2half_rn(v.x));
  p[1] = __half_as_ushort(__float2half_rn(v.y));
  p[2] = __half_as_ushort(__float2half_rn(v.z));
  p[3] = __half_as_ushort(__float2half_rn(v.w));
  *(u16x4*)(out + base) = p;
}

__global__ void wsplit16_kernel(const float* __restrict__ W,
                                unsigned short* __restrict__ hi,
                                unsigned short* __restrict__ lo) {
  int i = blockIdx.x*256 + threadIdx.x;
  unsigned short h, l;
  hsplit(W[i], h, l);
  hi[i] = h; lo[i] = l;
}

// ---------------- CSR build (once; graph shared by both GGC iterations) ----------------
__global__ void hist_kernel(const int* __restrict__ dst, int* __restrict__ cnt) {
  int e = blockIdx.x*256 + threadIdx.x;
  atomicAdd(&cnt[dst[e]], 1);
}

__global__ __launch_bounds__(1024) void scan_kernel(const int* __restrict__ cnt,
                                                    int* __restrict__ rowptr,
                                                    int* __restrict__ cursor) {
  __shared__ int part[1024];
  const int t = threadIdx.x;
  const int base = t*32;
  int loc[32];
  int s = 0;
#pragma unroll
  for (int k=0;k<32;++k){ loc[k]=s; s += cnt[base+k]; }
  part[t] = s;
  __syncthreads();
  for (int off=1; off<1024; off<<=1) {
    int v = (t>=off) ? part[t-off] : 0;
    __syncthreads();
    part[t] += v;
    __syncthreads();
  }
  int pbase = part[t] - s;   // exclusive prefix
#pragma unroll
  for (int k=0;k<32;++k){ int v = pbase + loc[k]; rowptr[base+k]=v; cursor[base+k]=v; }
  if (t == 1023) rowptr[NN] = part[1023];
}

__global__ void fill_kernel(const int* __restrict__ src, const int* __restrict__ dst,
                            int* __restrict__ cursor, int* __restrict__ elist) {
  int e = blockIdx.x*256 + threadIdx.x;
  int p = atomicAdd(&cursor[dst[e]], 1);
  elist[p] = src[e];
}

// gather-reduce: a[node] = sum over in-edges of m[src]; 1 wave/node, no atomics.
__global__ __launch_bounds__(256) void gather_ggc(const float* __restrict__ m,
    const int* __restrict__ rowptr, const int* __restrict__ elist,
    float* __restrict__ a) {
  const int node = blockIdx.x*4 + (threadIdx.x>>6);
  const int lane = threadIdx.x & 63;
  const int s0 = rowptr[node], s1 = rowptr[node+1];
  float a0 = 0.0f, a1 = 0.0f;
  for (int e=s0; e<s1; ++e) {
    const float* mr = m + (size_t)elist[e]*128;
    a0 += mr[lane];
    a1 += mr[64+lane];
  }
  float* ar = a + (size_t)node*128;
  ar[lane] = a0;
  ar[64+lane] = a1;
}

// ---------------- embeddings (+fp16 shadows for lstm features) ----------------
__global__ void embed3_kernel(const int* __restrict__ a_ids, const int* __restrict__ d_ids,
                              const int* __restrict__ a2_ids,
                              const float* __restrict__ ea, const float* __restrict__ ed,
                              const float* __restrict__ ea2,
                              float* __restrict__ ha, float* __restrict__ hd,
                              float* __restrict__ hg2,
                              unsigned short* __restrict__ fs16a,
                              unsigned short* __restrict__ fs16d) {
  int idx = blockIdx.x*256 + threadIdx.x;
  int n = idx >> 7, j = idx & 127;
  int w = blockIdx.y;
  if (w == 0) {
    float v = ea[(size_t)a_ids[n]*128 + j];
    ha[idx] = v;
    fs16a[idx] = __half_as_ushort(__float2half_rn(v));
  } else if (w == 1) {
    float v = ed[(size_t)d_ids[n]*128 + j];
    hd[idx] = v;
    fs16d[idx] = __half_as_ushort(__float2half_rn(v));
  } else {
    hg2[idx] = ea2[(size_t)a2_ids[n]*128 + j];
  }
}

// ---------------- generic fp32 GEMM (heads only) ----------------
template<int BN, int ACT>
__global__ __launch_bounds__(256) void gemm_nt(
    const float* __restrict__ A0, const float* __restrict__ A1,
    const float* __restrict__ A2, const float* __restrict__ A3,
    int lda, const float* __restrict__ WT, const float* __restrict__ bias,
    float* __restrict__ C, int K, int beta)
{
  extern __shared__ float sm[];
  const int KP = K + 4;
  float* At = sm;
  float* Bc = sm + 32*KP;
  const int tid = threadIdx.x;
  const int m0 = blockIdx.x*32;
  const int ng = tid >> 5, cg = tid & 31;
  const int n0 = ng*4, c4 = cg*4;
  constexpr int G = BN/128;
  float acc[G][4][4];
#pragma unroll
  for (int g=0; g<G; ++g)
#pragma unroll
    for (int i=0;i<4;++i)
#pragma unroll
      for (int e=0;e<4;++e) acc[g][i][e] = 0.0f;

  const int nf4 = K >> 2;
  for (int idx = tid; idx < 32*nf4; idx += 256) {
    int row = idx / nf4;
    int kk = (idx - row*nf4) << 2;
    const float* Ap = (kk < 128) ? A0 : (kk < 256) ? A1 : (kk < 384) ? A2 : A3;
    float4 v = *(const float4*)(Ap + (size_t)(m0+row)*lda + (kk & 127));
    *(float4*)(At + row*KP + kk) = v;
  }
  const int nchunk = K >> 4;
  for (int kc = 0; kc < nchunk; ++kc) {
    __syncthreads();
    for (int idx = tid; idx < 16*(BN/4); idx += 256) {
      int kk = idx / (BN/4);
      int jq = idx - kk*(BN/4);
      *(float4*)(Bc + kk*BN + jq*4) = *(const float4*)(WT + (size_t)(kc*16+kk)*BN + jq*4);
    }
    __syncthreads();
    for (int k=0;k<16;++k) {
      const int kk = kc*16 + k;
      float av[4];
#pragma unroll
      for (int i=0;i<4;++i) av[i] = At[(n0+i)*KP + kk];
#pragma unroll
      for (int g=0; g<G; ++g) {
        float4 bv = *(const float4*)(Bc + k*BN + g*128 + c4);
        float bb[4] = {bv.x, bv.y, bv.z, bv.w};
#pragma unroll
        for (int i=0;i<4;++i)
#pragma unroll
          for (int e=0;e<4;++e)
            acc[g][i][e] += av[i]*bb[e];
      }
    }
  }
#pragma unroll
  for (int g=0; g<G; ++g) {
#pragma unroll
    for (int i=0;i<4;++i) {
      float* dst = C + (size_t)(m0+n0+i)*BN + g*128 + c4;
      float o[4];
#pragma unroll
      for (int e=0;e<4;++e) o[e] = acc[g][i][e];
      if (bias) {
#pragma unroll
        for (int e=0;e<4;++e) o[e] += bias[g*128 + c4 + e];
      }
      if (beta) {
        float4 p = *(const float4*)dst;
        o[0]+=p.x; o[1]+=p.y; o[2]+=p.z; o[3]+=p.w;
      }
      if (ACT==1) {
#pragma unroll
        for (int e=0;e<4;++e) o[e] = fmaxf(o[e], 0.0f);
      }
      *(float4*)dst = make_float4(o[0],o[1],o[2],o[3]);
    }
  }
}

// ---------------- LDS staging helper ----------------
__device__ __forceinline__ void stage_hi_lo(const float* __restrict__ A, int rb, int tid,
                                            unsigned short* xhi, unsigned short* xlo) {
  const int r = tid >> 3;
  const int cf = (tid & 7) * 16;
  const float* src = A + (size_t)(rb + r)*128 + cf;
  unsigned short* dh = xhi + r*136 + cf;
  unsigned short* dl = xlo + r*136 + cf;
#pragma unroll
  for (int q=0; q<4; ++q) {
    float4 v = *(const float4*)(src + q*4);
    float vs[4] = {v.x, v.y, v.z, v.w};
    u16x4 ph, pl;
#pragma unroll
    for (int e=0;e<4;++e){ unsigned short h_,l_; hsplit(vs[e],h_,l_); ph[e]=h_; pl[e]=l_; }
    *(u16x4*)(dh + q*4) = ph;
    *(u16x4*)(dl + q*4) = pl;
  }
}

// ---------------- MFMA GEMM single-input ----------------
__global__ __launch_bounds__(512) void mgemm(
    const float* __restrict__ A,
    const unsigned short* __restrict__ Whi, const unsigned short* __restrict__ Wlo,
    const float* __restrict__ bias, float* __restrict__ C, int BN, int ntpw)
{
  __shared__ unsigned short xhi[64*136];
  __shared__ unsigned short xlo[64*136];
  const int tid = threadIdx.x;
  const int w = tid >> 6;
  const int lane = tid & 63;
  const int ln16 = lane & 15;
  const int lq = lane >> 4;
  const int rb = blockIdx.x * 64;
  stage_hi_lo(A, rb, tid, xhi, xlo);
  __syncthreads();

  for (int j=0; j<ntpw; ++j) {
    const int tile = w + j*8;
    f32x4 acc[4];
    f32x4 bv = *(const f32x4*)(bias + tile*16 + lq*4);
#pragma unroll
    for (int nt=0; nt<4; ++nt) acc[nt] = bv;
#pragma unroll
    for (int kt=0; kt<4; ++kt) {
      const int bo = kt*32 + lq*8;
      f16x8 bxh[4], bxl[4];
#pragma unroll
      for (int nt=0; nt<4; ++nt) {
        bxh[nt] = *(const f16x8*)(xhi + (nt*16+ln16)*136 + bo);
        bxl[nt] = *(const f16x8*)(xlo + (nt*16+ln16)*136 + bo);
      }
      const size_t co = (size_t)(tile*16 + ln16)*128 + kt*32 + lq*8;
      f16x8 ah = *(const f16x8*)(Whi + co);
      f16x8 al = *(const f16x8*)(Wlo + co);
#pragma unroll
      for (int nt=0; nt<4; ++nt) {
        acc[nt] = __builtin_amdgcn_mfma_f32_16x16x32_f16(ah, bxh[nt], acc[nt], 0,0,0);
        acc[nt] = __builtin_amdgcn_mfma_f32_16x16x32_f16(ah, bxl[nt], acc[nt], 0,0,0);
        acc[nt] = __builtin_amdgcn_mfma_f32_16x16x32_f16(al, bxh[nt], acc[nt], 0,0,0);
      }
    }
#pragma unroll
    for (int nt=0; nt<4; ++nt) {
      f32x4 o = acc[nt];
      *(float4*)(C + (size_t)(rb + nt*16 + ln16)*BN + tile*16 + lq*4) =
          make_float4(o[0],o[1],o[2],o[3]);
    }
  }
}

// ---------------- MFMA GEMM dual-input (+ optional dual output) ----------------
__global__ __launch_bounds__(512) void mgemm2(
    const float* __restrict__ A1,
    const unsigned short* __restrict__ W1hi, const unsigned short* __restrict__ W1lo,
    const float* __restrict__ A2,
    const unsigned short* __restrict__ W2hi, const unsigned short* __restrict__ W2lo,
    const float* __restrict__ bias1, const float* __restrict__ bias2,
    float* __restrict__ C, float* __restrict__ C2, int wstride)
{
  extern __shared__ unsigned short sm16[];
  unsigned short* x1hi = sm16;
  unsigned short* x1lo = sm16 + 8704;
  unsigned short* x2hi = sm16 + 17408;
  unsigned short* x2lo = sm16 + 26112;
  const int tid = threadIdx.x;
  const int w = tid >> 6;
  const int lane = tid & 63;
  const int ln16 = lane & 15;
  const int lq = lane >> 4;
  const int rb = blockIdx.x * 64;
  stage_hi_lo(A1, rb, tid, x1hi, x1lo);
  stage_hi_lo(A2, rb, tid, x2hi, x2lo);
  __syncthreads();

  f32x4 acc[4];
  {
    f32x4 bv = *(const f32x4*)(bias1 + w*16 + lq*4);
    if (bias2) {
      f32x4 b2 = *(const f32x4*)(bias2 + w*16 + lq*4);
#pragma unroll
      for (int e=0;e<4;++e) bv[e] += b2[e];
    }
#pragma unroll
    for (int nt=0; nt<4; ++nt) acc[nt] = bv;
  }
#pragma unroll
  for (int p=0; p<2; ++p) {
    const unsigned short* xh = p ? x2hi : x1hi;
    const unsigned short* xl = p ? x2lo : x1lo;
    const unsigned short* Wh = p ? W2hi : W1hi;
    const unsigned short* Wl = p ? W2lo : W1lo;
#pragma unroll
    for (int kt=0; kt<4; ++kt) {
      const int bo = kt*32 + lq*8;
      f16x8 bxh[4], bxl[4];
#pragma unroll
      for (int nt=0; nt<4; ++nt) {
        bxh[nt] = *(const f16x8*)(xh + (nt*16+ln16)*136 + bo);
        bxl[nt] = *(const f16x8*)(xl + (nt*16+ln16)*136 + bo);
      }
      const size_t co = (size_t)(w*16 + ln16)*wstride + kt*32 + lq*8;
      f16x8 ah = *(const f16x8*)(Wh + co);
      f16x8 al = *(const f16x8*)(Wl + co);
#pragma unroll
      for (int nt=0; nt<4; ++nt) {
        acc[nt] = __builtin_amdgcn_mfma_f32_16x16x32_f16(ah, bxh[nt], acc[nt], 0,0,0);
        acc[nt] = __builtin_amdgcn_mfma_f32_16x16x32_f16(ah, bxl[nt], acc[nt], 0,0,0);
        acc[nt] = __builtin_amdgcn_mfma_f32_16x16x32_f16(al, bxh[nt], acc[nt], 0,0,0);
      }
    }
  }
#pragma unroll
  for (int nt=0; nt<4; ++nt) {
    f32x4 o = acc[nt];
    const size_t off = (size_t)(rb + nt*16 + ln16)*128 + w*16 + lq*4;
    *(float4*)(C + off) = make_float4(o[0],o[1],o[2],o[3]);
    if (C2) *(float4*)(C2 + off) = make_float4(o[0],o[1],o[2],o[3]);
  }
}

// ---------------- fused GRU ----------------
__global__ __launch_bounds__(512) void gru_fused(
    const float* __restrict__ abuf, float* __restrict__ hh,
    const unsigned short* __restrict__ GIhi, const unsigned short* __restrict__ GIlo,
    const unsigned short* __restrict__ GHhi, const unsigned short* __restrict__ GHlo,
    const float* __restrict__ bih, const float* __restrict__ bhh)
{
  extern __shared__ unsigned short sm16[];
  unsigned short* xhi = sm16;
  unsigned short* xlo = sm16 + 8704;
  unsigned short* hhi = sm16 + 17408;
  unsigned short* hlo = sm16 + 26112;
  const int tid = threadIdx.x;
  const int w = tid >> 6;
  const int lane = tid & 63;
  const int ln16 = lane & 15;
  const int lq = lane >> 4;
  const int rb = blockIdx.x * 64;
  stage_hi_lo(abuf, rb, tid, xhi, xlo);
  stage_hi_lo(hh, rb, tid, hhi, hlo);
  __syncthreads();

  f32x4 rr[4], zz[4], nn_[4];
#pragma unroll
  for (int j=0; j<3; ++j) {
    const int tile = w + j*8;
    f32x4 ai[4], ag[4];
    f32x4 bi = *(const f32x4*)(bih + tile*16 + lq*4);
    f32x4 bg = *(const f32x4*)(bhh + tile*16 + lq*4);
#pragma unroll
    for (int nt=0; nt<4; ++nt) { ai[nt] = bi; ag[nt] = bg; }
#pragma unroll
    for (int kt=0; kt<4; ++kt) {
      const int bo = kt*32 + lq*8;
      f16x8 bxh[4], bxl[4], bhh_[4], bhl_[4];
#pragma unroll
      for (int nt=0; nt<4; ++nt) {
        bxh[nt] = *(const f16x8*)(xhi + (nt*16+ln16)*136 + bo);
        bxl[nt] = *(const f16x8*)(xlo + (nt*16+ln16)*136 + bo);
        bhh_[nt] = *(const f16x8*)(hhi + (nt*16+ln16)*136 + bo);
        bhl_[nt] = *(const f16x8*)(hlo + (nt*16+ln16)*136 + bo);
      }
      const size_t co = (size_t)(tile*16 + ln16)*128 + kt*32 + lq*8;
      f16x8 ih = *(const f16x8*)(GIhi + co);
      f16x8 il = *(const f16x8*)(GIlo + co);
      f16x8 gh = *(const f16x8*)(GHhi + co);
      f16x8 gl = *(const f16x8*)(GHlo + co);
#pragma unroll
      for (int nt=0; nt<4; ++nt) {
        ai[nt] = __builtin_amdgcn_mfma_f32_16x16x32_f16(ih, bxh[nt], ai[nt], 0,0,0);
        ai[nt] = __builtin_amdgcn_mfma_f32_16x16x32_f16(ih, bxl[nt], ai[nt], 0,0,0);
        ai[nt] = __builtin_amdgcn_mfma_f32_16x16x32_f16(il, bxh[nt], ai[nt], 0,0,0);
        ag[nt] = __builtin_amdgcn_mfma_f32_16x16x32_f16(gh, bhh_[nt], ag[nt], 0,0,0);
        ag[nt] = __builtin_amdgcn_mfma_f32_16x16x32_f16(gh, bhl_[nt], ag[nt], 0,0,0);
        ag[nt] = __builtin_amdgcn_mfma_f32_16x16x32_f16(gl, bhh_[nt], ag[nt], 0,0,0);
      }
    }
#pragma unroll
    for (int nt=0; nt<4; ++nt) {
#pragma unroll
      for (int e=0; e<4; ++e) {
        if (j == 0)      rr[nt][e] = fsig(ai[nt][e] + ag[nt][e]);
        else if (j == 1) zz[nt][e] = fsig(ai[nt][e] + ag[nt][e]);
        else             nn_[nt][e] = ftanh(ai[nt][e] + rr[nt][e]*ag[nt][e]);
      }
    }
  }
#pragma unroll
  for (int nt=0; nt<4; ++nt) {
    float* hp = hh + (size_t)(rb + nt*16 + ln16)*128 + w*16 + lq*4;
    float4 ho = *(const float4*)hp;
    float hv[4] = {ho.x, ho.y, ho.z, ho.w};
    float o[4];
#pragma unroll
    for (int e=0; e<4; ++e)
      o[e] = (1.0f - zz[nt][e])*nn_[nt][e] + zz[nt][e]*hv[e];
    *(float4*)hp = make_float4(o[0],o[1],o[2],o[3]);
  }
}

// ---------------- fused LSTM v6 ----------------
__global__ __launch_bounds__(512) void lstm_fused6(
    float* __restrict__ hL,
    const unsigned short* __restrict__ fs16a, const unsigned short* __restrict__ fs16d,
    const int* __restrict__ nbrA, const int* __restrict__ nbrD,
    const unsigned short* __restrict__ WI0, const unsigned short* __restrict__ WH0,
    const unsigned short* __restrict__ WI1, const unsigned short* __restrict__ WH1,
    const float* __restrict__ bsum0, const float* __restrict__ bsum1)
{
  __shared__ unsigned short xb[64*132];
  __shared__ unsigned short hb[64*132];
  const int tid = threadIdx.x;
  const int w = tid >> 6;
  const int lane = tid & 63;
  const int ln16 = lane & 15;
  const int lq = lane >> 4;
  const int b = blockIdx.x;
  const bool dir = (b >= 512);
  const int nb = (dir ? (b - 512) : b) * 64;
  const unsigned short* fs16 = dir ? fs16d : fs16a;
  const int* nbr = dir ? nbrD : nbrA;
  const unsigned short* WI = dir ? WI1 : WI0;
  const unsigned short* WH = dir ? WH1 : WH0;
  const float* bsum = dir ? bsum1 : bsum0;

  const int gr = tid >> 3;
  const int gc = (tid & 7) * 16;
  const int* nrow = nbr + (size_t)(nb + gr)*DD;

  f32x4 bias[4];
#pragma unroll
  for (int g=0; g<4; ++g)
    bias[g] = *(const f32x4*)(bsum + g*128 + w*16 + lq*4);

  f32x4 cst[4];
#pragma unroll
  for (int nt=0; nt<4; ++nt)
#pragma unroll
    for (int e=0; e<4; ++e) cst[nt][e] = 0.0f;

  u16x8 xg0, xg1;
  {
    int gidx = nrow[0];
    const unsigned short* src = fs16 + (size_t)gidx*128 + gc;
    xg0 = *(const u16x8*)(src);
    xg1 = *(const u16x8*)(src + 8);
    unsigned short* d = xb + gr*132 + gc;
    *(u16x8*)d = xg0;
    *(u16x8*)(d+8) = xg1;
  }
  int gnext = nrow[1];

#pragma unroll 1
  for (int t=0; t<16; ++t) {
    __syncthreads();

    f32x4 racc[4][4];
#pragma unroll
    for (int g=0; g<4; ++g)
#pragma unroll
      for (int nt=0; nt<4; ++nt)
        racc[g][nt] = bias[g];

#pragma unroll
    for (int kt=0; kt<4; ++kt) {
      const int bo = kt*32 + lq*8;
      f16x8 bx[4];
#pragma unroll
      for (int nt=0; nt<4; ++nt)
        bx[nt] = *(const f16x8*)(xb + (nt*16+ln16)*132 + bo);
#pragma unroll
      for (int g=0; g<4; ++g) {
        f16x8 aI = *(const f16x8*)(WI + (size_t)(g*128 + w*16 + ln16)*128 + kt*32 + lq*8);
#pragma unroll
        for (int nt=0; nt<4; ++nt)
          racc[g][nt] = __builtin_amdgcn_mfma_f32_16x16x32_f16(aI, bx[nt], racc[g][nt], 0,0,0);
      }
    }
    if (t < 15) {
      const unsigned short* src = fs16 + (size_t)gnext*128 + gc;
      xg0 = *(const u16x8*)(src);
      xg1 = *(const u16x8*)(src + 8);
      if (t < 14) gnext = nrow[t+2];
    }
    if (t > 0) {
#pragma unroll
      for (int kt=0; kt<4; ++kt) {
        const int bo = kt*32 + lq*8;
        f16x8 bh[4];
#pragma unroll
        for (int nt=0; nt<4; ++nt)
          bh[nt] = *(const f16x8*)(hb + (nt*16+ln16)*132 + bo);
#pragma unroll
        for (int g=0; g<4; ++g) {
          f16x8 aH = *(const f16x8*)(WH + (size_t)(g*128 + w*16 + ln16)*128 + kt*32 + lq*8);
#pragma unroll
          for (int nt=0; nt<4; ++nt)
            racc[g][nt] = __builtin_amdgcn_mfma_f32_16x16x32_f16(aH, bh[nt], racc[g][nt], 0,0,0);
        }
      }
    }
    __syncthreads();

#pragma unroll
    for (int nt=0; nt<4; ++nt) {
      float hv[4];
#pragma unroll
      for (int e=0; e<4; ++e) {
        float ig = fsig(racc[0][nt][e]);
        float fg = fsig(racc[1][nt][e]);
        float gg = ftanh(racc[2][nt][e]);
        float og = fsig(racc[3][nt][e]);
        float cc = fg*cst[nt][e] + ig*gg;
        cst[nt][e] = cc;
        hv[e] = og*ftanh(cc);
      }
      const int node = nt*16 + ln16;
      const int col = w*16 + lq*4;
      if (t < 15) {
        u16x4 hw;
#pragma unroll
        for (int e=0; e<4; ++e) hw[e] = __half_as_ushort(__float2half_rn(hv[e]));
        *(u16x4*)(hb + node*132 + col) = hw;
      } else {
        *(float4*)(hL + (size_t)((dir?NN:0) + nb + node)*128 + col) =
            make_float4(hv[0], hv[1], hv[2], hv[3]);
      }
    }
    if (t < 15) {
      unsigned short* d = xb + gr*132 + gc;
      *(u16x8*)d = xg0;
      *(u16x8*)(d+8) = xg1;
    }
  }
}

// ---------------- LayerNorm + leaky relu ----------------
__global__ void ln_lrelu_kernel(float* __restrict__ out, const float* __restrict__ x,
                                const float* __restrict__ add,
                                const float* __restrict__ g, const float* __restrict__ b) {
  int n = blockIdx.x, j = threadIdx.x;
  size_t base = (size_t)n*128;
  float v = x[base+j];
  if (add) v += add[base+j];
  __shared__ float sh[4];
  float s = v;
#pragma unroll
  for (int m=32; m>=1; m>>=1) s += __shfl_xor(s, m, 64);
  if ((j&63)==0) sh[j>>6] = s;
  __syncthreads();
  float mean = (sh[0]+sh[1]) * 0.0078125f;
  float d = v - mean;
  float q = d*d;
#pragma unroll
  for (int m=32; m>=1; m>>=1) q += __shfl_xor(q, m, 64);
  if ((j&63)==0) sh[2+(j>>6)] = q;
  __syncthreads();
  float var = (sh[2]+sh[3]) * 0.0078125f;
  float y = d * rsqrtf(var + 1e-5f) * g[j] + b[j];
  out[base+j] = (y >= 0.0f) ? y : 0.01f*y;
}

// ---------------- fused LN1 -> residual LN3 ----------------
__global__ void ln13_kernel(float* __restrict__ h, const float* __restrict__ nsrc,
                            const float* __restrict__ g1, const float* __restrict__ b1,
                            const float* __restrict__ g3, const float* __restrict__ b3,
                            unsigned short* __restrict__ out16) {
  int n = blockIdx.x, j = threadIdx.x;
  size_t base = (size_t)n*128;
  __shared__ float sh[4];
  float v = nsrc[base+j];
  float s = v;
#pragma unroll
  for (int m=32; m>=1; m>>=1) s += __shfl_xor(s, m, 64);
  if ((j&63)==0) sh[j>>6] = s;
  __syncthreads();
  float mean = (sh[0]+sh[1]) * 0.0078125f;
  float d = v - mean;
  float q = d*d;
#pragma unroll
  for (int m=32; m>=1; m>>=1) q += __shfl_xor(q, m, 64);
  if ((j&63)==0) sh[2+(j>>6)] = q;
  __syncthreads();
  float var = (sh[2]+sh[3]) * 0.0078125f;
  float y1 = d * rsqrtf(var + 1e-5f) * g1[j] + b1[j];
  y1 = (y1 >= 0.0f) ? y1 : 0.01f*y1;
  __syncthreads();
  float u = h[base+j] + y1;
  s = u;
#pragma unroll
  for (int m=32; m>=1; m>>=1) s += __shfl_xor(s, m, 64);
  if ((j&63)==0) sh[j>>6] = s;
  __syncthreads();
  mean = (sh[0]+sh[1]) * 0.0078125f;
  d = u - mean;
  q = d*d;
#pragma unroll
  for (int m=32; m>=1; m>>=1) q += __shfl_xor(q, m, 64);
  if ((j&63)==0) sh[2+(j>>6)] = q;
  __syncthreads();
  var = (sh[2]+sh[3]) * 0.0078125f;
  float y3 = d * rsqrtf(var + 1e-5f) * g3[j] + b3[j];
  float o = (y3 >= 0.0f) ? y3 : 0.01f*y3;
  h[base+j] = o;
  if (out16) out16[base+j] = __half_as_ushort(__float2half_rn(o));
}

// ---------------- segment mean ----------------
__global__ void segmean_kernel(float* __restrict__ out, const float* __restrict__ x,
                               const float* __restrict__ y) {
  int b = blockIdx.x, j = threadIdx.x;
  float s = 0.0f;
  for (int r=0; r<128; ++r) {
    size_t n = (size_t)(b*128 + r)*128 + j;
    s += x[n];
    if (y) s += y[n];
  }
  out[(size_t)b*128 + j] = s * 0.0078125f;
}

// ---------------- classifier head ----------------
__global__ void cls_kernel(float* __restrict__ out, const float* __restrict__ h2,
                           const float* __restrict__ Wc, const float* __restrict__ bc) {
  int gid = blockIdx.x*256 + threadIdx.x;
  if (gid >= BB*10) return;
  int mrow = gid/10, c = gid - mrow*10;
  const float* arow = h2 + (size_t)mrow*128;
  const float* wrow = Wc + (size_t)c*128;
  float s = bc[c];
  for (int k=0;k<128;++k) s += arow[k]*wrow[k];
  out[gid] = s;
}

__global__ void bail_kernel(float* out, float v) {
  if (threadIdx.x==0 && blockIdx.x==0) out[0] = v;
}

// ---------------- host orchestration ----------------
extern "C" void kernel_launch(void* const* d_in, const int* in_sizes, int n_in,
                              void* d_out, int out_size, void* d_ws, size_t ws_size,
                              hipStream_t stream)
{
  const int* act_ids  = (const int*)d_in[0];
  const int* dur_ids  = (const int*)d_in[1];
  const int* act2_ids = (const int*)d_in[2];
  const int* nbr_a2d  = (const int*)d_in[3];
  const int* nbr_d2a  = (const int*)d_in[4];
  const int* src2     = (const int*)d_in[5];
  const int* dst2     = (const int*)d_in[6];
  const float* emb_act     = (const float*)d_in[8];
  const float* emb_dur     = (const float*)d_in[9];
  const float* emb_act2    = (const float*)d_in[10];
  const float* transform_W = (const float*)d_in[11];
  const float* transform_b = (const float*)d_in[12];
  const float* ggc_W   = (const float*)d_in[13];
  const float* ggc_b   = (const float*)d_in[14];
  const float* gru_Wih = (const float*)d_in[15];
  const float* gru_Whh = (const float*)d_in[16];
  const float* gru_bih = (const float*)d_in[17];
  const float* gru_bhh = (const float*)d_in[18];
  const float* hn_g    = (const float*)d_in[19];
  const float* hn_b    = (const float*)d_in[20];
  const float* lstm_Wih = (const float*)d_in[21];
  const float* lstm_Whh = (const float*)d_in[22];
  const float* lstm_bih = (const float*)d_in[23];
  const float* lstm_bhh = (const float*)d_in[24];
  const float* fcs_W = (const float*)d_in[25];
  const float* fcs_b = (const float*)d_in[26];
  const float* fcn_W = (const float*)d_in[27];
  const float* fcn_b = (const float*)d_in[28];
  const float* n1_g = (const float*)d_in[29];
  const float* n1_b = (const float*)d_in[30];
  const float* n3_g = (const float*)d_in[31];
  const float* n3_b = (const float*)d_in[32];
  const float* mh_W1 = (const float*)d_in[33];
  const float* mh_b1 = (const float*)d_in[34];
  const float* mh_W2 = (const float*)d_in[35];
  const float* mh_b2 = (const float*)d_in[36];
  const float* mo_W1 = (const float*)d_in[37];
  const float* mo_b1 = (const float*)d_in[38];
  const float* mo_W2 = (const float*)d_in[39];
  const float* mo_b2 = (const float*)d_in[40];
  const float* mlp_W1 = (const float*)d_in[41];
  const float* mlp_b1 = (const float*)d_in[42];
  const float* mlp_W2 = (const float*)d_in[43];
  const float* mlp_b2 = (const float*)d_in[44];
  const float* cls_W = (const float*)d_in[45];
  const float* cls_b = (const float*)d_in[46];

  float* ws = (float*)d_ws;
  float* ha   = ws;
  float* hd   = ws + (size_t)NF;
  float* hg2  = ws + 2*(size_t)NF;
  float* res  = ws + 3*(size_t)NF;
  float* hh   = ws + 4*(size_t)NF;
  float* SCR  = ws + 5*(size_t)NF;
  float* mb   = SCR;
  float* abuf = SCR + (size_t)NF;
  float* hnf  = mb;
  float* hLb  = SCR + 8*(size_t)NF;
  float* SMALL = ws + 15*(size_t)NF;
  float* hg2m = SMALL;
  float* hgm  = SMALL + 32768;
  float* o1b  = SMALL + 65536;
  float* o2b  = SMALL + 98304;
  float* t1b  = SMALL + 131072;
  float* t2b  = SMALL + 163840;
  float* h1b  = SMALL + 196608;
  float* h2b  = SMALL + 262144;
  float* bsum = SMALL + 294912;
  float* WTb  = SMALL + 296960;
  const size_t NEED_BYTES = (size_t)(15*(size_t)NF + 296960 + 1032192) * 4;
  if (ws_size < NEED_BYTES) {
    hipMemsetAsync(d_out, 0, (size_t)out_size*sizeof(float), stream);
    bail_kernel<<<1,64,0,stream>>>((float*)d_out, (float)ws_size);
    return;
  }
  float* na = hg2;
  float* nd = res;
  unsigned short* fs16a = (unsigned short*)(SCR + 2*(size_t)NF);
  unsigned short* fs16d = fs16a + (size_t)NF;
  // CSR int arena in free SCR[3NF..8NF) region
  int* csr_cnt    = (int*)(SCR + 3*(size_t)NF);
  int* csr_rowptr = csr_cnt + NN;        // NN+1
  int* csr_cursor = csr_rowptr + NN + 2;
  int* csr_elist  = csr_cursor + NN;     // E2N

  const int O_TRANSFORM = 0;
  const int O_SPLIT    = 147456;
  const int O_SPLIT2   = 409600;
  const int O_MH1      = 802816;
  const int O_MH2      = 819200;
  const int O_MO1      = 835584;
  const int O_MO2      = 851968;
  const int O_MLP1     = 868352;
  const int O_MLP2     = 999424;

  unsigned short* THi = (unsigned short*)(WTb + O_TRANSFORM);
  unsigned short* TLo = THi + 32768;
  unsigned short* WI16 = (unsigned short*)(WTb + O_SPLIT);
  unsigned short* WH16 = WI16 + 4*65536;

  unsigned short* SP2 = (unsigned short*)(WTb + O_SPLIT2);
  unsigned short* GGChi = SP2;                 unsigned short* GGClo = GGChi + 16384;
  unsigned short* GIHhi = GGClo + 16384;       unsigned short* GIHlo = GIHhi + 49152;
  unsigned short* GHHhi = GIHlo + 49152;       unsigned short* GHHlo = GHHhi + 49152;
  unsigned short* FCShi = GHHlo + 49152;       unsigned short* FCSlo = FCShi + 65536;
  unsigned short* FCNhi = FCSlo + 65536;       unsigned short* FCNlo = FCNhi + 65536;

  TDescArr da;
  int di = 0;
  auto addT = [&](const float* s, float* d, int R, int C){ da.d[di].src=s; da.d[di].dst=d; da.d[di].R=R; da.d[di].C=C; ++di; };
  addT(mh_W1, WTb + O_MH1, 128, 128);
  addT(mh_W2, WTb + O_MH2, 128, 128);
  addT(mo_W1, WTb + O_MO1, 128, 128);
  addT(mo_W2, WTb + O_MO2, 128, 128);
  addT(mlp_W1, WTb + O_MLP1, 256, 512);
  addT(mlp_W2, WTb + O_MLP2, 128, 256);
  transpose_many<<<dim3(512, di), 256, 0, stream>>>(da);
  bias_sum_kernel<<<8, 256, 0, stream>>>(lstm_bih, lstm_bhh, bsum);
  f32to16_kernel<<<(4*512*128)/1024, 256, 0, stream>>>(lstm_Wih, WI16);
  f32to16_kernel<<<(4*512*128)/1024, 256, 0, stream>>>(lstm_Whh, WH16);
  wsplit16_kernel<<<32768/256, 256, 0, stream>>>(transform_W, THi, TLo);
  wsplit16_kernel<<<16384/256, 256, 0, stream>>>(ggc_W, GGChi, GGClo);
  wsplit16_kernel<<<49152/256, 256, 0, stream>>>(gru_Wih, GIHhi, GIHlo);
  wsplit16_kernel<<<49152/256, 256, 0, stream>>>(gru_Whh, GHHhi, GHHlo);
  wsplit16_kernel<<<65536/256, 256, 0, stream>>>(fcs_W, FCShi, FCSlo);
  wsplit16_kernel<<<65536/256, 256, 0, stream>>>(fcn_W, FCNhi, FCNlo);
  // CSR build (once; shared by both GGC iterations)
  hipMemsetAsync(csr_cnt, 0, (size_t)NN*sizeof(int), stream);
  hist_kernel<<<E2N/256, 256, 0, stream>>>(dst2, csr_cnt);
  scan_kernel<<<1, 1024, 0, stream>>>(csr_cnt, csr_rowptr, csr_cursor);
  fill_kernel<<<E2N/256, 256, 0, stream>>>(src2, dst2, csr_cursor, csr_elist);

  auto smemK = [](int K, int BN){ return (size_t)(32*(K+4) + 16*BN)*4; };
  const int gB = BB/32;
  const int gM = NN/64;
  const size_t LDS2 = 69632;

  embed3_kernel<<<dim3(NF/256, 3), 256, 0, stream>>>(act_ids, dur_ids, act2_ids,
      emb_act, emb_dur, emb_act2, ha, hd, hg2, fs16a, fs16d);
  // transform -> res AND hh (dual output, replaces memcpy)
  mgemm2<<<gM, 512, LDS2, stream>>>(hg2, THi, TLo, hd, THi + 128, TLo + 128,
      transform_b, nullptr, res, hh, 256);

  for (int it=0; it<2; ++it) {
    mgemm<<<gM, 512, 0, stream>>>(hh, GGChi, GGClo, ggc_b, mb, 128, 1);
    gather_ggc<<<NN/4, 256, 0, stream>>>(mb, csr_rowptr, csr_elist, abuf);
    gru_fused<<<gM, 512, LDS2, stream>>>(abuf, hh, GIHhi, GIHlo, GHHhi, GHHlo,
        gru_bih, gru_bhh);
  }
  ln_lrelu_kernel<<<NN, 128, 0, stream>>>(hnf, hh, res, hn_g, hn_b);
  segmean_kernel<<<BB, 128, 0, stream>>>(hg2m, hnf, nullptr);

  for (int l=0; l<2; ++l) {
    const int i0 = l*2 + 0, i1 = l*2 + 1;
    lstm_fused6<<<1024, 512, 0, stream>>>(hLb, fs16a, fs16d, nbr_a2d, nbr_d2a,
        WI16 + i0*65536, WH16 + i0*65536,
        WI16 + i1*65536, WH16 + i1*65536,
        bsum + i0*512, bsum + i1*512);

    mgemm2<<<gM, 512, LDS2, stream>>>(hd, FCShi + i0*16384, FCSlo + i0*16384,
        hLb, FCNhi + i0*16384, FCNlo + i0*16384,
        fcs_b + i0*128, fcn_b + i0*128, nd, nullptr, 128);
    mgemm2<<<gM, 512, LDS2, stream>>>(ha, FCShi + i1*16384, FCSlo + i1*16384,
        hLb + (size_t)NN*128, FCNhi + i1*16384, FCNlo + i1*16384,
        fcs_b + i1*128, fcn_b + i1*128, na, nullptr, 128);
    ln13_kernel<<<NN, 128, 0, stream>>>(ha, na, n1_g + i0*128, n1_b + i0*128,
        n3_g + i0*128, n3_b + i0*128, (l==0) ? fs16a : nullptr);
    ln13_kernel<<<NN, 128, 0, stream>>>(hd, nd, n1_g + i1*128, n1_b + i1*128,
        n3_g + i1*128, n3_b + i1*128, (l==0) ? fs16d : nullptr);
  }
  segmean_kernel<<<BB, 128, 0, stream>>>(hgm, ha, hd);

  gemm_nt<128,1><<<gB, 256, smemK(128,128), stream>>>(hg2m, nullptr, nullptr, nullptr, 128,
      WTb + O_MO1, mo_b1, t1b, 128, 0);
  gemm_nt<128,1><<<gB, 256, smemK(128,128), stream>>>(t1b, nullptr, nullptr, nullptr, 128,
      WTb + O_MO2, mo_b2, o1b, 128, 0);
  gemm_nt<128,1><<<gB, 256, smemK(128,128), stream>>>(hgm, nullptr, nullptr, nullptr, 128,
      WTb + O_MH1, mh_b1, t2b, 128, 0);
  gemm_nt<128,1><<<gB, 256, smemK(128,128), stream>>>(t2b, nullptr, nullptr, nullptr, 128,
      WTb + O_MH2, mh_b2, o2b, 128, 0);
  gemm_nt<256,0><<<gB, 256, smemK(256,256), stream>>>(o1b, hg2m, nullptr, nullptr, 128,
      WTb + O_MLP1, nullptr, h1b, 256, 0);
  gemm_nt<256,1><<<gB, 256, smemK(256,256), stream>>>(o2b, hgm, nullptr, nullptr, 128,
      WTb + O_MLP1 + 256*256, mlp_b1, h1b, 256, 1);
  gemm_nt<128,1><<<gB, 256, smemK(256,128), stream>>>(h1b, h1b + 128, nullptr, nullptr, 256,
      WTb + O_MLP2, mlp_b2, h2b, 256, 0);
  cls_kernel<<<10, 256, 0, stream>>>((float*)d_out, h2b, cls_W, cls_b);
}

// Round 18
// 1583.362 us; speedup vs baseline: 3.3734x; 1.0263x over previous
//
#include <hip/hip_runtime.h>
#include <hip/hip_fp16.h>
#include <math.h>

#define NN 32768
#define HH 128
#define DD 16
#define BB 256
#define E2N (NN*DD)
#define NF (NN*HH)

typedef __attribute__((ext_vector_type(4))) float f32x4;
typedef __attribute__((ext_vector_type(4))) unsigned short u16x4;
typedef __attribute__((ext_vector_type(8))) unsigned short u16x8;
typedef _Float16 f16x8 __attribute__((ext_vector_type(8)));

__device__ __forceinline__ float fsig(float x) {
  return __builtin_amdgcn_rcpf(1.0f + __builtin_amdgcn_exp2f(-1.442695041f*x));
}
__device__ __forceinline__ float ftanh(float x) {
  return 1.0f - 2.0f*__builtin_amdgcn_rcpf(1.0f + __builtin_amdgcn_exp2f(2.885390082f*x));
}

// ---------------- transpose prep (head weights -> [K][Nout]) ----------------
struct TDesc { const float* src; float* dst; int R; int C; };
struct TDescArr { TDesc d[8]; };

__global__ void transpose_many(TDescArr da) {
  TDesc t = da.d[blockIdx.y];
  int idx = blockIdx.x*256 + threadIdx.x;
  if (idx < t.R*t.C) {
    int r = idx / t.C, c = idx - r*t.C;
    t.dst[(size_t)c*t.R + r] = t.src[idx];
  }
}

__global__ void bias_sum_kernel(const float* __restrict__ bih, const float* __restrict__ bhh,
                                float* __restrict__ bsum) {
  int i = blockIdx.x*256 + threadIdx.x;
  if (i < 2048) bsum[i] = bih[i] + bhh[i];
}

__global__ void f32to16_kernel(const float* __restrict__ in, unsigned short* __restrict__ out) {
  int base = (blockIdx.x*256 + threadIdx.x) * 4;
  float4 v = *(const float4*)(in + base);
  u16x4 p;
  p[0] = __half_as_ushort(__float2half_rn(v.x));
  p[1] = __half_as_ushort(__float2half_rn(v.y));
  p[2] = __half_as_ushort(__float2half_rn(v.z));
  p[3] = __half_as_ushort(__float2half_rn(v.w));
  *(u16x4*)(out + base) = p;
}

// ---------------- CSR build ----------------
__global__ void hist_kernel(const int* __restrict__ dst, int* __restrict__ cnt) {
  int e = blockIdx.x*256 + threadIdx.x;
  atomicAdd(&cnt[dst[e]], 1);
}

__global__ __launch_bounds__(1024) void scan_kernel(const int* __restrict__ cnt,
                                                    int* __restrict__ rowptr,
                                                    int* __restrict__ cursor) {
  __shared__ int part[1024];
  const int t = threadIdx.x;
  const int base = t*32;
  int loc[32];
  int s = 0;
#pragma unroll
  for (int k=0;k<32;++k){ loc[k]=s; s += cnt[base+k]; }
  part[t] = s;
  __syncthreads();
  for (int off=1; off<1024; off<<=1) {
    int v = (t>=off) ? part[t-off] : 0;
    __syncthreads();
    part[t] += v;
    __syncthreads();
  }
  int pbase = part[t] - s;
#pragma unroll
  for (int k=0;k<32;++k){ int v = pbase + loc[k]; rowptr[base+k]=v; cursor[base+k]=v; }
  if (t == 1023) rowptr[NN] = part[1023];
}

__global__ void fill_kernel(const int* __restrict__ src, const int* __restrict__ dst,
                            int* __restrict__ cursor, int* __restrict__ elist) {
  int e = blockIdx.x*256 + threadIdx.x;
  int p = atomicAdd(&cursor[dst[e]], 1);
  elist[p] = src[e];
}

__global__ __launch_bounds__(256) void gather_ggc(const float* __restrict__ m,
    const int* __restrict__ rowptr, const int* __restrict__ elist,
    float* __restrict__ a) {
  const int node = blockIdx.x*4 + (threadIdx.x>>6);
  const int lane = threadIdx.x & 63;
  const int s0 = rowptr[node], s1 = rowptr[node+1];
  float a0 = 0.0f, a1 = 0.0f;
  for (int e=s0; e<s1; ++e) {
    const float* mr = m + (size_t)elist[e]*128;
    a0 += mr[lane];
    a1 += mr[64+lane];
  }
  float* ar = a + (size_t)node*128;
  ar[lane] = a0;
  ar[64+lane] = a1;
}

// ---------------- embeddings (+fp16 shadows) ----------------
__global__ void embed3_kernel(const int* __restrict__ a_ids, const int* __restrict__ d_ids,
                              const int* __restrict__ a2_ids,
                              const float* __restrict__ ea, const float* __restrict__ ed,
                              const float* __restrict__ ea2,
                              float* __restrict__ ha, float* __restrict__ hd,
                              float* __restrict__ hg2,
                              unsigned short* __restrict__ fs16a,
                              unsigned short* __restrict__ fs16d) {
  int idx = blockIdx.x*256 + threadIdx.x;
  int n = idx >> 7, j = idx & 127;
  int w = blockIdx.y;
  if (w == 0) {
    float v = ea[(size_t)a_ids[n]*128 + j];
    ha[idx] = v;
    fs16a[idx] = __half_as_ushort(__float2half_rn(v));
  } else if (w == 1) {
    float v = ed[(size_t)d_ids[n]*128 + j];
    hd[idx] = v;
    fs16d[idx] = __half_as_ushort(__float2half_rn(v));
  } else {
    hg2[idx] = ea2[(size_t)a2_ids[n]*128 + j];
  }
}

// ---------------- generic fp32 GEMM (heads only) ----------------
template<int BN, int ACT>
__global__ __launch_bounds__(256) void gemm_nt(
    const float* __restrict__ A0, const float* __restrict__ A1,
    const float* __restrict__ A2, const float* __restrict__ A3,
    int lda, const float* __restrict__ WT, const float* __restrict__ bias,
    float* __restrict__ C, int K, int beta)
{
  extern __shared__ float sm[];
  const int KP = K + 4;
  float* At = sm;
  float* Bc = sm + 32*KP;
  const int tid = threadIdx.x;
  const int m0 = blockIdx.x*32;
  const int ng = tid >> 5, cg = tid & 31;
  const int n0 = ng*4, c4 = cg*4;
  constexpr int G = BN/128;
  float acc[G][4][4];
#pragma unroll
  for (int g=0; g<G; ++g)
#pragma unroll
    for (int i=0;i<4;++i)
#pragma unroll
      for (int e=0;e<4;++e) acc[g][i][e] = 0.0f;

  const int nf4 = K >> 2;
  for (int idx = tid; idx < 32*nf4; idx += 256) {
    int row = idx / nf4;
    int kk = (idx - row*nf4) << 2;
    const float* Ap = (kk < 128) ? A0 : (kk < 256) ? A1 : (kk < 384) ? A2 : A3;
    float4 v = *(const float4*)(Ap + (size_t)(m0+row)*lda + (kk & 127));
    *(float4*)(At + row*KP + kk) = v;
  }
  const int nchunk = K >> 4;
  for (int kc = 0; kc < nchunk; ++kc) {
    __syncthreads();
    for (int idx = tid; idx < 16*(BN/4); idx += 256) {
      int kk = idx / (BN/4);
      int jq = idx - kk*(BN/4);
      *(float4*)(Bc + kk*BN + jq*4) = *(const float4*)(WT + (size_t)(kc*16+kk)*BN + jq*4);
    }
    __syncthreads();
    for (int k=0;k<16;++k) {
      const int kk = kc*16 + k;
      float av[4];
#pragma unroll
      for (int i=0;i<4;++i) av[i] = At[(n0+i)*KP + kk];
#pragma unroll
      for (int g=0; g<G; ++g) {
        float4 bv = *(const float4*)(Bc + k*BN + g*128 + c4);
        float bb[4] = {bv.x, bv.y, bv.z, bv.w};
#pragma unroll
        for (int i=0;i<4;++i)
#pragma unroll
          for (int e=0;e<4;++e)
            acc[g][i][e] += av[i]*bb[e];
      }
    }
  }
#pragma unroll
  for (int g=0; g<G; ++g) {
#pragma unroll
    for (int i=0;i<4;++i) {
      float* dst = C + (size_t)(m0+n0+i)*BN + g*128 + c4;
      float o[4];
#pragma unroll
      for (int e=0;e<4;++e) o[e] = acc[g][i][e];
      if (bias) {
#pragma unroll
        for (int e=0;e<4;++e) o[e] += bias[g*128 + c4 + e];
      }
      if (beta) {
        float4 p = *(const float4*)dst;
        o[0]+=p.x; o[1]+=p.y; o[2]+=p.z; o[3]+=p.w;
      }
      if (ACT==1) {
#pragma unroll
        for (int e=0;e<4;++e) o[e] = fmaxf(o[e], 0.0f);
      }
      *(float4*)dst = make_float4(o[0],o[1],o[2],o[3]);
    }
  }
}

// ---------------- fp16-single staging (1 cvt/elem) ----------------
__device__ __forceinline__ void stage_f16(const float* __restrict__ A, int rb, int tid,
                                          unsigned short* x16) {
  const int r = tid >> 3;
  const int cf = (tid & 7) * 16;
  const float* src = A + (size_t)(rb + r)*128 + cf;
  unsigned short* d = x16 + r*136 + cf;
#pragma unroll
  for (int q=0; q<4; ++q) {
    float4 v = *(const float4*)(src + q*4);
    u16x4 p;
    p[0] = __half_as_ushort(__float2half_rn(v.x));
    p[1] = __half_as_ushort(__float2half_rn(v.y));
    p[2] = __half_as_ushort(__float2half_rn(v.z));
    p[3] = __half_as_ushort(__float2half_rn(v.w));
    *(u16x4*)(d + q*4) = p;
  }
}

// ---------------- MFMA GEMM single-input, fp16-single ----------------
__global__ __launch_bounds__(512) void mgemm(
    const float* __restrict__ A, const unsigned short* __restrict__ W16,
    const float* __restrict__ bias, float* __restrict__ C, int BN, int ntpw)
{
  __shared__ unsigned short x16[64*136];
  const int tid = threadIdx.x;
  const int w = tid >> 6;
  const int lane = tid & 63;
  const int ln16 = lane & 15;
  const int lq = lane >> 4;
  const int rb = blockIdx.x * 64;
  stage_f16(A, rb, tid, x16);
  __syncthreads();

  for (int j=0; j<ntpw; ++j) {
    const int tile = w + j*8;
    f32x4 acc[4];
    f32x4 bv = *(const f32x4*)(bias + tile*16 + lq*4);
#pragma unroll
    for (int nt=0; nt<4; ++nt) acc[nt] = bv;
#pragma unroll
    for (int kt=0; kt<4; ++kt) {
      const int bo = kt*32 + lq*8;
      f16x8 bx[4];
#pragma unroll
      for (int nt=0; nt<4; ++nt)
        bx[nt] = *(const f16x8*)(x16 + (nt*16+ln16)*136 + bo);
      f16x8 ah = *(const f16x8*)(W16 + (size_t)(tile*16 + ln16)*128 + kt*32 + lq*8);
#pragma unroll
      for (int nt=0; nt<4; ++nt)
        acc[nt] = __builtin_amdgcn_mfma_f32_16x16x32_f16(ah, bx[nt], acc[nt], 0,0,0);
    }
#pragma unroll
    for (int nt=0; nt<4; ++nt) {
      f32x4 o = acc[nt];
      *(float4*)(C + (size_t)(rb + nt*16 + ln16)*BN + tile*16 + lq*4) =
          make_float4(o[0],o[1],o[2],o[3]);
    }
  }
}

// ---------------- MFMA GEMM dual-input, fp16-single (+optional dual output) ----------------
__global__ __launch_bounds__(512) void mgemm2(
    const float* __restrict__ A1, const unsigned short* __restrict__ W1,
    const float* __restrict__ A2, const unsigned short* __restrict__ W2,
    const float* __restrict__ bias1, const float* __restrict__ bias2,
    float* __restrict__ C, float* __restrict__ C2, int wstride)
{
  __shared__ unsigned short x1[64*136];
  __shared__ unsigned short x2[64*136];
  const int tid = threadIdx.x;
  const int w = tid >> 6;
  const int lane = tid & 63;
  const int ln16 = lane & 15;
  const int lq = lane >> 4;
  const int rb = blockIdx.x * 64;
  stage_f16(A1, rb, tid, x1);
  stage_f16(A2, rb, tid, x2);
  __syncthreads();

  f32x4 acc[4];
  {
    f32x4 bv = *(const f32x4*)(bias1 + w*16 + lq*4);
    if (bias2) {
      f32x4 b2 = *(const f32x4*)(bias2 + w*16 + lq*4);
#pragma unroll
      for (int e=0;e<4;++e) bv[e] += b2[e];
    }
#pragma unroll
    for (int nt=0; nt<4; ++nt) acc[nt] = bv;
  }
#pragma unroll
  for (int p=0; p<2; ++p) {
    const unsigned short* x = p ? x2 : x1;
    const unsigned short* W = p ? W2 : W1;
#pragma unroll
    for (int kt=0; kt<4; ++kt) {
      const int bo = kt*32 + lq*8;
      f16x8 bx[4];
#pragma unroll
      for (int nt=0; nt<4; ++nt)
        bx[nt] = *(const f16x8*)(x + (nt*16+ln16)*136 + bo);
      f16x8 ah = *(const f16x8*)(W + (size_t)(w*16 + ln16)*wstride + kt*32 + lq*8);
#pragma unroll
      for (int nt=0; nt<4; ++nt)
        acc[nt] = __builtin_amdgcn_mfma_f32_16x16x32_f16(ah, bx[nt], acc[nt], 0,0,0);
    }
  }
#pragma unroll
  for (int nt=0; nt<4; ++nt) {
    f32x4 o = acc[nt];
    const size_t off = (size_t)(rb + nt*16 + ln16)*128 + w*16 + lq*4;
    *(float4*)(C + off) = make_float4(o[0],o[1],o[2],o[3]);
    if (C2) *(float4*)(C2 + off) = make_float4(o[0],o[1],o[2],o[3]);
  }
}

// ---------------- fused GRU, fp16-single ----------------
__global__ __launch_bounds__(512) void gru_fused(
    const float* __restrict__ abuf, float* __restrict__ hh,
    const unsigned short* __restrict__ GI16, const unsigned short* __restrict__ GH16,
    const float* __restrict__ bih, const float* __restrict__ bhh)
{
  __shared__ unsigned short x16[64*136];
  __shared__ unsigned short h16[64*136];
  const int tid = threadIdx.x;
  const int w = tid >> 6;
  const int lane = tid & 63;
  const int ln16 = lane & 15;
  const int lq = lane >> 4;
  const int rb = blockIdx.x * 64;
  stage_f16(abuf, rb, tid, x16);
  stage_f16(hh, rb, tid, h16);
  __syncthreads();

  f32x4 rr[4], zz[4], nn_[4];
#pragma unroll
  for (int j=0; j<3; ++j) {
    const int tile = w + j*8;
    f32x4 ai[4], ag[4];
    f32x4 bi = *(const f32x4*)(bih + tile*16 + lq*4);
    f32x4 bg = *(const f32x4*)(bhh + tile*16 + lq*4);
#pragma unroll
    for (int nt=0; nt<4; ++nt) { ai[nt] = bi; ag[nt] = bg; }
#pragma unroll
    for (int kt=0; kt<4; ++kt) {
      const int bo = kt*32 + lq*8;
      f16x8 bx[4], bh_[4];
#pragma unroll
      for (int nt=0; nt<4; ++nt) {
        bx[nt] = *(const f16x8*)(x16 + (nt*16+ln16)*136 + bo);
        bh_[nt] = *(const f16x8*)(h16 + (nt*16+ln16)*136 + bo);
      }
      const size_t co = (size_t)(tile*16 + ln16)*128 + kt*32 + lq*8;
      f16x8 aI = *(const f16x8*)(GI16 + co);
      f16x8 aH = *(const f16x8*)(GH16 + co);
#pragma unroll
      for (int nt=0; nt<4; ++nt) {
        ai[nt] = __builtin_amdgcn_mfma_f32_16x16x32_f16(aI, bx[nt], ai[nt], 0,0,0);
        ag[nt] = __builtin_amdgcn_mfma_f32_16x16x32_f16(aH, bh_[nt], ag[nt], 0,0,0);
      }
    }
#pragma unroll
    for (int nt=0; nt<4; ++nt) {
#pragma unroll
      for (int e=0; e<4; ++e) {
        if (j == 0)      rr[nt][e] = fsig(ai[nt][e] + ag[nt][e]);
        else if (j == 1) zz[nt][e] = fsig(ai[nt][e] + ag[nt][e]);
        else             nn_[nt][e] = ftanh(ai[nt][e] + rr[nt][e]*ag[nt][e]);
      }
    }
  }
#pragma unroll
  for (int nt=0; nt<4; ++nt) {
    float* hp = hh + (size_t)(rb + nt*16 + ln16)*128 + w*16 + lq*4;
    float4 ho = *(const float4*)hp;
    float hv[4] = {ho.x, ho.y, ho.z, ho.w};
    float o[4];
#pragma unroll
    for (int e=0; e<4; ++e)
      o[e] = (1.0f - zz[nt][e])*nn_[nt][e] + zz[nt][e]*hv[e];
    *(float4*)hp = make_float4(o[0],o[1],o[2],o[3]);
  }
}

// ---------------- fused LSTM v6 (unchanged) ----------------
__global__ __launch_bounds__(512) void lstm_fused6(
    float* __restrict__ hL,
    const unsigned short* __restrict__ fs16a, const unsigned short* __restrict__ fs16d,
    const int* __restrict__ nbrA, const int* __restrict__ nbrD,
    const unsigned short* __restrict__ WI0, const unsigned short* __restrict__ WH0,
    const unsigned short* __restrict__ WI1, const unsigned short* __restrict__ WH1,
    const float* __restrict__ bsum0, const float* __restrict__ bsum1)
{
  __shared__ unsigned short xb[64*132];
  __shared__ unsigned short hb[64*132];
  const int tid = threadIdx.x;
  const int w = tid >> 6;
  const int lane = tid & 63;
  const int ln16 = lane & 15;
  const int lq = lane >> 4;
  const int b = blockIdx.x;
  const bool dir = (b >= 512);
  const int nb = (dir ? (b - 512) : b) * 64;
  const unsigned short* fs16 = dir ? fs16d : fs16a;
  const int* nbr = dir ? nbrD : nbrA;
  const unsigned short* WI = dir ? WI1 : WI0;
  const unsigned short* WH = dir ? WH1 : WH0;
  const float* bsum = dir ? bsum1 : bsum0;

  const int gr = tid >> 3;
  const int gc = (tid & 7) * 16;
  const int* nrow = nbr + (size_t)(nb + gr)*DD;

  f32x4 bias[4];
#pragma unroll
  for (int g=0; g<4; ++g)
    bias[g] = *(const f32x4*)(bsum + g*128 + w*16 + lq*4);

  f32x4 cst[4];
#pragma unroll
  for (int nt=0; nt<4; ++nt)
#pragma unroll
    for (int e=0; e<4; ++e) cst[nt][e] = 0.0f;

  u16x8 xg0, xg1;
  {
    int gidx = nrow[0];
    const unsigned short* src = fs16 + (size_t)gidx*128 + gc;
    xg0 = *(const u16x8*)(src);
    xg1 = *(const u16x8*)(src + 8);
    unsigned short* d = xb + gr*132 + gc;
    *(u16x8*)d = xg0;
    *(u16x8*)(d+8) = xg1;
  }
  int gnext = nrow[1];

#pragma unroll 1
  for (int t=0; t<16; ++t) {
    __syncthreads();

    f32x4 racc[4][4];
#pragma unroll
    for (int g=0; g<4; ++g)
#pragma unroll
      for (int nt=0; nt<4; ++nt)
        racc[g][nt] = bias[g];

#pragma unroll
    for (int kt=0; kt<4; ++kt) {
      const int bo = kt*32 + lq*8;
      f16x8 bx[4];
#pragma unroll
      for (int nt=0; nt<4; ++nt)
        bx[nt] = *(const f16x8*)(xb + (nt*16+ln16)*132 + bo);
#pragma unroll
      for (int g=0; g<4; ++g) {
        f16x8 aI = *(const f16x8*)(WI + (size_t)(g*128 + w*16 + ln16)*128 + kt*32 + lq*8);
#pragma unroll
        for (int nt=0; nt<4; ++nt)
          racc[g][nt] = __builtin_amdgcn_mfma_f32_16x16x32_f16(aI, bx[nt], racc[g][nt], 0,0,0);
      }
    }
    if (t < 15) {
      const unsigned short* src = fs16 + (size_t)gnext*128 + gc;
      xg0 = *(const u16x8*)(src);
      xg1 = *(const u16x8*)(src + 8);
      if (t < 14) gnext = nrow[t+2];
    }
    if (t > 0) {
#pragma unroll
      for (int kt=0; kt<4; ++kt) {
        const int bo = kt*32 + lq*8;
        f16x8 bh[4];
#pragma unroll
        for (int nt=0; nt<4; ++nt)
          bh[nt] = *(const f16x8*)(hb + (nt*16+ln16)*132 + bo);
#pragma unroll
        for (int g=0; g<4; ++g) {
          f16x8 aH = *(const f16x8*)(WH + (size_t)(g*128 + w*16 + ln16)*128 + kt*32 + lq*8);
#pragma unroll
          for (int nt=0; nt<4; ++nt)
            racc[g][nt] = __builtin_amdgcn_mfma_f32_16x16x32_f16(aH, bh[nt], racc[g][nt], 0,0,0);
        }
      }
    }
    __syncthreads();

#pragma unroll
    for (int nt=0; nt<4; ++nt) {
      float hv[4];
#pragma unroll
      for (int e=0; e<4; ++e) {
        float ig = fsig(racc[0][nt][e]);
        float fg = fsig(racc[1][nt][e]);
        float gg = ftanh(racc[2][nt][e]);
        float og = fsig(racc[3][nt][e]);
        float cc = fg*cst[nt][e] + ig*gg;
        cst[nt][e] = cc;
        hv[e] = og*ftanh(cc);
      }
      const int node = nt*16 + ln16;
      const int col = w*16 + lq*4;
      if (t < 15) {
        u16x4 hw;
#pragma unroll
        for (int e=0; e<4; ++e) hw[e] = __half_as_ushort(__float2half_rn(hv[e]));
        *(u16x4*)(hb + node*132 + col) = hw;
      } else {
        *(float4*)(hL + (size_t)((dir?NN:0) + nb + node)*128 + col) =
            make_float4(hv[0], hv[1], hv[2], hv[3]);
      }
    }
    if (t < 15) {
      unsigned short* d = xb + gr*132 + gc;
      *(u16x8*)d = xg0;
      *(u16x8*)(d+8) = xg1;
    }
  }
}

// ---------------- LayerNorm + leaky relu ----------------
__global__ void ln_lrelu_kernel(float* __restrict__ out, const float* __restrict__ x,
                                const float* __restrict__ add,
                                const float* __restrict__ g, const float* __restrict__ b) {
  int n = blockIdx.x, j = threadIdx.x;
  size_t base = (size_t)n*128;
  float v = x[base+j];
  if (add) v += add[base+j];
  __shared__ float sh[4];
  float s = v;
#pragma unroll
  for (int m=32; m>=1; m>>=1) s += __shfl_xor(s, m, 64);
  if ((j&63)==0) sh[j>>6] = s;
  __syncthreads();
  float mean = (sh[0]+sh[1]) * 0.0078125f;
  float d = v - mean;
  float q = d*d;
#pragma unroll
  for (int m=32; m>=1; m>>=1) q += __shfl_xor(q, m, 64);
  if ((j&63)==0) sh[2+(j>>6)] = q;
  __syncthreads();
  float var = (sh[2]+sh[3]) * 0.0078125f;
  float y = d * rsqrtf(var + 1e-5f) * g[j] + b[j];
  out[base+j] = (y >= 0.0f) ? y : 0.01f*y;
}

// ---------------- fused LN1 -> residual LN3 ----------------
__global__ void ln13_kernel(float* __restrict__ h, const float* __restrict__ nsrc,
                            const float* __restrict__ g1, const float* __restrict__ b1,
                            const float* __restrict__ g3, const float* __restrict__ b3,
                            unsigned short* __restrict__ out16) {
  int n = blockIdx.x, j = threadIdx.x;
  size_t base = (size_t)n*128;
  __shared__ float sh[4];
  float v = nsrc[base+j];
  float s = v;
#pragma unroll
  for (int m=32; m>=1; m>>=1) s += __shfl_xor(s, m, 64);
  if ((j&63)==0) sh[j>>6] = s;
  __syncthreads();
  float mean = (sh[0]+sh[1]) * 0.0078125f;
  float d = v - mean;
  float q = d*d;
#pragma unroll
  for (int m=32; m>=1; m>>=1) q += __shfl_xor(q, m, 64);
  if ((j&63)==0) sh[2+(j>>6)] = q;
  __syncthreads();
  float var = (sh[2]+sh[3]) * 0.0078125f;
  float y1 = d * rsqrtf(var + 1e-5f) * g1[j] + b1[j];
  y1 = (y1 >= 0.0f) ? y1 : 0.01f*y1;
  __syncthreads();
  float u = h[base+j] + y1;
  s = u;
#pragma unroll
  for (int m=32; m>=1; m>>=1) s += __shfl_xor(s, m, 64);
  if ((j&63)==0) sh[j>>6] = s;
  __syncthreads();
  mean = (sh[0]+sh[1]) * 0.0078125f;
  d = u - mean;
  q = d*d;
#pragma unroll
  for (int m=32; m>=1; m>>=1) q += __shfl_xor(q, m, 64);
  if ((j&63)==0) sh[2+(j>>6)] = q;
  __syncthreads();
  var = (sh[2]+sh[3]) * 0.0078125f;
  float y3 = d * rsqrtf(var + 1e-5f) * g3[j] + b3[j];
  float o = (y3 >= 0.0f) ? y3 : 0.01f*y3;
  h[base+j] = o;
  if (out16) out16[base+j] = __half_as_ushort(__float2half_rn(o));
}

// ---------------- segment mean ----------------
__global__ void segmean_kernel(float* __restrict__ out, const float* __restrict__ x,
                               const float* __restrict__ y) {
  int b = blockIdx.x, j = threadIdx.x;
  float s = 0.0f;
  for (int r=0; r<128; ++r) {
    size_t n = (size_t)(b*128 + r)*128 + j;
    s += x[n];
    if (y) s += y[n];
  }
  out[(size_t)b*128 + j] = s * 0.0078125f;
}

// ---------------- classifier head ----------------
__global__ void cls_kernel(float* __restrict__ out, const float* __restrict__ h2,
                           const float* __restrict__ Wc, const float* __restrict__ bc) {
  int gid = blockIdx.x*256 + threadIdx.x;
  if (gid >= BB*10) return;
  int mrow = gid/10, c = gid - mrow*10;
  const float* arow = h2 + (size_t)mrow*128;
  const float* wrow = Wc + (size_t)c*128;
  float s = bc[c];
  for (int k=0;k<128;++k) s += arow[k]*wrow[k];
  out[gid] = s;
}

__global__ void bail_kernel(float* out, float v) {
  if (threadIdx.x==0 && blockIdx.x==0) out[0] = v;
}

// ---------------- host orchestration ----------------
extern "C" void kernel_launch(void* const* d_in, const int* in_sizes, int n_in,
                              void* d_out, int out_size, void* d_ws, size_t ws_size,
                              hipStream_t stream)
{
  const int* act_ids  = (const int*)d_in[0];
  const int* dur_ids  = (const int*)d_in[1];
  const int* act2_ids = (const int*)d_in[2];
  const int* nbr_a2d  = (const int*)d_in[3];
  const int* nbr_d2a  = (const int*)d_in[4];
  const int* src2     = (const int*)d_in[5];
  const int* dst2     = (const int*)d_in[6];
  const float* emb_act     = (const float*)d_in[8];
  const float* emb_dur     = (const float*)d_in[9];
  const float* emb_act2    = (const float*)d_in[10];
  const float* transform_W = (const float*)d_in[11];
  const float* transform_b = (const float*)d_in[12];
  const float* ggc_W   = (const float*)d_in[13];
  const float* ggc_b   = (const float*)d_in[14];
  const float* gru_Wih = (const float*)d_in[15];
  const float* gru_Whh = (const float*)d_in[16];
  const float* gru_bih = (const float*)d_in[17];
  const float* gru_bhh = (const float*)d_in[18];
  const float* hn_g    = (const float*)d_in[19];
  const float* hn_b    = (const float*)d_in[20];
  const float* lstm_Wih = (const float*)d_in[21];
  const float* lstm_Whh = (const float*)d_in[22];
  const float* lstm_bih = (const float*)d_in[23];
  const float* lstm_bhh = (const float*)d_in[24];
  const float* fcs_W = (const float*)d_in[25];
  const float* fcs_b = (const float*)d_in[26];
  const float* fcn_W = (const float*)d_in[27];
  const float* fcn_b = (const float*)d_in[28];
  const float* n1_g = (const float*)d_in[29];
  const float* n1_b = (const float*)d_in[30];
  const float* n3_g = (const float*)d_in[31];
  const float* n3_b = (const float*)d_in[32];
  const float* mh_W1 = (const float*)d_in[33];
  const float* mh_b1 = (const float*)d_in[34];
  const float* mh_W2 = (const float*)d_in[35];
  const float* mh_b2 = (const float*)d_in[36];
  const float* mo_W1 = (const float*)d_in[37];
  const float* mo_b1 = (const float*)d_in[38];
  const float* mo_W2 = (const float*)d_in[39];
  const float* mo_b2 = (const float*)d_in[40];
  const float* mlp_W1 = (const float*)d_in[41];
  const float* mlp_b1 = (const float*)d_in[42];
  const float* mlp_W2 = (const float*)d_in[43];
  const float* mlp_b2 = (const float*)d_in[44];
  const float* cls_W = (const float*)d_in[45];
  const float* cls_b = (const float*)d_in[46];

  float* ws = (float*)d_ws;
  float* ha   = ws;
  float* hd   = ws + (size_t)NF;
  float* hg2  = ws + 2*(size_t)NF;
  float* res  = ws + 3*(size_t)NF;
  float* hh   = ws + 4*(size_t)NF;
  float* SCR  = ws + 5*(size_t)NF;
  float* mb   = SCR;
  float* abuf = SCR + (size_t)NF;
  float* hnf  = mb;
  float* hLb  = SCR + 8*(size_t)NF;
  float* SMALL = ws + 15*(size_t)NF;
  float* hg2m = SMALL;
  float* hgm  = SMALL + 32768;
  float* o1b  = SMALL + 65536;
  float* o2b  = SMALL + 98304;
  float* t1b  = SMALL + 131072;
  float* t2b  = SMALL + 163840;
  float* h1b  = SMALL + 196608;
  float* h2b  = SMALL + 262144;
  float* bsum = SMALL + 294912;
  float* WTb  = SMALL + 296960;
  const size_t NEED_BYTES = (size_t)(15*(size_t)NF + 296960 + 1032192) * 4;
  if (ws_size < NEED_BYTES) {
    hipMemsetAsync(d_out, 0, (size_t)out_size*sizeof(float), stream);
    bail_kernel<<<1,64,0,stream>>>((float*)d_out, (float)ws_size);
    return;
  }
  float* na = hg2;
  float* nd = res;
  unsigned short* fs16a = (unsigned short*)(SCR + 2*(size_t)NF);
  unsigned short* fs16d = fs16a + (size_t)NF;
  int* csr_cnt    = (int*)(SCR + 3*(size_t)NF);
  int* csr_rowptr = csr_cnt + NN;
  int* csr_cursor = csr_rowptr + NN + 2;
  int* csr_elist  = csr_cursor + NN;

  const int O_TRANSFORM = 0;       // T16: 32768 halfs
  const int O_SPLIT    = 147456;   // lstm WI/WH fp16
  const int O_SPLIT2   = 409600;   // fp16-single tail weights
  const int O_MH1      = 802816;
  const int O_MH2      = 819200;
  const int O_MO1      = 835584;
  const int O_MO2      = 851968;
  const int O_MLP1     = 868352;
  const int O_MLP2     = 999424;

  unsigned short* T16 = (unsigned short*)(WTb + O_TRANSFORM);
  unsigned short* WI16 = (unsigned short*)(WTb + O_SPLIT);
  unsigned short* WH16 = WI16 + 4*65536;

  unsigned short* SP2 = (unsigned short*)(WTb + O_SPLIT2);
  unsigned short* GGC16 = SP2;
  unsigned short* GIH16 = GGC16 + 16384;
  unsigned short* GHH16 = GIH16 + 49152;
  unsigned short* FCS16 = GHH16 + 49152;
  unsigned short* FCN16 = FCS16 + 65536;

  TDescArr da;
  int di = 0;
  auto addT = [&](const float* s, float* d, int R, int C){ da.d[di].src=s; da.d[di].dst=d; da.d[di].R=R; da.d[di].C=C; ++di; };
  addT(mh_W1, WTb + O_MH1, 128, 128);
  addT(mh_W2, WTb + O_MH2, 128, 128);
  addT(mo_W1, WTb + O_MO1, 128, 128);
  addT(mo_W2, WTb + O_MO2, 128, 128);
  addT(mlp_W1, WTb + O_MLP1, 256, 512);
  addT(mlp_W2, WTb + O_MLP2, 128, 256);
  transpose_many<<<dim3(512, di), 256, 0, stream>>>(da);
  bias_sum_kernel<<<8, 256, 0, stream>>>(lstm_bih, lstm_bhh, bsum);
  f32to16_kernel<<<(4*512*128)/1024, 256, 0, stream>>>(lstm_Wih, WI16);
  f32to16_kernel<<<(4*512*128)/1024, 256, 0, stream>>>(lstm_Whh, WH16);
  f32to16_kernel<<<32768/1024, 256, 0, stream>>>(transform_W, T16);
  f32to16_kernel<<<16384/1024, 256, 0, stream>>>(ggc_W, GGC16);
  f32to16_kernel<<<49152/1024, 256, 0, stream>>>(gru_Wih, GIH16);
  f32to16_kernel<<<49152/1024, 256, 0, stream>>>(gru_Whh, GHH16);
  f32to16_kernel<<<65536/1024, 256, 0, stream>>>(fcs_W, FCS16);
  f32to16_kernel<<<65536/1024, 256, 0, stream>>>(fcn_W, FCN16);
  hipMemsetAsync(csr_cnt, 0, (size_t)NN*sizeof(int), stream);
  hist_kernel<<<E2N/256, 256, 0, stream>>>(dst2, csr_cnt);
  scan_kernel<<<1, 1024, 0, stream>>>(csr_cnt, csr_rowptr, csr_cursor);
  fill_kernel<<<E2N/256, 256, 0, stream>>>(src2, dst2, csr_cursor, csr_elist);

  auto smemK = [](int K, int BN){ return (size_t)(32*(K+4) + 16*BN)*4; };
  const int gB = BB/32;
  const int gM = NN/64;

  embed3_kernel<<<dim3(NF/256, 3), 256, 0, stream>>>(act_ids, dur_ids, act2_ids,
      emb_act, emb_dur, emb_act2, ha, hd, hg2, fs16a, fs16d);
  mgemm2<<<gM, 512, 0, stream>>>(hg2, T16, hd, T16 + 128,
      transform_b, nullptr, res, hh, 256);

  for (int it=0; it<2; ++it) {
    mgemm<<<gM, 512, 0, stream>>>(hh, GGC16, ggc_b, mb, 128, 1);
    gather_ggc<<<NN/4, 256, 0, stream>>>(mb, csr_rowptr, csr_elist, abuf);
    gru_fused<<<gM, 512, 0, stream>>>(abuf, hh, GIH16, GHH16, gru_bih, gru_bhh);
  }
  ln_lrelu_kernel<<<NN, 128, 0, stream>>>(hnf, hh, res, hn_g, hn_b);
  segmean_kernel<<<BB, 128, 0, stream>>>(hg2m, hnf, nullptr);

  for (int l=0; l<2; ++l) {
    const int i0 = l*2 + 0, i1 = l*2 + 1;
    lstm_fused6<<<1024, 512, 0, stream>>>(hLb, fs16a, fs16d, nbr_a2d, nbr_d2a,
        WI16 + i0*65536, WH16 + i0*65536,
        WI16 + i1*65536, WH16 + i1*65536,
        bsum + i0*512, bsum + i1*512);

    mgemm2<<<gM, 512, 0, stream>>>(hd, FCS16 + i0*16384,
        hLb, FCN16 + i0*16384,
        fcs_b + i0*128, fcn_b + i0*128, nd, nullptr, 128);
    mgemm2<<<gM, 512, 0, stream>>>(ha, FCS16 + i1*16384,
        hLb + (size_t)NN*128, FCN16 + i1*16384,
        fcs_b + i1*128, fcn_b + i1*128, na, nullptr, 128);
    ln13_kernel<<<NN, 128, 0, stream>>>(ha, na, n1_g + i0*128, n1_b + i0*128,
        n3_g + i0*128, n3_b + i0*128, (l==0) ? fs16a : nullptr);
    ln13_kernel<<<NN, 128, 0, stream>>>(hd, nd, n1_g + i1*128, n1_b + i1*128,
        n3_g + i1*128, n3_b + i1*128, (l==0) ? fs16d : nullptr);
  }
  segmean_kernel<<<BB, 128, 0, stream>>>(hgm, ha, hd);

  gemm_nt<128,1><<<gB, 256, smemK(128,128), stream>>>(hg2m, nullptr, nullptr, nullptr, 128,
      WTb + O_MO1, mo_b1, t1b, 128, 0);
  gemm_nt<128,1><<<gB, 256, smemK(128,128), stream>>>(t1b, nullptr, nullptr, nullptr, 128,
      WTb + O_MO2, mo_b2, o1b, 128, 0);
  gemm_nt<128,1><<<gB, 256, smemK(128,128), stream>>>(hgm, nullptr, nullptr, nullptr, 128,
      WTb + O_MH1, mh_b1, t2b, 128, 0);
  gemm_nt<128,1><<<gB, 256, smemK(128,128), stream>>>(t2b, nullptr, nullptr, nullptr, 128,
      WTb + O_MH2, mh_b2, o2b, 128, 0);
  gemm_nt<256,0><<<gB, 256, smemK(256,256), stream>>>(o1b, hg2m, nullptr, nullptr, 128,
      WTb + O_MLP1, nullptr, h1b, 256, 0);
  gemm_nt<256,1><<<gB, 256, smemK(256,256), stream>>>(o2b, hgm, nullptr, nullptr, 128,
      WTb + O_MLP1 + 256*256, mlp_b1, h1b, 256, 1);
  gemm_nt<128,1><<<gB, 256, smemK(256,128), stream>>>(h1b, h1b + 128, nullptr, nullptr, 256,
      WTb + O_MLP2, mlp_b2, h2b, 256, 0);
  cls_kernel<<<10, 256, 0, stream>>>((float*)d_out, h2b, cls_W, cls_b);
}

// Round 19
// 1563.391 us; speedup vs baseline: 3.4165x; 1.0128x over previous
//
#include <hip/hip_runtime.h>
#include <hip/hip_fp16.h>
#include <math.h>

#define NN 32768
#define HH 128
#define DD 16
#define BB 256
#define E2N (NN*DD)
#define NF (NN*HH)

typedef __attribute__((ext_vector_type(4))) float f32x4;
typedef __attribute__((ext_vector_type(4))) unsigned short u16x4;
typedef __attribute__((ext_vector_type(8))) unsigned short u16x8;
typedef _Float16 f16x8 __attribute__((ext_vector_type(8)));

__device__ __forceinline__ float fsig(float x) {
  return __builtin_amdgcn_rcpf(1.0f + __builtin_amdgcn_exp2f(-1.442695041f*x));
}
__device__ __forceinline__ float ftanh(float x) {
  return 1.0f - 2.0f*__builtin_amdgcn_rcpf(1.0f + __builtin_amdgcn_exp2f(2.885390082f*x));
}

// ---------------- transpose prep (head weights -> [K][Nout]) ----------------
struct TDesc { const float* src; float* dst; int R; int C; };
struct TDescArr { TDesc d[8]; };

__global__ void transpose_many(TDescArr da) {
  TDesc t = da.d[blockIdx.y];
  int idx = blockIdx.x*256 + threadIdx.x;
  if (idx < t.R*t.C) {
    int r = idx / t.C, c = idx - r*t.C;
    t.dst[(size_t)c*t.R + r] = t.src[idx];
  }
}

__global__ void bias_sum_kernel(const float* __restrict__ bih, const float* __restrict__ bhh,
                                float* __restrict__ bsum) {
  int i = blockIdx.x*256 + threadIdx.x;
  if (i < 2048) bsum[i] = bih[i] + bhh[i];
}

// batched fp32->fp16 conversions (one launch for all weight tables)
struct CDesc { const float* src; unsigned short* dst; int n; };
struct CDescArr { CDesc d[8]; };

__global__ void f32to16_many(CDescArr da) {
  CDesc c = da.d[blockIdx.y];
  int base = (blockIdx.x*256 + threadIdx.x) * 4;
  if (base < c.n) {
    float4 v = *(const float4*)(c.src + base);
    u16x4 p;
    p[0] = __half_as_ushort(__float2half_rn(v.x));
    p[1] = __half_as_ushort(__float2half_rn(v.y));
    p[2] = __half_as_ushort(__float2half_rn(v.z));
    p[3] = __half_as_ushort(__float2half_rn(v.w));
    *(u16x4*)(c.dst + base) = p;
  }
}

// ---------------- CSR build ----------------
__global__ void hist_kernel(const int* __restrict__ dst, int* __restrict__ cnt) {
  int e = blockIdx.x*256 + threadIdx.x;
  atomicAdd(&cnt[dst[e]], 1);
}

__global__ __launch_bounds__(1024) void scan_kernel(const int* __restrict__ cnt,
                                                    int* __restrict__ rowptr,
                                                    int* __restrict__ cursor) {
  __shared__ int part[1024];
  const int t = threadIdx.x;
  const int base = t*32;
  int loc[32];
  int s = 0;
#pragma unroll
  for (int k=0;k<32;++k){ loc[k]=s; s += cnt[base+k]; }
  part[t] = s;
  __syncthreads();
  for (int off=1; off<1024; off<<=1) {
    int v = (t>=off) ? part[t-off] : 0;
    __syncthreads();
    part[t] += v;
    __syncthreads();
  }
  int pbase = part[t] - s;
#pragma unroll
  for (int k=0;k<32;++k){ int v = pbase + loc[k]; rowptr[base+k]=v; cursor[base+k]=v; }
  if (t == 1023) rowptr[NN] = part[1023];
}

__global__ void fill_kernel(const int* __restrict__ src, const int* __restrict__ dst,
                            int* __restrict__ cursor, int* __restrict__ elist) {
  int e = blockIdx.x*256 + threadIdx.x;
  int p = atomicAdd(&cursor[dst[e]], 1);
  elist[p] = src[e];
}

// gather-reduce on fp16 messages: a[node] = sum_in-edges m16[src]
__global__ __launch_bounds__(256) void gather_ggc(const unsigned short* __restrict__ m16,
    const int* __restrict__ rowptr, const int* __restrict__ elist,
    float* __restrict__ a) {
  const int node = blockIdx.x*4 + (threadIdx.x>>6);
  const int lane = threadIdx.x & 63;
  const int s0 = rowptr[node], s1 = rowptr[node+1];
  float a0 = 0.0f, a1 = 0.0f;
  for (int e=s0; e<s1; ++e) {
    const unsigned short* mr = m16 + (size_t)elist[e]*128;
    a0 += __half2float(__ushort_as_half(mr[lane]));
    a1 += __half2float(__ushort_as_half(mr[64+lane]));
  }
  float* ar = a + (size_t)node*128;
  ar[lane] = a0;
  ar[64+lane] = a1;
}

// ---------------- embeddings (+fp16 shadows) ----------------
__global__ void embed3_kernel(const int* __restrict__ a_ids, const int* __restrict__ d_ids,
                              const int* __restrict__ a2_ids,
                              const float* __restrict__ ea, const float* __restrict__ ed,
                              const float* __restrict__ ea2,
                              float* __restrict__ ha, float* __restrict__ hd,
                              float* __restrict__ hg2,
                              unsigned short* __restrict__ fs16a,
                              unsigned short* __restrict__ fs16d) {
  int idx = blockIdx.x*256 + threadIdx.x;
  int n = idx >> 7, j = idx & 127;
  int w = blockIdx.y;
  if (w == 0) {
    float v = ea[(size_t)a_ids[n]*128 + j];
    ha[idx] = v;
    fs16a[idx] = __half_as_ushort(__float2half_rn(v));
  } else if (w == 1) {
    float v = ed[(size_t)d_ids[n]*128 + j];
    hd[idx] = v;
    fs16d[idx] = __half_as_ushort(__float2half_rn(v));
  } else {
    hg2[idx] = ea2[(size_t)a2_ids[n]*128 + j];
  }
}

// ---------------- generic fp32 GEMM (heads only) ----------------
template<int BN, int ACT>
__global__ __launch_bounds__(256) void gemm_nt(
    const float* __restrict__ A0, const float* __restrict__ A1,
    const float* __restrict__ A2, const float* __restrict__ A3,
    int lda, const float* __restrict__ WT, const float* __restrict__ bias,
    float* __restrict__ C, int K, int beta)
{
  extern __shared__ float sm[];
  const int KP = K + 4;
  float* At = sm;
  float* Bc = sm + 32*KP;
  const int tid = threadIdx.x;
  const int m0 = blockIdx.x*32;
  const int ng = tid >> 5, cg = tid & 31;
  const int n0 = ng*4, c4 = cg*4;
  constexpr int G = BN/128;
  float acc[G][4][4];
#pragma unroll
  for (int g=0; g<G; ++g)
#pragma unroll
    for (int i=0;i<4;++i)
#pragma unroll
      for (int e=0;e<4;++e) acc[g][i][e] = 0.0f;

  const int nf4 = K >> 2;
  for (int idx = tid; idx < 32*nf4; idx += 256) {
    int row = idx / nf4;
    int kk = (idx - row*nf4) << 2;
    const float* Ap = (kk < 128) ? A0 : (kk < 256) ? A1 : (kk < 384) ? A2 : A3;
    float4 v = *(const float4*)(Ap + (size_t)(m0+row)*lda + (kk & 127));
    *(float4*)(At + row*KP + kk) = v;
  }
  const int nchunk = K >> 4;
  for (int kc = 0; kc < nchunk; ++kc) {
    __syncthreads();
    for (int idx = tid; idx < 16*(BN/4); idx += 256) {
      int kk = idx / (BN/4);
      int jq = idx - kk*(BN/4);
      *(float4*)(Bc + kk*BN + jq*4) = *(const float4*)(WT + (size_t)(kc*16+kk)*BN + jq*4);
    }
    __syncthreads();
    for (int k=0;k<16;++k) {
      const int kk = kc*16 + k;
      float av[4];
#pragma unroll
      for (int i=0;i<4;++i) av[i] = At[(n0+i)*KP + kk];
#pragma unroll
      for (int g=0; g<G; ++g) {
        float4 bv = *(const float4*)(Bc + k*BN + g*128 + c4);
        float bb[4] = {bv.x, bv.y, bv.z, bv.w};
#pragma unroll
        for (int i=0;i<4;++i)
#pragma unroll
          for (int e=0;e<4;++e)
            acc[g][i][e] += av[i]*bb[e];
      }
    }
  }
#pragma unroll
  for (int g=0; g<G; ++g) {
#pragma unroll
    for (int i=0;i<4;++i) {
      float* dst = C + (size_t)(m0+n0+i)*BN + g*128 + c4;
      float o[4];
#pragma unroll
      for (int e=0;e<4;++e) o[e] = acc[g][i][e];
      if (bias) {
#pragma unroll
        for (int e=0;e<4;++e) o[e] += bias[g*128 + c4 + e];
      }
      if (beta) {
        float4 p = *(const float4*)dst;
        o[0]+=p.x; o[1]+=p.y; o[2]+=p.z; o[3]+=p.w;
      }
      if (ACT==1) {
#pragma unroll
        for (int e=0;e<4;++e) o[e] = fmaxf(o[e], 0.0f);
      }
      *(float4*)dst = make_float4(o[0],o[1],o[2],o[3]);
    }
  }
}

// ---------------- fp16-single staging ----------------
__device__ __forceinline__ void stage_f16(const float* __restrict__ A, int rb, int tid,
                                          unsigned short* x16) {
  const int r = tid >> 3;
  const int cf = (tid & 7) * 16;
  const float* src = A + (size_t)(rb + r)*128 + cf;
  unsigned short* d = x16 + r*136 + cf;
#pragma unroll
  for (int q=0; q<4; ++q) {
    float4 v = *(const float4*)(src + q*4);
    u16x4 p;
    p[0] = __half_as_ushort(__float2half_rn(v.x));
    p[1] = __half_as_ushort(__float2half_rn(v.y));
    p[2] = __half_as_ushort(__float2half_rn(v.z));
    p[3] = __half_as_ushort(__float2half_rn(v.w));
    *(u16x4*)(d + q*4) = p;
  }
}

// ---------------- MFMA GEMM single-input, fp16 in & out (GGC message) ----------------
__global__ __launch_bounds__(512) void mgemm_h16(
    const float* __restrict__ A, const unsigned short* __restrict__ W16,
    const float* __restrict__ bias, unsigned short* __restrict__ C16)
{
  __shared__ unsigned short x16[64*136];
  const int tid = threadIdx.x;
  const int w = tid >> 6;
  const int lane = tid & 63;
  const int ln16 = lane & 15;
  const int lq = lane >> 4;
  const int rb = blockIdx.x * 64;
  stage_f16(A, rb, tid, x16);
  __syncthreads();

  f32x4 acc[4];
  f32x4 bv = *(const f32x4*)(bias + w*16 + lq*4);
#pragma unroll
  for (int nt=0; nt<4; ++nt) acc[nt] = bv;
#pragma unroll
  for (int kt=0; kt<4; ++kt) {
    const int bo = kt*32 + lq*8;
    f16x8 bx[4];
#pragma unroll
    for (int nt=0; nt<4; ++nt)
      bx[nt] = *(const f16x8*)(x16 + (nt*16+ln16)*136 + bo);
    f16x8 ah = *(const f16x8*)(W16 + (size_t)(w*16 + ln16)*128 + kt*32 + lq*8);
#pragma unroll
    for (int nt=0; nt<4; ++nt)
      acc[nt] = __builtin_amdgcn_mfma_f32_16x16x32_f16(ah, bx[nt], acc[nt], 0,0,0);
  }
#pragma unroll
  for (int nt=0; nt<4; ++nt) {
    f32x4 o = acc[nt];
    u16x4 p;
#pragma unroll
    for (int e=0;e<4;++e) p[e] = __half_as_ushort(__float2half_rn(o[e]));
    *(u16x4*)(C16 + (size_t)(rb + nt*16 + ln16)*128 + w*16 + lq*4) = p;
  }
}

// ---------------- MFMA GEMM dual-input, fp16-single (+optional dual output) ----------------
__global__ __launch_bounds__(512) void mgemm2(
    const float* __restrict__ A1, const unsigned short* __restrict__ W1,
    const float* __restrict__ A2, const unsigned short* __restrict__ W2,
    const float* __restrict__ bias1, const float* __restrict__ bias2,
    float* __restrict__ C, float* __restrict__ C2, int wstride)
{
  __shared__ unsigned short x1[64*136];
  __shared__ unsigned short x2[64*136];
  const int tid = threadIdx.x;
  const int w = tid >> 6;
  const int lane = tid & 63;
  const int ln16 = lane & 15;
  const int lq = lane >> 4;
  const int rb = blockIdx.x * 64;
  stage_f16(A1, rb, tid, x1);
  stage_f16(A2, rb, tid, x2);
  __syncthreads();

  f32x4 acc[4];
  {
    f32x4 bv = *(const f32x4*)(bias1 + w*16 + lq*4);
    if (bias2) {
      f32x4 b2 = *(const f32x4*)(bias2 + w*16 + lq*4);
#pragma unroll
      for (int e=0;e<4;++e) bv[e] += b2[e];
    }
#pragma unroll
    for (int nt=0; nt<4; ++nt) acc[nt] = bv;
  }
#pragma unroll
  for (int p=0; p<2; ++p) {
    const unsigned short* x = p ? x2 : x1;
    const unsigned short* W = p ? W2 : W1;
#pragma unroll
    for (int kt=0; kt<4; ++kt) {
      const int bo = kt*32 + lq*8;
      f16x8 bx[4];
#pragma unroll
      for (int nt=0; nt<4; ++nt)
        bx[nt] = *(const f16x8*)(x + (nt*16+ln16)*136 + bo);
      f16x8 ah = *(const f16x8*)(W + (size_t)(w*16 + ln16)*wstride + kt*32 + lq*8);
#pragma unroll
      for (int nt=0; nt<4; ++nt)
        acc[nt] = __builtin_amdgcn_mfma_f32_16x16x32_f16(ah, bx[nt], acc[nt], 0,0,0);
    }
  }
#pragma unroll
  for (int nt=0; nt<4; ++nt) {
    f32x4 o = acc[nt];
    const size_t off = (size_t)(rb + nt*16 + ln16)*128 + w*16 + lq*4;
    *(float4*)(C + off) = make_float4(o[0],o[1],o[2],o[3]);
    if (C2) *(float4*)(C2 + off) = make_float4(o[0],o[1],o[2],o[3]);
  }
}

// ---------------- fused GRU, fp16-single ----------------
__global__ __launch_bounds__(512) void gru_fused(
    const float* __restrict__ abuf, float* __restrict__ hh,
    const unsigned short* __restrict__ GI16, const unsigned short* __restrict__ GH16,
    const float* __restrict__ bih, const float* __restrict__ bhh)
{
  __shared__ unsigned short x16[64*136];
  __shared__ unsigned short h16[64*136];
  const int tid = threadIdx.x;
  const int w = tid >> 6;
  const int lane = tid & 63;
  const int ln16 = lane & 15;
  const int lq = lane >> 4;
  const int rb = blockIdx.x * 64;
  stage_f16(abuf, rb, tid, x16);
  stage_f16(hh, rb, tid, h16);
  __syncthreads();

  f32x4 rr[4], zz[4], nn_[4];
#pragma unroll
  for (int j=0; j<3; ++j) {
    const int tile = w + j*8;
    f32x4 ai[4], ag[4];
    f32x4 bi = *(const f32x4*)(bih + tile*16 + lq*4);
    f32x4 bg = *(const f32x4*)(bhh + tile*16 + lq*4);
#pragma unroll
    for (int nt=0; nt<4; ++nt) { ai[nt] = bi; ag[nt] = bg; }
#pragma unroll
    for (int kt=0; kt<4; ++kt) {
      const int bo = kt*32 + lq*8;
      f16x8 bx[4], bh_[4];
#pragma unroll
      for (int nt=0; nt<4; ++nt) {
        bx[nt] = *(const f16x8*)(x16 + (nt*16+ln16)*136 + bo);
        bh_[nt] = *(const f16x8*)(h16 + (nt*16+ln16)*136 + bo);
      }
      const size_t co = (size_t)(tile*16 + ln16)*128 + kt*32 + lq*8;
      f16x8 aI = *(const f16x8*)(GI16 + co);
      f16x8 aH = *(const f16x8*)(GH16 + co);
#pragma unroll
      for (int nt=0; nt<4; ++nt) {
        ai[nt] = __builtin_amdgcn_mfma_f32_16x16x32_f16(aI, bx[nt], ai[nt], 0,0,0);
        ag[nt] = __builtin_amdgcn_mfma_f32_16x16x32_f16(aH, bh_[nt], ag[nt], 0,0,0);
      }
    }
#pragma unroll
    for (int nt=0; nt<4; ++nt) {
#pragma unroll
      for (int e=0; e<4; ++e) {
        if (j == 0)      rr[nt][e] = fsig(ai[nt][e] + ag[nt][e]);
        else if (j == 1) zz[nt][e] = fsig(ai[nt][e] + ag[nt][e]);
        else             nn_[nt][e] = ftanh(ai[nt][e] + rr[nt][e]*ag[nt][e]);
      }
    }
  }
#pragma unroll
  for (int nt=0; nt<4; ++nt) {
    float* hp = hh + (size_t)(rb + nt*16 + ln16)*128 + w*16 + lq*4;
    float4 ho = *(const float4*)hp;
    float hv[4] = {ho.x, ho.y, ho.z, ho.w};
    float o[4];
#pragma unroll
    for (int e=0; e<4; ++e)
      o[e] = (1.0f - zz[nt][e])*nn_[nt][e] + zz[nt][e]*hv[e];
    *(float4*)hp = make_float4(o[0],o[1],o[2],o[3]);
  }
}

// ---------------- fused LSTM v6 ----------------
__global__ __launch_bounds__(512) void lstm_fused6(
    float* __restrict__ hL,
    const unsigned short* __restrict__ fs16a, const unsigned short* __restrict__ fs16d,
    const int* __restrict__ nbrA, const int* __restrict__ nbrD,
    const unsigned short* __restrict__ WI0, const unsigned short* __restrict__ WH0,
    const unsigned short* __restrict__ WI1, const unsigned short* __restrict__ WH1,
    const float* __restrict__ bsum0, const float* __restrict__ bsum1)
{
  __shared__ unsigned short xb[64*132];
  __shared__ unsigned short hb[64*132];
  const int tid = threadIdx.x;
  const int w = tid >> 6;
  const int lane = tid & 63;
  const int ln16 = lane & 15;
  const int lq = lane >> 4;
  const int b = blockIdx.x;
  const bool dir = (b >= 512);
  const int nb = (dir ? (b - 512) : b) * 64;
  const unsigned short* fs16 = dir ? fs16d : fs16a;
  const int* nbr = dir ? nbrD : nbrA;
  const unsigned short* WI = dir ? WI1 : WI0;
  const unsigned short* WH = dir ? WH1 : WH0;
  const float* bsum = dir ? bsum1 : bsum0;

  const int gr = tid >> 3;
  const int gc = (tid & 7) * 16;
  const int* nrow = nbr + (size_t)(nb + gr)*DD;

  f32x4 bias[4];
#pragma unroll
  for (int g=0; g<4; ++g)
    bias[g] = *(const f32x4*)(bsum + g*128 + w*16 + lq*4);

  f32x4 cst[4];
#pragma unroll
  for (int nt=0; nt<4; ++nt)
#pragma unroll
    for (int e=0; e<4; ++e) cst[nt][e] = 0.0f;

  u16x8 xg0, xg1;
  {
    int gidx = nrow[0];
    const unsigned short* src = fs16 + (size_t)gidx*128 + gc;
    xg0 = *(const u16x8*)(src);
    xg1 = *(const u16x8*)(src + 8);
    unsigned short* d = xb + gr*132 + gc;
    *(u16x8*)d = xg0;
    *(u16x8*)(d+8) = xg1;
  }
  int gnext = nrow[1];

#pragma unroll 1
  for (int t=0; t<16; ++t) {
    __syncthreads();

    f32x4 racc[4][4];
#pragma unroll
    for (int g=0; g<4; ++g)
#pragma unroll
      for (int nt=0; nt<4; ++nt)
        racc[g][nt] = bias[g];

#pragma unroll
    for (int kt=0; kt<4; ++kt) {
      const int bo = kt*32 + lq*8;
      f16x8 bx[4];
#pragma unroll
      for (int nt=0; nt<4; ++nt)
        bx[nt] = *(const f16x8*)(xb + (nt*16+ln16)*132 + bo);
#pragma unroll
      for (int g=0; g<4; ++g) {
        f16x8 aI = *(const f16x8*)(WI + (size_t)(g*128 + w*16 + ln16)*128 + kt*32 + lq*8);
#pragma unroll
        for (int nt=0; nt<4; ++nt)
          racc[g][nt] = __builtin_amdgcn_mfma_f32_16x16x32_f16(aI, bx[nt], racc[g][nt], 0,0,0);
      }
    }
    if (t < 15) {
      const unsigned short* src = fs16 + (size_t)gnext*128 + gc;
      xg0 = *(const u16x8*)(src);
      xg1 = *(const u16x8*)(src + 8);
      if (t < 14) gnext = nrow[t+2];
    }
    if (t > 0) {
#pragma unroll
      for (int kt=0; kt<4; ++kt) {
        const int bo = kt*32 + lq*8;
        f16x8 bh[4];
#pragma unroll
        for (int nt=0; nt<4; ++nt)
          bh[nt] = *(const f16x8*)(hb + (nt*16+ln16)*132 + bo);
#pragma unroll
        for (int g=0; g<4; ++g) {
          f16x8 aH = *(const f16x8*)(WH + (size_t)(g*128 + w*16 + ln16)*128 + kt*32 + lq*8);
#pragma unroll
          for (int nt=0; nt<4; ++nt)
            racc[g][nt] = __builtin_amdgcn_mfma_f32_16x16x32_f16(aH, bh[nt], racc[g][nt], 0,0,0);
        }
      }
    }
    __syncthreads();

#pragma unroll
    for (int nt=0; nt<4; ++nt) {
      float hv[4];
#pragma unroll
      for (int e=0; e<4; ++e) {
        float ig = fsig(racc[0][nt][e]);
        float fg = fsig(racc[1][nt][e]);
        float gg = ftanh(racc[2][nt][e]);
        float og = fsig(racc[3][nt][e]);
        float cc = fg*cst[nt][e] + ig*gg;
        cst[nt][e] = cc;
        hv[e] = og*ftanh(cc);
      }
      const int node = nt*16 + ln16;
      const int col = w*16 + lq*4;
      if (t < 15) {
        u16x4 hw;
#pragma unroll
        for (int e=0; e<4; ++e) hw[e] = __half_as_ushort(__float2half_rn(hv[e]));
        *(u16x4*)(hb + node*132 + col) = hw;
      } else {
        *(float4*)(hL + (size_t)((dir?NN:0) + nb + node)*128 + col) =
            make_float4(hv[0], hv[1], hv[2], hv[3]);
      }
    }
    if (t < 15) {
      unsigned short* d = xb + gr*132 + gc;
      *(u16x8*)d = xg0;
      *(u16x8*)(d+8) = xg1;
    }
  }
}

// ---------------- LayerNorm + leaky relu ----------------
__global__ void ln_lrelu_kernel(float* __restrict__ out, const float* __restrict__ x,
                                const float* __restrict__ add,
                                const float* __restrict__ g, const float* __restrict__ b) {
  int n = blockIdx.x, j = threadIdx.x;
  size_t base = (size_t)n*128;
  float v = x[base+j];
  if (add) v += add[base+j];
  __shared__ float sh[4];
  float s = v;
#pragma unroll
  for (int m=32; m>=1; m>>=1) s += __shfl_xor(s, m, 64);
  if ((j&63)==0) sh[j>>6] = s;
  __syncthreads();
  float mean = (sh[0]+sh[1]) * 0.0078125f;
  float d = v - mean;
  float q = d*d;
#pragma unroll
  for (int m=32; m>=1; m>>=1) q += __shfl_xor(q, m, 64);
  if ((j&63)==0) sh[2+(j>>6)] = q;
  __syncthreads();
  float var = (sh[2]+sh[3]) * 0.0078125f;
  float y = d * rsqrtf(var + 1e-5f) * g[j] + b[j];
  out[base+j] = (y >= 0.0f) ? y : 0.01f*y;
}

// ---------------- fused LN1 -> residual LN3 ----------------
__global__ void ln13_kernel(float* __restrict__ h, const float* __restrict__ nsrc,
                            const float* __restrict__ g1, const float* __restrict__ b1,
                            const float* __restrict__ g3, const float* __restrict__ b3,
                            unsigned short* __restrict__ out16) {
  int n = blockIdx.x, j = threadIdx.x;
  size_t base = (size_t)n*128;
  __shared__ float sh[4];
  float v = nsrc[base+j];
  float s = v;
#pragma unroll
  for (int m=32; m>=1; m>>=1) s += __shfl_xor(s, m, 64);
  if ((j&63)==0) sh[j>>6] = s;
  __syncthreads();
  float mean = (sh[0]+sh[1]) * 0.0078125f;
  float d = v - mean;
  float q = d*d;
#pragma unroll
  for (int m=32; m>=1; m>>=1) q += __shfl_xor(q, m, 64);
  if ((j&63)==0) sh[2+(j>>6)] = q;
  __syncthreads();
  float var = (sh[2]+sh[3]) * 0.0078125f;
  float y1 = d * rsqrtf(var + 1e-5f) * g1[j] + b1[j];
  y1 = (y1 >= 0.0f) ? y1 : 0.01f*y1;
  __syncthreads();
  float u = h[base+j] + y1;
  s = u;
#pragma unroll
  for (int m=32; m>=1; m>>=1) s += __shfl_xor(s, m, 64);
  if ((j&63)==0) sh[j>>6] = s;
  __syncthreads();
  mean = (sh[0]+sh[1]) * 0.0078125f;
  d = u - mean;
  q = d*d;
#pragma unroll
  for (int m=32; m>=1; m>>=1) q += __shfl_xor(q, m, 64);
  if ((j&63)==0) sh[2+(j>>6)] = q;
  __syncthreads();
  var = (sh[2]+sh[3]) * 0.0078125f;
  float y3 = d * rsqrtf(var + 1e-5f) * g3[j] + b3[j];
  float o = (y3 >= 0.0f) ? y3 : 0.01f*y3;
  h[base+j] = o;
  if (out16) out16[base+j] = __half_as_ushort(__float2half_rn(o));
}

// ---------------- segment mean ----------------
__global__ void segmean_kernel(float* __restrict__ out, const float* __restrict__ x,
                               const float* __restrict__ y) {
  int b = blockIdx.x, j = threadIdx.x;
  float s = 0.0f;
  for (int r=0; r<128; ++r) {
    size_t n = (size_t)(b*128 + r)*128 + j;
    s += x[n];
    if (y) s += y[n];
  }
  out[(size_t)b*128 + j] = s * 0.0078125f;
}

// ---------------- classifier head ----------------
__global__ void cls_kernel(float* __restrict__ out, const float* __restrict__ h2,
                           const float* __restrict__ Wc, const float* __restrict__ bc) {
  int gid = blockIdx.x*256 + threadIdx.x;
  if (gid >= BB*10) return;
  int mrow = gid/10, c = gid - mrow*10;
  const float* arow = h2 + (size_t)mrow*128;
  const float* wrow = Wc + (size_t)c*128;
  float s = bc[c];
  for (int k=0;k<128;++k) s += arow[k]*wrow[k];
  out[gid] = s;
}

__global__ void bail_kernel(float* out, float v) {
  if (threadIdx.x==0 && blockIdx.x==0) out[0] = v;
}

// ---------------- host orchestration ----------------
extern "C" void kernel_launch(void* const* d_in, const int* in_sizes, int n_in,
                              void* d_out, int out_size, void* d_ws, size_t ws_size,
                              hipStream_t stream)
{
  const int* act_ids  = (const int*)d_in[0];
  const int* dur_ids  = (const int*)d_in[1];
  const int* act2_ids = (const int*)d_in[2];
  const int* nbr_a2d  = (const int*)d_in[3];
  const int* nbr_d2a  = (const int*)d_in[4];
  const int* src2     = (const int*)d_in[5];
  const int* dst2     = (const int*)d_in[6];
  const float* emb_act     = (const float*)d_in[8];
  const float* emb_dur     = (const float*)d_in[9];
  const float* emb_act2    = (const float*)d_in[10];
  const float* transform_W = (const float*)d_in[11];
  const float* transform_b = (const float*)d_in[12];
  const float* ggc_W   = (const float*)d_in[13];
  const float* ggc_b   = (const float*)d_in[14];
  const float* gru_Wih = (const float*)d_in[15];
  const float* gru_Whh = (const float*)d_in[16];
  const float* gru_bih = (const float*)d_in[17];
  const float* gru_bhh = (const float*)d_in[18];
  const float* hn_g    = (const float*)d_in[19];
  const float* hn_b    = (const float*)d_in[20];
  const float* lstm_Wih = (const float*)d_in[21];
  const float* lstm_Whh = (const float*)d_in[22];
  const float* lstm_bih = (const float*)d_in[23];
  const float* lstm_bhh = (const float*)d_in[24];
  const float* fcs_W = (const float*)d_in[25];
  const float* fcs_b = (const float*)d_in[26];
  const float* fcn_W = (const float*)d_in[27];
  const float* fcn_b = (const float*)d_in[28];
  const float* n1_g = (const float*)d_in[29];
  const float* n1_b = (const float*)d_in[30];
  const float* n3_g = (const float*)d_in[31];
  const float* n3_b = (const float*)d_in[32];
  const float* mh_W1 = (const float*)d_in[33];
  const float* mh_b1 = (const float*)d_in[34];
  const float* mh_W2 = (const float*)d_in[35];
  const float* mh_b2 = (const float*)d_in[36];
  const float* mo_W1 = (const float*)d_in[37];
  const float* mo_b1 = (const float*)d_in[38];
  const float* mo_W2 = (const float*)d_in[39];
  const float* mo_b2 = (const float*)d_in[40];
  const float* mlp_W1 = (const float*)d_in[41];
  const float* mlp_b1 = (const float*)d_in[42];
  const float* mlp_W2 = (const float*)d_in[43];
  const float* mlp_b2 = (const float*)d_in[44];
  const float* cls_W = (const float*)d_in[45];
  const float* cls_b = (const float*)d_in[46];

  float* ws = (float*)d_ws;
  float* ha   = ws;
  float* hd   = ws + (size_t)NF;
  float* hg2  = ws + 2*(size_t)NF;
  float* res  = ws + 3*(size_t)NF;
  float* hh   = ws + 4*(size_t)NF;
  float* SCR  = ws + 5*(size_t)NF;
  float* abuf = SCR + (size_t)NF;
  float* hnf  = SCR;                       // fp32, used after GGC loop
  float* hLb  = SCR + 8*(size_t)NF;
  float* SMALL = ws + 15*(size_t)NF;
  float* hg2m = SMALL;
  float* hgm  = SMALL + 32768;
  float* o1b  = SMALL + 65536;
  float* o2b  = SMALL + 98304;
  float* t1b  = SMALL + 131072;
  float* t2b  = SMALL + 163840;
  float* h1b  = SMALL + 196608;
  float* h2b  = SMALL + 262144;
  float* bsum = SMALL + 294912;
  float* WTb  = SMALL + 296960;
  const size_t NEED_BYTES = (size_t)(15*(size_t)NF + 296960 + 1032192) * 4;
  if (ws_size < NEED_BYTES) {
    hipMemsetAsync(d_out, 0, (size_t)out_size*sizeof(float), stream);
    bail_kernel<<<1,64,0,stream>>>((float*)d_out, (float)ws_size);
    return;
  }
  float* na = hg2;
  float* nd = res;
  unsigned short* mb16 = (unsigned short*)SCR;          // fp16 GGC messages (within loop only)
  unsigned short* fs16a = (unsigned short*)(SCR + 2*(size_t)NF);
  unsigned short* fs16d = fs16a + (size_t)NF;
  int* csr_cnt    = (int*)(SCR + 3*(size_t)NF);
  int* csr_rowptr = csr_cnt + NN;
  int* csr_cursor = csr_rowptr + NN + 2;
  int* csr_elist  = csr_cursor + NN;

  const int O_TRANSFORM = 0;
  const int O_SPLIT    = 147456;
  const int O_SPLIT2   = 409600;
  const int O_MH1      = 802816;
  const int O_MH2      = 819200;
  const int O_MO1      = 835584;
  const int O_MO2      = 851968;
  const int O_MLP1     = 868352;
  const int O_MLP2     = 999424;

  unsigned short* T16 = (unsigned short*)(WTb + O_TRANSFORM);
  unsigned short* WI16 = (unsigned short*)(WTb + O_SPLIT);
  unsigned short* WH16 = WI16 + 4*65536;

  unsigned short* SP2 = (unsigned short*)(WTb + O_SPLIT2);
  unsigned short* GGC16 = SP2;
  unsigned short* GIH16 = GGC16 + 16384;
  unsigned short* GHH16 = GIH16 + 49152;
  unsigned short* FCS16 = GHH16 + 49152;
  unsigned short* FCN16 = FCS16 + 65536;

  TDescArr da;
  int di = 0;
  auto addT = [&](const float* s, float* d, int R, int C){ da.d[di].src=s; da.d[di].dst=d; da.d[di].R=R; da.d[di].C=C; ++di; };
  addT(mh_W1, WTb + O_MH1, 128, 128);
  addT(mh_W2, WTb + O_MH2, 128, 128);
  addT(mo_W1, WTb + O_MO1, 128, 128);
  addT(mo_W2, WTb + O_MO2, 128, 128);
  addT(mlp_W1, WTb + O_MLP1, 256, 512);
  addT(mlp_W2, WTb + O_MLP2, 128, 256);
  transpose_many<<<dim3(512, di), 256, 0, stream>>>(da);
  bias_sum_kernel<<<8, 256, 0, stream>>>(lstm_bih, lstm_bhh, bsum);

  CDescArr ca;
  int ci = 0;
  auto addC = [&](const float* s, unsigned short* d, int n){ ca.d[ci].src=s; ca.d[ci].dst=d; ca.d[ci].n=n; ++ci; };
  addC(lstm_Wih, WI16, 4*512*128);
  addC(lstm_Whh, WH16, 4*512*128);
  addC(transform_W, T16, 32768);
  addC(ggc_W, GGC16, 16384);
  addC(gru_Wih, GIH16, 49152);
  addC(gru_Whh, GHH16, 49152);
  addC(fcs_W, FCS16, 65536);
  addC(fcn_W, FCN16, 65536);
  f32to16_many<<<dim3(256, ci), 256, 0, stream>>>(ca);

  hipMemsetAsync(csr_cnt, 0, (size_t)NN*sizeof(int), stream);
  hist_kernel<<<E2N/256, 256, 0, stream>>>(dst2, csr_cnt);
  scan_kernel<<<1, 1024, 0, stream>>>(csr_cnt, csr_rowptr, csr_cursor);
  fill_kernel<<<E2N/256, 256, 0, stream>>>(src2, dst2, csr_cursor, csr_elist);

  auto smemK = [](int K, int BN){ return (size_t)(32*(K+4) + 16*BN)*4; };
  const int gB = BB/32;
  const int gM = NN/64;

  embed3_kernel<<<dim3(NF/256, 3), 256, 0, stream>>>(act_ids, dur_ids, act2_ids,
      emb_act, emb_dur, emb_act2, ha, hd, hg2, fs16a, fs16d);
  mgemm2<<<gM, 512, 0, stream>>>(hg2, T16, hd, T16 + 128,
      transform_b, nullptr, res, hh, 256);

  for (int it=0; it<2; ++it) {
    mgemm_h16<<<gM, 512, 0, stream>>>(hh, GGC16, ggc_b, mb16);
    gather_ggc<<<NN/4, 256, 0, stream>>>(mb16, csr_rowptr, csr_elist, abuf);
    gru_fused<<<gM, 512, 0, stream>>>(abuf, hh, GIH16, GHH16, gru_bih, gru_bhh);
  }
  ln_lrelu_kernel<<<NN, 128, 0, stream>>>(hnf, hh, res, hn_g, hn_b);
  segmean_kernel<<<BB, 128, 0, stream>>>(hg2m, hnf, nullptr);

  for (int l=0; l<2; ++l) {
    const int i0 = l*2 + 0, i1 = l*2 + 1;
    lstm_fused6<<<1024, 512, 0, stream>>>(hLb, fs16a, fs16d, nbr_a2d, nbr_d2a,
        WI16 + i0*65536, WH16 + i0*65536,
        WI16 + i1*65536, WH16 + i1*65536,
        bsum + i0*512, bsum + i1*512);

    mgemm2<<<gM, 512, 0, stream>>>(hd, FCS16 + i0*16384,
        hLb, FCN16 + i0*16384,
        fcs_b + i0*128, fcn_b + i0*128, nd, nullptr, 128);
    mgemm2<<<gM, 512, 0, stream>>>(ha, FCS16 + i1*16384,
        hLb + (size_t)NN*128, FCN16 + i1*16384,
        fcs_b + i1*128, fcn_b + i1*128, na, nullptr, 128);
    ln13_kernel<<<NN, 128, 0, stream>>>(ha, na, n1_g + i0*128, n1_b + i0*128,
        n3_g + i0*128, n3_b + i0*128, (l==0) ? fs16a : nullptr);
    ln13_kernel<<<NN, 128, 0, stream>>>(hd, nd, n1_g + i1*128, n1_b + i1*128,
        n3_g + i1*128, n3_b + i1*128, (l==0) ? fs16d : nullptr);
  }
  segmean_kernel<<<BB, 128, 0, stream>>>(hgm, ha, hd);

  gemm_nt<128,1><<<gB, 256, smemK(128,128), stream>>>(hg2m, nullptr, nullptr, nullptr, 128,
      WTb + O_MO1, mo_b1, t1b, 128, 0);
  gemm_nt<128,1><<<gB, 256, smemK(128,128), stream>>>(t1b, nullptr, nullptr, nullptr, 128,
      WTb + O_MO2, mo_b2, o1b, 128, 0);
  gemm_nt<128,1><<<gB, 256, smemK(128,128), stream>>>(hgm, nullptr, nullptr, nullptr, 128,
      WTb + O_MH1, mh_b1, t2b, 128, 0);
  gemm_nt<128,1><<<gB, 256, smemK(128,128), stream>>>(t2b, nullptr, nullptr, nullptr, 128,
      WTb + O_MH2, mh_b2, o2b, 128, 0);
  gemm_nt<256,0><<<gB, 256, smemK(256,256), stream>>>(o1b, hg2m, nullptr, nullptr, 128,
      WTb + O_MLP1, nullptr, h1b, 256, 0);
  gemm_nt<256,1><<<gB, 256, smemK(256,256), stream>>>(o2b, hgm, nullptr, nullptr, 128,
      WTb + O_MLP1 + 256*256, mlp_b1, h1b, 256, 1);
  gemm_nt<128,1><<<gB, 256, smemK(256,128), stream>>>(h1b, h1b + 128, nullptr, nullptr, 256,
      WTb + O_MLP2, mlp_b2, h2b, 256, 0);
  cls_kernel<<<10, 256, 0, stream>>>((float*)d_out, h2b, cls_W, cls_b);
}